// Round 1
// baseline (681.102 us; speedup 1.0000x reference)
//
#include <hip/hip_runtime.h>

typedef unsigned short u16;
typedef u16  u16x4 __attribute__((ext_vector_type(4)));
typedef u16  u16x8 __attribute__((ext_vector_type(8)));
typedef float f32x4 __attribute__((ext_vector_type(4)));
typedef int   i32x4 __attribute__((ext_vector_type(4)));
typedef __bf16 bf16x8 __attribute__((ext_vector_type(8)));

#define LSEQ 2048
#define NB 8
#define EDIM 1024
#define HNUM 16
#define DDIM 64
#define KPDIM 256
#define NE (NB*EDIM)       /* 8192 */
#define MROWS (LSEQ*NB)    /* 16384 */

__device__ __forceinline__ u16 f2b(float f) {
  unsigned u = __builtin_bit_cast(unsigned, f);
  u += 0x7fffu + ((u >> 16) & 1u);
  return (u16)(u >> 16);
}

__device__ __forceinline__ void gl_lds16(const void* g, void* l) {
  __builtin_amdgcn_global_load_lds(
      (const __attribute__((address_space(1))) void*)g,
      (__attribute__((address_space(3))) void*)l, 16, 0, 0);
}

__device__ __forceinline__ f32x4 mfma16(bf16x8 a, bf16x8 b, f32x4 c) {
  return __builtin_amdgcn_mfma_f32_16x16x32_bf16(a, b, c, 0, 0, 0);
}

// ---------------------------------------------------------------------------
// Weight prep kernels
// ---------------------------------------------------------------------------
// f32 -> bf16 cast, first scale_n4 float4's multiplied by sc (q-row scaling)
__global__ void wconv(const float* __restrict__ src, u16* __restrict__ dst,
                      int n4, int scale_n4, float sc) {
  int i = blockIdx.x * blockDim.x + threadIdx.x;
  if (i >= n4) return;
  f32x4 v = ((const f32x4*)src)[i];
  float s = (i < scale_n4) ? sc : 1.0f;
  u16x4 o;
  o[0] = f2b(v[0] * s); o[1] = f2b(v[1] * s);
  o[2] = f2b(v[2] * s); o[3] = f2b(v[3] * s);
  ((u16x4*)dst)[i] = o;
}

// (O, I, 8) f32  ->  (O, t*E + i) bf16   (per-wave LDS transpose)
__global__ void wtrans(const float* __restrict__ ew, const float* __restrict__ fw,
                       u16* __restrict__ eT, u16* __restrict__ fT) {
  const float* src = blockIdx.y ? fw : ew;
  u16* dst = blockIdx.y ? fT : eT;
  int eo = blockIdx.x >> 4;
  int ei0 = (blockIdx.x & 15) * 64;
  int l = threadIdx.x;
  __shared__ u16 lds[8][64];
  const float* s = src + (size_t)eo * 8192 + (size_t)ei0 * 8 + l * 8;
  f32x4 a = *(const f32x4*)s;
  f32x4 b = *(const f32x4*)(s + 4);
  float v[8] = {a[0], a[1], a[2], a[3], b[0], b[1], b[2], b[3]};
#pragma unroll
  for (int t = 0; t < 8; ++t) lds[t][l] = f2b(v[t]);
  __syncthreads();
  int t = l >> 3, c = l & 7;
  i32x4 out = *(const i32x4*)&lds[t][c * 8];
  *(i32x4*)(dst + (size_t)eo * 8192 + t * 1024 + ei0 + c * 8) = out;
}

__global__ void bscale(const float* __restrict__ b, float* __restrict__ out) {
  int i = blockIdx.x * blockDim.x + threadIdx.x;
  if (i < EDIM) out[i] = b[i] * 0.125f;
}

// ---------------------------------------------------------------------------
// GEMM: C[m, o] = sum_k A[m,k] * B[o,k] + bias[o]
//   AMODE 0: A bf16, rows contiguous (ld = K), global_load_lds staging
//   AMODE 1: A bf16 conv-gather (compression): m=(nn,p), k=(t,ei)
//   AMODE 2: A f32, rows contiguous; reg-staged convert to bf16
//   F32OUT : 0 -> bf16 C, 1 -> f32 C.   NCOL fixed = 1024.
// grid = (M/128, 8, z) ; block = 256
// ---------------------------------------------------------------------------
template<int AMODE, int F32OUT>
__global__ __launch_bounds__(256)
void gemm_bt(const void* A0p, const void* A1p, const void* A2p,
             const u16* B0p, const u16* B1p, const u16* B2p,
             const float* b0p, const float* b1p, const float* b2p,
             void* C0p, void* C1p, void* C2p,
             int M, int K) {
  const int z = blockIdx.z;
  const void* Ap = z == 0 ? A0p : (z == 1 ? A1p : A2p);
  const u16* Bp = z == 0 ? B0p : (z == 1 ? B1p : B2p);
  const float* biasp = z == 0 ? b0p : (z == 1 ? b1p : b2p);
  void* Cp = z == 0 ? C0p : (z == 1 ? C1p : C2p);

  __shared__ u16 Alds[128 * 64];
  __shared__ u16 Blds[128 * 64];

  const int tid = threadIdx.x;
  const int w = tid >> 6, lane = tid & 63;
  const int lr = lane & 15, lg = lane >> 4;
  const int m0 = blockIdx.x * 128, n0 = blockIdx.y * 128;
  const int wr = (w >> 1) * 64, wc = (w & 1) * 64;
  const int brow = lane >> 3;        // row within 8-row chunk
  const int bcol = (lane & 7) * 8;   // k element offset within tile

  f32x4 acc[4][4];
#pragma unroll
  for (int mi = 0; mi < 4; ++mi)
#pragma unroll
    for (int ni = 0; ni < 4; ++ni) {
      f32x4 zv = {0.f, 0.f, 0.f, 0.f};
      acc[mi][ni] = zv;
    }

  const int ktn = K >> 6;
  for (int kt = 0; kt < ktn; ++kt) {
    const int k0 = kt << 6;
    __syncthreads();
    // ---- stage B (always bf16 rows, ld = K) ----
#pragma unroll
    for (int i = 0; i < 4; ++i) {
      const int c = w * 4 + i;
      const int row = c * 8 + brow;
      gl_lds16(Bp + (size_t)(n0 + row) * K + k0 + bcol, &Blds[c * 512]);
    }
    // ---- stage A ----
    if (AMODE == 2) {
      const float* Af = (const float*)Ap;
#pragma unroll
      for (int i = 0; i < 4; ++i) {
        const int c = i * 256 + tid;       // 0..1023
        const int row = c >> 3, k8 = (c & 7) * 8;
        const float* s = Af + (size_t)(m0 + row) * K + k0 + k8;
        f32x4 v0 = *(const f32x4*)s;
        f32x4 v1 = *(const f32x4*)(s + 4);
        u16x8 pk;
        pk[0] = f2b(v0[0]); pk[1] = f2b(v0[1]); pk[2] = f2b(v0[2]); pk[3] = f2b(v0[3]);
        pk[4] = f2b(v1[0]); pk[5] = f2b(v1[1]); pk[6] = f2b(v1[2]); pk[7] = f2b(v1[3]);
        *(u16x8*)&Alds[row * 64 + k8] = pk;
      }
    } else if (AMODE == 0) {
      const u16* Ab = (const u16*)Ap;
#pragma unroll
      for (int i = 0; i < 4; ++i) {
        const int c = w * 4 + i;
        const int row = c * 8 + brow;
        gl_lds16(Ab + (size_t)(m0 + row) * K + k0 + bcol, &Alds[c * 512]);
      }
    } else {  // AMODE 1: conv gather.  m = nn*256 + p ; k = t*1024 + ei
      const u16* Ab = (const u16*)Ap;
#pragma unroll
      for (int i = 0; i < 4; ++i) {
        const int c = w * 4 + i;
        const int m = m0 + c * 8 + brow;
        const int nn = m >> 8, p = m & 255;
        const int k = k0 + bcol;
        gl_lds16(Ab + (size_t)(p * 8 + (k >> 10)) * NE + nn * EDIM + (k & 1023),
                 &Alds[c * 512]);
      }
    }
    __syncthreads();
    // ---- compute ----
#pragma unroll
    for (int ks = 0; ks < 2; ++ks) {
      bf16x8 af[4], bf[4];
#pragma unroll
      for (int mi = 0; mi < 4; ++mi)
        af[mi] = *(const bf16x8*)&Alds[(wr + mi * 16 + lr) * 64 + ks * 32 + lg * 8];
#pragma unroll
      for (int ni = 0; ni < 4; ++ni)
        bf[ni] = *(const bf16x8*)&Blds[(wc + ni * 16 + lr) * 64 + ks * 32 + lg * 8];
#pragma unroll
      for (int mi = 0; mi < 4; ++mi)
#pragma unroll
        for (int ni = 0; ni < 4; ++ni)
          acc[mi][ni] = mfma16(af[mi], bf[ni], acc[mi][ni]);
    }
  }
  // ---- epilogue ----
#pragma unroll
  for (int ni = 0; ni < 4; ++ni) {
    const int col = n0 + wc + ni * 16 + lr;
    const float bv = biasp[col];
#pragma unroll
    for (int mi = 0; mi < 4; ++mi)
#pragma unroll
      for (int j = 0; j < 4; ++j) {
        const int row = m0 + wr + mi * 16 + lg * 4 + j;
        const float v = acc[mi][ni][j] + bv;
        if (F32OUT) ((float*)Cp)[(size_t)row * 1024 + col] = v;
        else        ((u16*)Cp)[(size_t)row * 1024 + col] = f2b(v);
      }
  }
}

// ---------------------------------------------------------------------------
// Fused attention: per block (n, 64 q-rows), loop 16 heads.
// Q:(L,N,E) bf16 (pre-scaled)  Kc,Vc:(N,Kp,E) bf16 -> Aout:(L,N,E) bf16,
// AW:(N,L,Kp) f32 (head-mean of probs)
// ---------------------------------------------------------------------------
__global__ __launch_bounds__(256)
void attn_fused(const u16* __restrict__ Q, const u16* __restrict__ Kc,
                const u16* __restrict__ Vc, u16* __restrict__ Aout,
                float* __restrict__ AW) {
  __shared__ u16 klds[256 * 64];   // [p][d]  swizzled
  __shared__ u16 vlds[64 * 256];   // [d][p]  swizzled (transposed V)
  __shared__ u16 plds[4][16 * 256];// per-wave P [r][p] swizzled
  const int tid = threadIdx.x;
  const int w = tid >> 6, lane = tid & 63;
  const int lr = lane & 15, lg = lane >> 4;
  const int n = blockIdx.y;
  const int l0 = blockIdx.x * 64;
  const int lrow = l0 + w * 16 + lr;

  char* kbase = (char*)klds;
  char* vbase = (char*)vlds;
  char* pbase = (char*)&plds[w][0];

  f32x4 macc[16];
#pragma unroll
  for (int ni = 0; ni < 16; ++ni) { f32x4 zv = {0.f,0.f,0.f,0.f}; macc[ni] = zv; }

  for (int h = 0; h < HNUM; ++h) {
    __syncthreads();  // previous head fully consumed LDS
    // ---- stage K (swizzled rows) and V (transposed, swizzled) ----
    for (int it = 0; it < 8; ++it) {
      int c = it * 256 + tid;          // 0..2047 : p = c>>3, 16B chunk c&7
      int p = c >> 3, c16 = c & 7;
      size_t goff = (size_t)n * (KPDIM * EDIM) + (size_t)p * EDIM + h * DDIM + c16 * 8;
      i32x4 kd = *(const i32x4*)(Kc + goff);
      *(i32x4*)(kbase + p * 128 + ((c16 * 16) ^ ((p & 7) << 4))) = kd;
      i32x4 vd = *(const i32x4*)(Vc + goff);
      u16x8 vv = __builtin_bit_cast(u16x8, vd);
#pragma unroll
      for (int j = 0; j < 8; ++j) {
        int d = c16 * 8 + j;
        *(u16*)(vbase + d * 512 + ((p * 2) ^ ((d & 7) << 4))) = vv[j];
      }
    }
    // ---- q fragments (A operand: row=lr, k = lg*8 + i (+32*ks)) ----
    const u16* qp = Q + (size_t)lrow * NE + n * EDIM + h * DDIM + lg * 8;
    bf16x8 aq0 = *(const bf16x8*)qp;
    bf16x8 aq1 = *(const bf16x8*)(qp + 32);
    __syncthreads();
    // ---- S = q @ k^T : 16 rows x 256 cols per wave ----
    f32x4 s[16];
#pragma unroll
    for (int ni = 0; ni < 16; ++ni) { f32x4 zv = {0.f,0.f,0.f,0.f}; s[ni] = zv; }
#pragma unroll
    for (int ni = 0; ni < 16; ++ni) {
      int row = ni * 16 + lr;
      const char* kr = kbase + row * 128;
      bf16x8 b0 = *(const bf16x8*)(kr + ((16 * lg) ^ ((row & 7) << 4)));
      bf16x8 b1 = *(const bf16x8*)(kr + ((64 + 16 * lg) ^ ((row & 7) << 4)));
      s[ni] = mfma16(aq0, b0, s[ni]);
      s[ni] = mfma16(aq1, b1, s[ni]);
    }
    // ---- softmax (row r = lg*4+j lives in 16-lane group lg) ----
    float mx[4], sm[4], inv[4];
#pragma unroll
    for (int j = 0; j < 4; ++j) mx[j] = -1e30f;
#pragma unroll
    for (int ni = 0; ni < 16; ++ni)
#pragma unroll
      for (int j = 0; j < 4; ++j) mx[j] = fmaxf(mx[j], s[ni][j]);
#pragma unroll
    for (int msk = 1; msk <= 8; msk <<= 1)
#pragma unroll
      for (int j = 0; j < 4; ++j) mx[j] = fmaxf(mx[j], __shfl_xor(mx[j], msk, 64));
#pragma unroll
    for (int j = 0; j < 4; ++j) sm[j] = 0.f;
#pragma unroll
    for (int ni = 0; ni < 16; ++ni)
#pragma unroll
      for (int j = 0; j < 4; ++j) {
        float e = __expf(s[ni][j] - mx[j]);
        s[ni][j] = e; sm[j] += e;
      }
#pragma unroll
    for (int msk = 1; msk <= 8; msk <<= 1)
#pragma unroll
      for (int j = 0; j < 4; ++j) sm[j] += __shfl_xor(sm[j], msk, 64);
#pragma unroll
    for (int j = 0; j < 4; ++j) inv[j] = 1.0f / sm[j];
    // ---- normalize, accumulate head-mean, store P to LDS (bf16, swizzled) ----
#pragma unroll
    for (int ni = 0; ni < 16; ++ni)
#pragma unroll
      for (int j = 0; j < 4; ++j) {
        float pv = s[ni][j] * inv[j];
        macc[ni][j] += pv * 0.0625f;
        int r = lg * 4 + j;
        *(u16*)(pbase + r * 512 + ((ni * 32 + lr * 2) ^ ((r & 7) << 4))) = f2b(pv);
      }
    __syncthreads();
    // ---- O = P @ V ----
    f32x4 o[4];
#pragma unroll
    for (int ni2 = 0; ni2 < 4; ++ni2) { f32x4 zv = {0.f,0.f,0.f,0.f}; o[ni2] = zv; }
#pragma unroll
    for (int ks = 0; ks < 8; ++ks) {
      bf16x8 a = *(const bf16x8*)(pbase + lr * 512 + ((ks * 64 + 16 * lg) ^ ((lr & 7) << 4)));
#pragma unroll
      for (int ni2 = 0; ni2 < 4; ++ni2) {
        int d = ni2 * 16 + lr;
        bf16x8 b = *(const bf16x8*)(vbase + d * 512 + ((ks * 64 + 16 * lg) ^ ((d & 7) << 4)));
        o[ni2] = mfma16(a, b, o[ni2]);
      }
    }
    // ---- write O tile ----
#pragma unroll
    for (int ni2 = 0; ni2 < 4; ++ni2)
#pragma unroll
      for (int j = 0; j < 4; ++j) {
        int gl = l0 + w * 16 + lg * 4 + j;
        Aout[(size_t)gl * NE + n * EDIM + h * DDIM + ni2 * 16 + lr] = f2b(o[ni2][j]);
      }
  }
  // ---- write head-mean attention weights ----
#pragma unroll
  for (int ni = 0; ni < 16; ++ni)
#pragma unroll
    for (int j = 0; j < 4; ++j) {
      int r = lg * 4 + j;
      AW[(size_t)n * (LSEQ * KPDIM) + (size_t)(l0 + w * 16 + r) * KPDIM + ni * 16 + lr]
          = macc[ni][j];
    }
}

// ---------------------------------------------------------------------------
extern "C" void kernel_launch(void* const* d_in, const int* in_sizes, int n_in,
                              void* d_out, int out_size, void* d_ws, size_t ws_size,
                              hipStream_t stream) {
  const float* query = (const float*)d_in[0];
  const float* key   = (const float*)d_in[1];
  const float* value = (const float*)d_in[2];
  const float* ipw   = (const float*)d_in[3];
  const float* ipb   = (const float*)d_in[4];
  const float* ew    = (const float*)d_in[5];
  const float* eb    = (const float*)d_in[6];
  const float* fw    = (const float*)d_in[7];
  const float* fb    = (const float*)d_in[8];
  const float* ow    = (const float*)d_in[9];
  const float* ob    = (const float*)d_in[10];

  char* ws = (char*)d_ws;
  size_t off = 0;
  auto alloc = [&](size_t bytes) {
    void* p = ws + off;
    off += (bytes + 255) & ~(size_t)255;
    return p;
  };
  u16* qp    = (u16*)alloc((size_t)MROWS * EDIM * 2);
  u16* kp    = (u16*)alloc((size_t)MROWS * EDIM * 2);
  u16* vp    = (u16*)alloc((size_t)MROWS * EDIM * 2);
  u16* ao    = (u16*)alloc((size_t)MROWS * EDIM * 2);
  u16* kc    = (u16*)alloc((size_t)NB * KPDIM * EDIM * 2);
  u16* vc    = (u16*)alloc((size_t)NB * KPDIM * EDIM * 2);
  u16* w_in  = (u16*)alloc((size_t)3 * EDIM * EDIM * 2);
  u16* w_eT  = (u16*)alloc((size_t)EDIM * 8 * EDIM * 2);
  u16* w_fT  = (u16*)alloc((size_t)EDIM * 8 * EDIM * 2);
  u16* w_out = (u16*)alloc((size_t)EDIM * EDIM * 2);
  float* bq  = (float*)alloc(EDIM * 4);

  float* out_f = (float*)d_out;                       // (L, N, E)
  float* aw_f  = (float*)d_out + (size_t)MROWS * EDIM; // (N, L, Kp)

  // weight prep
  wconv<<<dim3(3072), 256, 0, stream>>>(ipw, w_in, 786432, 262144, 0.125f);
  wconv<<<dim3(1024), 256, 0, stream>>>(ow, w_out, 262144, 0, 1.0f);
  wtrans<<<dim3(16384, 2), 64, 0, stream>>>(ew, fw, w_eT, w_fT);
  bscale<<<dim3(4), 256, 0, stream>>>(ipb, bq);

  // q/k/v projections (f32 A, reg-staged convert). q scale folded into w/b.
  gemm_bt<2, 0><<<dim3(128, 8, 3), 256, 0, stream>>>(
      query, key, value,
      w_in, w_in + 1048576, w_in + 2097152,
      bq, ipb + 1024, ipb + 2048,
      qp, kp, vp, MROWS, 1024);

  // conv compression of k and v (GEMM with gather addressing)
  gemm_bt<1, 0><<<dim3(16, 8, 2), 256, 0, stream>>>(
      kp, vp, vp,
      w_eT, w_fT, w_fT,
      eb, fb, fb,
      kc, vc, vc, NB * KPDIM, 8192);

  // fused attention + head-mean weights
  attn_fused<<<dim3(32, 8), 256, 0, stream>>>(qp, kc, vc, ao, aw_f);

  // output projection -> f32 d_out
  gemm_bt<0, 1><<<dim3(128, 8, 1), 256, 0, stream>>>(
      ao, ao, ao,
      w_out, w_out, w_out,
      ob, ob, ob,
      out_f, out_f, out_f, MROWS, 1024);
}

// Round 2
// 618.995 us; speedup vs baseline: 1.1003x; 1.1003x over previous
//
#include <hip/hip_runtime.h>

typedef unsigned short u16;
typedef u16  u16x4 __attribute__((ext_vector_type(4)));
typedef u16  u16x8 __attribute__((ext_vector_type(8)));
typedef float f32x4 __attribute__((ext_vector_type(4)));
typedef int   i32x4 __attribute__((ext_vector_type(4)));
typedef __bf16 bf16x8 __attribute__((ext_vector_type(8)));

#define LSEQ 2048
#define NB 8
#define EDIM 1024
#define HNUM 16
#define DDIM 64
#define KPDIM 256
#define NE (NB*EDIM)       /* 8192 */
#define MROWS (LSEQ*NB)    /* 16384 */

__device__ __forceinline__ u16 f2b(float f) {
  unsigned u = __builtin_bit_cast(unsigned, f);
  u += 0x7fffu + ((u >> 16) & 1u);
  return (u16)(u >> 16);
}

__device__ __forceinline__ void gl_lds16(const void* g, void* l) {
  __builtin_amdgcn_global_load_lds(
      (const __attribute__((address_space(1))) void*)g,
      (__attribute__((address_space(3))) void*)l, 16, 0, 0);
}

__device__ __forceinline__ f32x4 mfma16(bf16x8 a, bf16x8 b, f32x4 c) {
  return __builtin_amdgcn_mfma_f32_16x16x32_bf16(a, b, c, 0, 0, 0);
}

// ---------------------------------------------------------------------------
// Weight prep kernels
// ---------------------------------------------------------------------------
__global__ void wconv(const float* __restrict__ src, u16* __restrict__ dst,
                      int n4, int scale_n4, float sc) {
  int i = blockIdx.x * blockDim.x + threadIdx.x;
  if (i >= n4) return;
  f32x4 v = ((const f32x4*)src)[i];
  float s = (i < scale_n4) ? sc : 1.0f;
  u16x4 o;
  o[0] = f2b(v[0] * s); o[1] = f2b(v[1] * s);
  o[2] = f2b(v[2] * s); o[3] = f2b(v[3] * s);
  ((u16x4*)dst)[i] = o;
}

// (O, I, 8) f32  ->  (O, t*E + i) bf16   (per-wave LDS transpose)
__global__ void wtrans(const float* __restrict__ ew, const float* __restrict__ fw,
                       u16* __restrict__ eT, u16* __restrict__ fT) {
  const float* src = blockIdx.y ? fw : ew;
  u16* dst = blockIdx.y ? fT : eT;
  int eo = blockIdx.x >> 4;
  int ei0 = (blockIdx.x & 15) * 64;
  int l = threadIdx.x;
  __shared__ u16 lds[8][64];
  const float* s = src + (size_t)eo * 8192 + (size_t)ei0 * 8 + l * 8;
  f32x4 a = *(const f32x4*)s;
  f32x4 b = *(const f32x4*)(s + 4);
  float v[8] = {a[0], a[1], a[2], a[3], b[0], b[1], b[2], b[3]};
#pragma unroll
  for (int t = 0; t < 8; ++t) lds[t][l] = f2b(v[t]);
  __syncthreads();
  int t = l >> 3, c = l & 7;
  i32x4 out = *(const i32x4*)&lds[t][c * 8];
  *(i32x4*)(dst + (size_t)eo * 8192 + t * 1024 + ei0 + c * 8) = out;
}

__global__ void bscale(const float* __restrict__ b, float* __restrict__ out) {
  int i = blockIdx.x * blockDim.x + threadIdx.x;
  if (i < EDIM) out[i] = b[i] * 0.125f;
}

// q/k/v f32 -> bf16, contiguous [3][MROWS][E]
__global__ void castqkv(const float* __restrict__ q, const float* __restrict__ k,
                        const float* __restrict__ v, u16* __restrict__ out) {
  const float* src = blockIdx.y == 0 ? q : (blockIdx.y == 1 ? k : v);
  size_t base = (size_t)blockIdx.y * ((size_t)MROWS * EDIM);
  size_t i = ((size_t)blockIdx.x * 256 + threadIdx.x) * 8;
  f32x4 v0 = *(const f32x4*)(src + i);
  f32x4 v1 = *(const f32x4*)(src + i + 4);
  u16x8 o;
  o[0] = f2b(v0[0]); o[1] = f2b(v0[1]); o[2] = f2b(v0[2]); o[3] = f2b(v0[3]);
  o[4] = f2b(v1[0]); o[5] = f2b(v1[1]); o[6] = f2b(v1[2]); o[7] = f2b(v1[3]);
  *(u16x8*)(out + base + i) = o;
}

// sum 4 split-K partials + bias -> bf16
__global__ void redc(const float* __restrict__ part, const float* __restrict__ eb,
                     const float* __restrict__ fb, u16* __restrict__ kc,
                     u16* __restrict__ vc) {
  int zc = blockIdx.y;
  const float* p = part + (size_t)zc * 4 * 2048 * 1024;
  u16* out = zc ? vc : kc;
  const float* bias = zc ? fb : eb;
  size_t i = ((size_t)blockIdx.x * 256 + threadIdx.x) * 4;
  f32x4 s = *(const f32x4*)(p + i);
  s += *(const f32x4*)(p + 2097152 + i);
  s += *(const f32x4*)(p + 2 * 2097152 + i);
  s += *(const f32x4*)(p + 3 * 2097152 + i);
  int col = (int)(i & 1023);
  f32x4 b = *(const f32x4*)(bias + col);
  u16x4 o;
  o[0] = f2b(s[0] + b[0]); o[1] = f2b(s[1] + b[1]);
  o[2] = f2b(s[2] + b[2]); o[3] = f2b(s[3] + b[3]);
  *(u16x4*)(out + i) = o;
}

// ---------------------------------------------------------------------------
// GEMM: C[m, o] = sum_k A[m,k] * B[o,k] (+ bias[o])
//   AMODE 0: A bf16, rows contiguous (ld = K), global_load_lds staging
//   AMODE 1: A bf16 conv-gather (compression): m=(nn,p), k=(t,ei)
//   AMODE 2: A f32, rows contiguous; reg-staged convert to bf16 (fallback)
//   OUTMODE 0: bf16 C + bias; 1: f32 C + bias; 2: f32 split-K partial, no bias
// grid = (M/128, 8, nz*kspl) ; block = 256
// ---------------------------------------------------------------------------
template<int AMODE, int OUTMODE>
__global__ __launch_bounds__(256)
void gemm_bt(const void* A0p, const void* A1p, const void* A2p,
             const u16* B0p, const u16* B1p, const u16* B2p,
             const float* b0p, const float* b1p, const float* b2p,
             void* C0p, void* C1p, void* C2p,
             int M, int K, int kspl) {
  const int zc = blockIdx.z / kspl, sp = blockIdx.z % kspl;
  const void* Ap = zc == 0 ? A0p : (zc == 1 ? A1p : A2p);
  const u16* Bp = zc == 0 ? B0p : (zc == 1 ? B1p : B2p);
  const float* biasp = zc == 0 ? b0p : (zc == 1 ? b1p : b2p);
  void* Cp = zc == 0 ? C0p : (zc == 1 ? C1p : C2p);

  __shared__ u16 Alds[128 * 64];
  __shared__ u16 Blds[128 * 64];

  const int tid = threadIdx.x;
  const int w = tid >> 6, lane = tid & 63;
  const int lr = lane & 15, lg = lane >> 4;
  const int m0 = blockIdx.x * 128, n0 = blockIdx.y * 128;
  const int wr = (w >> 1) * 64, wc = (w & 1) * 64;
  const int brow = lane >> 3;        // row within 8-row chunk
  const int bcol = (lane & 7) * 8;   // k element offset within tile

  f32x4 acc[4][4];
#pragma unroll
  for (int mi = 0; mi < 4; ++mi)
#pragma unroll
    for (int ni = 0; ni < 4; ++ni) {
      f32x4 zv = {0.f, 0.f, 0.f, 0.f};
      acc[mi][ni] = zv;
    }

  const int kper = K / kspl;
  const int ktn = kper >> 6;
  const int kbase = sp * kper;
  for (int kt = 0; kt < ktn; ++kt) {
    const int k0 = kbase + (kt << 6);
    __syncthreads();
    // ---- stage B (always bf16 rows, ld = K) ----
#pragma unroll
    for (int i = 0; i < 4; ++i) {
      const int c = w * 4 + i;
      const int row = c * 8 + brow;
      gl_lds16(Bp + (size_t)(n0 + row) * K + k0 + bcol, &Blds[c * 512]);
    }
    // ---- stage A ----
    if (AMODE == 2) {
      const float* Af = (const float*)Ap;
#pragma unroll
      for (int i = 0; i < 4; ++i) {
        const int c = i * 256 + tid;       // 0..1023
        const int row = c >> 3, k8 = (c & 7) * 8;
        const float* s = Af + (size_t)(m0 + row) * K + k0 + k8;
        f32x4 v0 = *(const f32x4*)s;
        f32x4 v1 = *(const f32x4*)(s + 4);
        u16x8 pk;
        pk[0] = f2b(v0[0]); pk[1] = f2b(v0[1]); pk[2] = f2b(v0[2]); pk[3] = f2b(v0[3]);
        pk[4] = f2b(v1[0]); pk[5] = f2b(v1[1]); pk[6] = f2b(v1[2]); pk[7] = f2b(v1[3]);
        *(u16x8*)&Alds[row * 64 + k8] = pk;
      }
    } else if (AMODE == 0) {
      const u16* Ab = (const u16*)Ap;
#pragma unroll
      for (int i = 0; i < 4; ++i) {
        const int c = w * 4 + i;
        const int row = c * 8 + brow;
        gl_lds16(Ab + (size_t)(m0 + row) * K + k0 + bcol, &Alds[c * 512]);
      }
    } else {  // AMODE 1: conv gather.  m = nn*256 + p ; k = t*1024 + ei
      const u16* Ab = (const u16*)Ap;
#pragma unroll
      for (int i = 0; i < 4; ++i) {
        const int c = w * 4 + i;
        const int m = m0 + c * 8 + brow;
        const int nn = m >> 8, p = m & 255;
        const int k = k0 + bcol;
        gl_lds16(Ab + (size_t)(p * 8 + (k >> 10)) * NE + nn * EDIM + (k & 1023),
                 &Alds[c * 512]);
      }
    }
    __syncthreads();
    // ---- compute ----
#pragma unroll
    for (int ks = 0; ks < 2; ++ks) {
      bf16x8 af[4], bf[4];
#pragma unroll
      for (int mi = 0; mi < 4; ++mi)
        af[mi] = *(const bf16x8*)&Alds[(wr + mi * 16 + lr) * 64 + ks * 32 + lg * 8];
#pragma unroll
      for (int ni = 0; ni < 4; ++ni)
        bf[ni] = *(const bf16x8*)&Blds[(wc + ni * 16 + lr) * 64 + ks * 32 + lg * 8];
#pragma unroll
      for (int mi = 0; mi < 4; ++mi)
#pragma unroll
        for (int ni = 0; ni < 4; ++ni)
          acc[mi][ni] = mfma16(af[mi], bf[ni], acc[mi][ni]);
    }
  }
  // ---- epilogue ----
#pragma unroll
  for (int ni = 0; ni < 4; ++ni) {
    const int col = n0 + wc + ni * 16 + lr;
    const float bv = (OUTMODE == 2) ? 0.f : biasp[col];
#pragma unroll
    for (int mi = 0; mi < 4; ++mi)
#pragma unroll
      for (int j = 0; j < 4; ++j) {
        const int row = m0 + wr + mi * 16 + lg * 4 + j;
        const float v = acc[mi][ni][j] + bv;
        if (OUTMODE == 2)
          ((float*)Cp)[(size_t)sp * M * 1024 + (size_t)row * 1024 + col] = v;
        else if (OUTMODE == 1)
          ((float*)Cp)[(size_t)row * 1024 + col] = v;
        else
          ((u16*)Cp)[(size_t)row * 1024 + col] = f2b(v);
      }
  }
}

// ---------------------------------------------------------------------------
// Fused attention: per block (n, 64 q-rows), loop 16 heads.
// ---------------------------------------------------------------------------
__global__ __launch_bounds__(256)
void attn_fused(const u16* __restrict__ Q, const u16* __restrict__ Kc,
                const u16* __restrict__ Vc, u16* __restrict__ Aout,
                float* __restrict__ AW) {
  __shared__ u16 klds[256 * 64];   // [p][d]  swizzled
  __shared__ u16 vlds[64 * 256];   // [d][p]  swizzled (transposed V)
  __shared__ u16 plds[4][16 * 256];// per-wave P [r][p] swizzled
  const int tid = threadIdx.x;
  const int w = tid >> 6, lane = tid & 63;
  const int lr = lane & 15, lg = lane >> 4;
  const int n = blockIdx.y;
  const int l0 = blockIdx.x * 64;
  const int lrow = l0 + w * 16 + lr;

  char* kbase = (char*)klds;
  char* vbase = (char*)vlds;
  char* pbase = (char*)&plds[w][0];

  f32x4 macc[16];
#pragma unroll
  for (int ni = 0; ni < 16; ++ni) { f32x4 zv = {0.f,0.f,0.f,0.f}; macc[ni] = zv; }

  for (int h = 0; h < HNUM; ++h) {
    __syncthreads();  // previous head fully consumed LDS
    // ---- stage K (swizzled rows) and V (transposed, swizzled) ----
    for (int it = 0; it < 8; ++it) {
      int c = it * 256 + tid;          // 0..2047 : p = c>>3, 16B chunk c&7
      int p = c >> 3, c16 = c & 7;
      size_t goff = (size_t)n * (KPDIM * EDIM) + (size_t)p * EDIM + h * DDIM + c16 * 8;
      i32x4 kd = *(const i32x4*)(Kc + goff);
      *(i32x4*)(kbase + p * 128 + ((c16 * 16) ^ ((p & 7) << 4))) = kd;
      i32x4 vd = *(const i32x4*)(Vc + goff);
      u16x8 vv = __builtin_bit_cast(u16x8, vd);
#pragma unroll
      for (int j = 0; j < 8; ++j) {
        int d = c16 * 8 + j;
        *(u16*)(vbase + d * 512 + ((p * 2) ^ ((d & 7) << 4))) = vv[j];
      }
    }
    // ---- q fragments ----
    const u16* qp = Q + (size_t)lrow * NE + n * EDIM + h * DDIM + lg * 8;
    bf16x8 aq0 = *(const bf16x8*)qp;
    bf16x8 aq1 = *(const bf16x8*)(qp + 32);
    __syncthreads();
    // ---- S = q @ k^T ----
    f32x4 s[16];
#pragma unroll
    for (int ni = 0; ni < 16; ++ni) { f32x4 zv = {0.f,0.f,0.f,0.f}; s[ni] = zv; }
#pragma unroll
    for (int ni = 0; ni < 16; ++ni) {
      int row = ni * 16 + lr;
      const char* kr = kbase + row * 128;
      bf16x8 b0 = *(const bf16x8*)(kr + ((16 * lg) ^ ((row & 7) << 4)));
      bf16x8 b1 = *(const bf16x8*)(kr + ((64 + 16 * lg) ^ ((row & 7) << 4)));
      s[ni] = mfma16(aq0, b0, s[ni]);
      s[ni] = mfma16(aq1, b1, s[ni]);
    }
    // ---- softmax ----
    float mx[4], sm[4], inv[4];
#pragma unroll
    for (int j = 0; j < 4; ++j) mx[j] = -1e30f;
#pragma unroll
    for (int ni = 0; ni < 16; ++ni)
#pragma unroll
      for (int j = 0; j < 4; ++j) mx[j] = fmaxf(mx[j], s[ni][j]);
#pragma unroll
    for (int msk = 1; msk <= 8; msk <<= 1)
#pragma unroll
      for (int j = 0; j < 4; ++j) mx[j] = fmaxf(mx[j], __shfl_xor(mx[j], msk, 64));
#pragma unroll
    for (int j = 0; j < 4; ++j) sm[j] = 0.f;
#pragma unroll
    for (int ni = 0; ni < 16; ++ni)
#pragma unroll
      for (int j = 0; j < 4; ++j) {
        float e = __expf(s[ni][j] - mx[j]);
        s[ni][j] = e; sm[j] += e;
      }
#pragma unroll
    for (int msk = 1; msk <= 8; msk <<= 1)
#pragma unroll
      for (int j = 0; j < 4; ++j) sm[j] += __shfl_xor(sm[j], msk, 64);
#pragma unroll
    for (int j = 0; j < 4; ++j) inv[j] = 1.0f / sm[j];
    // ---- normalize, head-mean, store P (bf16, swizzled) ----
#pragma unroll
    for (int ni = 0; ni < 16; ++ni)
#pragma unroll
      for (int j = 0; j < 4; ++j) {
        float pv = s[ni][j] * inv[j];
        macc[ni][j] += pv * 0.0625f;
        int r = lg * 4 + j;
        *(u16*)(pbase + r * 512 + ((ni * 32 + lr * 2) ^ ((r & 7) << 4))) = f2b(pv);
      }
    __syncthreads();
    // ---- O = P @ V ----
    f32x4 o[4];
#pragma unroll
    for (int ni2 = 0; ni2 < 4; ++ni2) { f32x4 zv = {0.f,0.f,0.f,0.f}; o[ni2] = zv; }
#pragma unroll
    for (int ks = 0; ks < 8; ++ks) {
      bf16x8 a = *(const bf16x8*)(pbase + lr * 512 + ((ks * 64 + 16 * lg) ^ ((lr & 7) << 4)));
#pragma unroll
      for (int ni2 = 0; ni2 < 4; ++ni2) {
        int d = ni2 * 16 + lr;
        bf16x8 b = *(const bf16x8*)(vbase + d * 512 + ((ks * 64 + 16 * lg) ^ ((d & 7) << 4)));
        o[ni2] = mfma16(a, b, o[ni2]);
      }
    }
    // ---- write O tile ----
#pragma unroll
    for (int ni2 = 0; ni2 < 4; ++ni2)
#pragma unroll
      for (int j = 0; j < 4; ++j) {
        int gl = l0 + w * 16 + lg * 4 + j;
        Aout[(size_t)gl * NE + n * EDIM + h * DDIM + ni2 * 16 + lr] = f2b(o[ni2][j]);
      }
  }
  // ---- write head-mean attention weights ----
#pragma unroll
  for (int ni = 0; ni < 16; ++ni)
#pragma unroll
    for (int j = 0; j < 4; ++j) {
      int r = lg * 4 + j;
      AW[(size_t)n * (LSEQ * KPDIM) + (size_t)(l0 + w * 16 + r) * KPDIM + ni * 16 + lr]
          = macc[ni][j];
    }
}

// ---------------------------------------------------------------------------
extern "C" void kernel_launch(void* const* d_in, const int* in_sizes, int n_in,
                              void* d_out, int out_size, void* d_ws, size_t ws_size,
                              hipStream_t stream) {
  const float* query = (const float*)d_in[0];
  const float* key   = (const float*)d_in[1];
  const float* value = (const float*)d_in[2];
  const float* ipw   = (const float*)d_in[3];
  const float* ipb   = (const float*)d_in[4];
  const float* ew    = (const float*)d_in[5];
  const float* eb    = (const float*)d_in[6];
  const float* fw    = (const float*)d_in[7];
  const float* fb    = (const float*)d_in[8];
  const float* ow    = (const float*)d_in[9];
  const float* ob    = (const float*)d_in[10];

  char* ws = (char*)d_ws;
  size_t off = 0;
  auto alloc = [&](size_t bytes) {
    void* p = ws + off;
    off += (bytes + 255) & ~(size_t)255;
    return p;
  };
  u16* qp    = (u16*)alloc((size_t)MROWS * EDIM * 2);
  u16* kp    = (u16*)alloc((size_t)MROWS * EDIM * 2);
  u16* vp    = (u16*)alloc((size_t)MROWS * EDIM * 2);
  u16* ao    = (u16*)alloc((size_t)MROWS * EDIM * 2);
  u16* kc    = (u16*)alloc((size_t)NB * KPDIM * EDIM * 2);
  u16* vc    = (u16*)alloc((size_t)NB * KPDIM * EDIM * 2);
  u16* w_in  = (u16*)alloc((size_t)3 * EDIM * EDIM * 2);
  u16* w_eT  = (u16*)alloc((size_t)EDIM * 8 * EDIM * 2);
  u16* w_fT  = (u16*)alloc((size_t)EDIM * 8 * EDIM * 2);
  u16* w_out = (u16*)alloc((size_t)EDIM * EDIM * 2);
  float* bq  = (float*)alloc(EDIM * 4);
  size_t base_needed = off;

  // X region: qkv16 (100.7 MB) aliased with split-K partials (64 MB) —
  // qkv16 is dead before the compress GEMM writes partials.
  size_t qkv16_b = (size_t)3 * MROWS * EDIM * 2;     // 100.7 MB
  size_t part_b  = (size_t)2 * 4 * 2048 * 1024 * 4;  // 64 MB
  bool bigX  = ws_size >= base_needed + qkv16_b;     // prepass + split-K
  bool midX  = ws_size >= base_needed + part_b;      // split-K only
  char* X = (char*)alloc(bigX ? qkv16_b : (midX ? part_b : 0));
  u16* qkv16 = (u16*)X;
  float* part = (float*)X;

  float* out_f = (float*)d_out;                        // (L, N, E)
  float* aw_f  = (float*)d_out + (size_t)MROWS * EDIM; // (N, L, Kp)

  // weight prep
  wconv<<<dim3(3072), 256, 0, stream>>>(ipw, w_in, 786432, 262144, 0.125f);
  wconv<<<dim3(1024), 256, 0, stream>>>(ow, w_out, 262144, 0, 1.0f);
  wtrans<<<dim3(16384, 2), 64, 0, stream>>>(ew, fw, w_eT, w_fT);
  bscale<<<dim3(4), 256, 0, stream>>>(ipb, bq);

  // q/k/v projections
  if (bigX) {
    castqkv<<<dim3(8192, 3), 256, 0, stream>>>(query, key, value, qkv16);
    gemm_bt<0, 0><<<dim3(128, 8, 3), 256, 0, stream>>>(
        qkv16, qkv16 + (size_t)MROWS * EDIM, qkv16 + (size_t)2 * MROWS * EDIM,
        w_in, w_in + 1048576, w_in + 2097152,
        bq, ipb + 1024, ipb + 2048,
        qp, kp, vp, MROWS, 1024, 1);
  } else {
    gemm_bt<2, 0><<<dim3(128, 8, 3), 256, 0, stream>>>(
        query, key, value,
        w_in, w_in + 1048576, w_in + 2097152,
        bq, ipb + 1024, ipb + 2048,
        qp, kp, vp, MROWS, 1024, 1);
  }

  // conv compression of k and v
  if (bigX || midX) {
    // split-K x4 -> f32 partials -> reduce
    gemm_bt<1, 2><<<dim3(16, 8, 8), 256, 0, stream>>>(
        kp, vp, vp,
        w_eT, w_fT, w_fT,
        eb, fb, fb,
        part, part + (size_t)4 * 2048 * 1024, part,
        NB * KPDIM, 8192, 4);
    redc<<<dim3(2048, 2), 256, 0, stream>>>(part, eb, fb, kc, vc);
  } else {
    gemm_bt<1, 0><<<dim3(16, 8, 2), 256, 0, stream>>>(
        kp, vp, vp,
        w_eT, w_fT, w_fT,
        eb, fb, fb,
        kc, vc, vc, NB * KPDIM, 8192, 1);
  }

  // fused attention + head-mean weights
  attn_fused<<<dim3(32, 8), 256, 0, stream>>>(qp, kc, vc, ao, aw_f);

  // output projection -> f32 d_out
  gemm_bt<0, 1><<<dim3(128, 8, 1), 256, 0, stream>>>(
      ao, ao, ao,
      w_out, w_out, w_out,
      ob, ob, ob,
      out_f, out_f, out_f, MROWS, 1024, 1);
}

// Round 3
// 540.370 us; speedup vs baseline: 1.2604x; 1.1455x over previous
//
#include <hip/hip_runtime.h>

typedef unsigned short u16;
typedef u16  u16x4 __attribute__((ext_vector_type(4)));
typedef u16  u16x8 __attribute__((ext_vector_type(8)));
typedef float f32x4 __attribute__((ext_vector_type(4)));
typedef int   i32x4 __attribute__((ext_vector_type(4)));
typedef __bf16 bf16x8 __attribute__((ext_vector_type(8)));

#define LSEQ 2048
#define NB 8
#define EDIM 1024
#define HNUM 16
#define DDIM 64
#define KPDIM 256
#define NE (NB*EDIM)       /* 8192 */
#define MROWS (LSEQ*NB)    /* 16384 */

__device__ __forceinline__ u16 f2b(float f) {
  unsigned u = __builtin_bit_cast(unsigned, f);
  u += 0x7fffu + ((u >> 16) & 1u);
  return (u16)(u >> 16);
}

__device__ __forceinline__ void gl_lds16(const void* g, void* l) {
  __builtin_amdgcn_global_load_lds(
      (const __attribute__((address_space(1))) void*)g,
      (__attribute__((address_space(3))) void*)l, 16, 0, 0);
}

__device__ __forceinline__ f32x4 mfma16(bf16x8 a, bf16x8 b, f32x4 c) {
  return __builtin_amdgcn_mfma_f32_16x16x32_bf16(a, b, c, 0, 0, 0);
}

// ---------------------------------------------------------------------------
// Weight prep kernels
// ---------------------------------------------------------------------------
__global__ void wconv(const float* __restrict__ src, u16* __restrict__ dst,
                      int n4, int scale_n4, float sc) {
  int i = blockIdx.x * blockDim.x + threadIdx.x;
  if (i >= n4) return;
  f32x4 v = ((const f32x4*)src)[i];
  float s = (i < scale_n4) ? sc : 1.0f;
  u16x4 o;
  o[0] = f2b(v[0] * s); o[1] = f2b(v[1] * s);
  o[2] = f2b(v[2] * s); o[3] = f2b(v[3] * s);
  ((u16x4*)dst)[i] = o;
}

// (O, I, 8) f32  ->  (O, t*E + i) bf16   (per-wave LDS transpose)
__global__ void wtrans(const float* __restrict__ ew, const float* __restrict__ fw,
                       u16* __restrict__ eT, u16* __restrict__ fT) {
  const float* src = blockIdx.y ? fw : ew;
  u16* dst = blockIdx.y ? fT : eT;
  int eo = blockIdx.x >> 4;
  int ei0 = (blockIdx.x & 15) * 64;
  int l = threadIdx.x;
  __shared__ u16 lds[8][64];
  const float* s = src + (size_t)eo * 8192 + (size_t)ei0 * 8 + l * 8;
  f32x4 a = *(const f32x4*)s;
  f32x4 b = *(const f32x4*)(s + 4);
  float v[8] = {a[0], a[1], a[2], a[3], b[0], b[1], b[2], b[3]};
#pragma unroll
  for (int t = 0; t < 8; ++t) lds[t][l] = f2b(v[t]);
  __syncthreads();
  int t = l >> 3, c = l & 7;
  i32x4 out = *(const i32x4*)&lds[t][c * 8];
  *(i32x4*)(dst + (size_t)eo * 8192 + t * 1024 + ei0 + c * 8) = out;
}

__global__ void bscale(const float* __restrict__ b, float* __restrict__ out) {
  int i = blockIdx.x * blockDim.x + threadIdx.x;
  if (i < EDIM) out[i] = b[i] * 0.125f;
}

// q/k/v f32 -> bf16, contiguous [3][MROWS][E]
__global__ void castqkv(const float* __restrict__ q, const float* __restrict__ k,
                        const float* __restrict__ v, u16* __restrict__ out) {
  const float* src = blockIdx.y == 0 ? q : (blockIdx.y == 1 ? k : v);
  size_t base = (size_t)blockIdx.y * ((size_t)MROWS * EDIM);
  size_t i = ((size_t)blockIdx.x * 256 + threadIdx.x) * 8;
  f32x4 v0 = *(const f32x4*)(src + i);
  f32x4 v1 = *(const f32x4*)(src + i + 4);
  u16x8 o;
  o[0] = f2b(v0[0]); o[1] = f2b(v0[1]); o[2] = f2b(v0[2]); o[3] = f2b(v0[3]);
  o[4] = f2b(v1[0]); o[5] = f2b(v1[1]); o[6] = f2b(v1[2]); o[7] = f2b(v1[3]);
  *(u16x8*)(out + base + i) = o;
}

// sum 4 split-K partials + bias -> bf16
__global__ void redc(const float* __restrict__ part, const float* __restrict__ eb,
                     const float* __restrict__ fb, u16* __restrict__ kc,
                     u16* __restrict__ vc) {
  int zc = blockIdx.y;
  const float* p = part + (size_t)zc * 4 * 2048 * 1024;
  u16* out = zc ? vc : kc;
  const float* bias = zc ? fb : eb;
  size_t i = ((size_t)blockIdx.x * 256 + threadIdx.x) * 4;
  f32x4 s = *(const f32x4*)(p + i);
  s += *(const f32x4*)(p + 2097152 + i);
  s += *(const f32x4*)(p + 2 * 2097152 + i);
  s += *(const f32x4*)(p + 3 * 2097152 + i);
  int col = (int)(i & 1023);
  f32x4 b = *(const f32x4*)(bias + col);
  u16x4 o;
  o[0] = f2b(s[0] + b[0]); o[1] = f2b(s[1] + b[1]);
  o[2] = f2b(s[2] + b[2]); o[3] = f2b(s[3] + b[3]);
  *(u16x4*)(out + i) = o;
}

// ---------------------------------------------------------------------------
// 256x256 double-buffered 2-phase GEMM: C[m,o] = sum_k A[m,k]*B[o,k] (+bias)
//   AMODE 0: A bf16 rows contiguous (ld=K); AMODE 1: conv-gather
//   OUTMODE 0: bf16 C + bias; 1: f32 C + bias; 2: f32 split-K partial
// grid = (M/256, N/256, nz*kspl); block = 512 (8 waves, 2M x 4N)
// LDS 128 KiB (2 bufs x (A 32K + B 32K)); 1 block/CU.
// Schedule: stage(t+1 -> buf^1) issued BEFORE compute(t from buf);
// single __syncthreads per K-tile provides the vmcnt(0)+lgkmcnt(0) drain
// AFTER the 64-MFMA compute phase, so staging latency hides under MFMA.
// ---------------------------------------------------------------------------
template<int AMODE, int OUTMODE>
__global__ __launch_bounds__(512, 2)
void gemm256(const void* A0p, const void* A1p, const void* A2p,
             const u16* B0p, const u16* B1p, const u16* B2p,
             const float* b0p, const float* b1p, const float* b2p,
             void* C0p, void* C1p, void* C2p,
             int M, int K, int kspl) {
  const int zc = blockIdx.z / kspl, sp = blockIdx.z % kspl;
  const void* Ap = zc == 0 ? A0p : (zc == 1 ? A1p : A2p);
  const u16* Bp = zc == 0 ? B0p : (zc == 1 ? B1p : B2p);
  const float* biasp = zc == 0 ? b0p : (zc == 1 ? b1p : b2p);
  void* Cp = zc == 0 ? C0p : (zc == 1 ? C1p : C2p);

  __shared__ u16 lds[2][2][256 * 64];   // [buf][A=0/B=1][row*64+k]

  const int tid = threadIdx.x;
  const int w = tid >> 6, lane = tid & 63;
  const int lr = lane & 15, lg = lane >> 4;
  const int wr = w >> 2, wc = w & 3;            // 2M x 4N waves
  const int m0 = blockIdx.x * 256, n0 = blockIdx.y * 256;
  const int kper = K / kspl, kbase = sp * kper, nt = kper >> 6;

  f32x4 acc[8][4];
#pragma unroll
  for (int mi = 0; mi < 8; ++mi)
#pragma unroll
    for (int ni = 0; ni < 4; ++ni) {
      f32x4 zv = {0.f, 0.f, 0.f, 0.f};
      acc[mi][ni] = zv;
    }

  auto stage = [&](int buf, int k0) {
    // B: 256 rows x 64 k, 4 x 16B per thread, linear LDS
#pragma unroll
    for (int i = 0; i < 4; ++i) {
      int c = i * 512 + tid;                 // 0..2047
      int row = c >> 3, k8 = (c & 7) * 8;
      gl_lds16(Bp + (size_t)(n0 + row) * K + k0 + k8, &lds[buf][1][c * 8]);
    }
    if (AMODE == 0) {
      const u16* Ab = (const u16*)Ap;
#pragma unroll
      for (int i = 0; i < 4; ++i) {
        int c = i * 512 + tid;
        int row = c >> 3, k8 = (c & 7) * 8;
        gl_lds16(Ab + (size_t)(m0 + row) * K + k0 + k8, &lds[buf][0][c * 8]);
      }
    } else {  // conv gather: m=(nn,p), k=(t,ei)
      const u16* Ab = (const u16*)Ap;
#pragma unroll
      for (int i = 0; i < 4; ++i) {
        int c = i * 512 + tid;
        int row = c >> 3, k8 = (c & 7) * 8;
        int m = m0 + row;
        int nn = m >> 8, p = m & 255;
        int k = k0 + k8;
        gl_lds16(Ab + (size_t)(p * 8 + (k >> 10)) * NE + nn * EDIM + (k & 1023),
                 &lds[buf][0][c * 8]);
      }
    }
  };

  auto compute = [&](const u16* As, const u16* Bs) {
#pragma unroll
    for (int ks = 0; ks < 2; ++ks) {
      bf16x8 af[8], bfr[4];
#pragma unroll
      for (int mi = 0; mi < 8; ++mi)
        af[mi] = *(const bf16x8*)&As[(wr * 128 + mi * 16 + lr) * 64 + ks * 32 + lg * 8];
#pragma unroll
      for (int ni = 0; ni < 4; ++ni)
        bfr[ni] = *(const bf16x8*)&Bs[(wc * 64 + ni * 16 + lr) * 64 + ks * 32 + lg * 8];
#pragma unroll
      for (int mi = 0; mi < 8; ++mi)
#pragma unroll
        for (int ni = 0; ni < 4; ++ni)
          acc[mi][ni] = mfma16(af[mi], bfr[ni], acc[mi][ni]);
    }
  };

  stage(0, kbase);
  __syncthreads();
  int cur = 0;
  for (int kt = 0; kt < nt; ++kt) {
    if (kt + 1 < nt) stage(cur ^ 1, kbase + ((kt + 1) << 6));
    compute(&lds[cur][0][0], &lds[cur][1][0]);
    __syncthreads();
    cur ^= 1;
  }

  // ---- epilogue ----
#pragma unroll
  for (int ni = 0; ni < 4; ++ni) {
    const int col = n0 + wc * 64 + ni * 16 + lr;
    const float bv = (OUTMODE == 2) ? 0.f : biasp[col];
#pragma unroll
    for (int mi = 0; mi < 8; ++mi)
#pragma unroll
      for (int j = 0; j < 4; ++j) {
        const int row = m0 + wr * 128 + mi * 16 + lg * 4 + j;
        const float v = acc[mi][ni][j] + bv;
        if (OUTMODE == 2)
          ((float*)Cp)[(size_t)sp * M * 1024 + (size_t)row * 1024 + col] = v;
        else if (OUTMODE == 1)
          ((float*)Cp)[(size_t)row * 1024 + col] = v;
        else
          ((u16*)Cp)[(size_t)row * 1024 + col] = f2b(v);
      }
  }
}

// ---------------------------------------------------------------------------
// Legacy 128x128 GEMM — fallback paths only (small workspace)
// ---------------------------------------------------------------------------
template<int AMODE, int OUTMODE>
__global__ __launch_bounds__(256)
void gemm_bt(const void* A0p, const void* A1p, const void* A2p,
             const u16* B0p, const u16* B1p, const u16* B2p,
             const float* b0p, const float* b1p, const float* b2p,
             void* C0p, void* C1p, void* C2p,
             int M, int K, int kspl) {
  const int zc = blockIdx.z / kspl, sp = blockIdx.z % kspl;
  const void* Ap = zc == 0 ? A0p : (zc == 1 ? A1p : A2p);
  const u16* Bp = zc == 0 ? B0p : (zc == 1 ? B1p : B2p);
  const float* biasp = zc == 0 ? b0p : (zc == 1 ? b1p : b2p);
  void* Cp = zc == 0 ? C0p : (zc == 1 ? C1p : C2p);

  __shared__ u16 Alds[128 * 64];
  __shared__ u16 Blds[128 * 64];

  const int tid = threadIdx.x;
  const int w = tid >> 6, lane = tid & 63;
  const int lr = lane & 15, lg = lane >> 4;
  const int m0 = blockIdx.x * 128, n0 = blockIdx.y * 128;
  const int wr = (w >> 1) * 64, wc = (w & 1) * 64;
  const int brow = lane >> 3;
  const int bcol = (lane & 7) * 8;

  f32x4 acc[4][4];
#pragma unroll
  for (int mi = 0; mi < 4; ++mi)
#pragma unroll
    for (int ni = 0; ni < 4; ++ni) {
      f32x4 zv = {0.f, 0.f, 0.f, 0.f};
      acc[mi][ni] = zv;
    }

  const int kper = K / kspl;
  const int ktn = kper >> 6;
  const int kbase = sp * kper;
  for (int kt = 0; kt < ktn; ++kt) {
    const int k0 = kbase + (kt << 6);
    __syncthreads();
#pragma unroll
    for (int i = 0; i < 4; ++i) {
      const int c = w * 4 + i;
      const int row = c * 8 + brow;
      gl_lds16(Bp + (size_t)(n0 + row) * K + k0 + bcol, &Blds[c * 512]);
    }
    if (AMODE == 2) {
      const float* Af = (const float*)Ap;
#pragma unroll
      for (int i = 0; i < 4; ++i) {
        const int c = i * 256 + tid;
        const int row = c >> 3, k8 = (c & 7) * 8;
        const float* s = Af + (size_t)(m0 + row) * K + k0 + k8;
        f32x4 v0 = *(const f32x4*)s;
        f32x4 v1 = *(const f32x4*)(s + 4);
        u16x8 pk;
        pk[0] = f2b(v0[0]); pk[1] = f2b(v0[1]); pk[2] = f2b(v0[2]); pk[3] = f2b(v0[3]);
        pk[4] = f2b(v1[0]); pk[5] = f2b(v1[1]); pk[6] = f2b(v1[2]); pk[7] = f2b(v1[3]);
        *(u16x8*)&Alds[row * 64 + k8] = pk;
      }
    } else if (AMODE == 0) {
      const u16* Ab = (const u16*)Ap;
#pragma unroll
      for (int i = 0; i < 4; ++i) {
        const int c = w * 4 + i;
        const int row = c * 8 + brow;
        gl_lds16(Ab + (size_t)(m0 + row) * K + k0 + bcol, &Alds[c * 512]);
      }
    } else {
      const u16* Ab = (const u16*)Ap;
#pragma unroll
      for (int i = 0; i < 4; ++i) {
        const int c = w * 4 + i;
        const int m = m0 + c * 8 + brow;
        const int nn = m >> 8, p = m & 255;
        const int k = k0 + bcol;
        gl_lds16(Ab + (size_t)(p * 8 + (k >> 10)) * NE + nn * EDIM + (k & 1023),
                 &Alds[c * 512]);
      }
    }
    __syncthreads();
#pragma unroll
    for (int ks = 0; ks < 2; ++ks) {
      bf16x8 af[4], bf[4];
#pragma unroll
      for (int mi = 0; mi < 4; ++mi)
        af[mi] = *(const bf16x8*)&Alds[(wr + mi * 16 + lr) * 64 + ks * 32 + lg * 8];
#pragma unroll
      for (int ni = 0; ni < 4; ++ni)
        bf[ni] = *(const bf16x8*)&Blds[(wc + ni * 16 + lr) * 64 + ks * 32 + lg * 8];
#pragma unroll
      for (int mi = 0; mi < 4; ++mi)
#pragma unroll
        for (int ni = 0; ni < 4; ++ni)
          acc[mi][ni] = mfma16(af[mi], bf[ni], acc[mi][ni]);
    }
  }
#pragma unroll
  for (int ni = 0; ni < 4; ++ni) {
    const int col = n0 + wc + ni * 16 + lr;
    const float bv = (OUTMODE == 2) ? 0.f : biasp[col];
#pragma unroll
    for (int mi = 0; mi < 4; ++mi)
#pragma unroll
      for (int j = 0; j < 4; ++j) {
        const int row = m0 + wr + mi * 16 + lg * 4 + j;
        const float v = acc[mi][ni][j] + bv;
        if (OUTMODE == 2)
          ((float*)Cp)[(size_t)sp * M * 1024 + (size_t)row * 1024 + col] = v;
        else if (OUTMODE == 1)
          ((float*)Cp)[(size_t)row * 1024 + col] = v;
        else
          ((u16*)Cp)[(size_t)row * 1024 + col] = f2b(v);
      }
  }
}

// ---------------------------------------------------------------------------
// Fused attention: per block (n, 64 q-rows), loop 16 heads.
// ---------------------------------------------------------------------------
__global__ __launch_bounds__(256)
void attn_fused(const u16* __restrict__ Q, const u16* __restrict__ Kc,
                const u16* __restrict__ Vc, u16* __restrict__ Aout,
                float* __restrict__ AW) {
  __shared__ u16 klds[256 * 64];   // [p][d]  swizzled
  __shared__ u16 vlds[64 * 256];   // [d][p]  swizzled (transposed V)
  __shared__ u16 plds[4][16 * 256];// per-wave P [r][p] swizzled
  const int tid = threadIdx.x;
  const int w = tid >> 6, lane = tid & 63;
  const int lr = lane & 15, lg = lane >> 4;
  const int n = blockIdx.y;
  const int l0 = blockIdx.x * 64;
  const int lrow = l0 + w * 16 + lr;

  char* kbase = (char*)klds;
  char* vbase = (char*)vlds;
  char* pbase = (char*)&plds[w][0];

  f32x4 macc[16];
#pragma unroll
  for (int ni = 0; ni < 16; ++ni) { f32x4 zv = {0.f,0.f,0.f,0.f}; macc[ni] = zv; }

  for (int h = 0; h < HNUM; ++h) {
    __syncthreads();
    for (int it = 0; it < 8; ++it) {
      int c = it * 256 + tid;
      int p = c >> 3, c16 = c & 7;
      size_t goff = (size_t)n * (KPDIM * EDIM) + (size_t)p * EDIM + h * DDIM + c16 * 8;
      i32x4 kd = *(const i32x4*)(Kc + goff);
      *(i32x4*)(kbase + p * 128 + ((c16 * 16) ^ ((p & 7) << 4))) = kd;
      i32x4 vd = *(const i32x4*)(Vc + goff);
      u16x8 vv = __builtin_bit_cast(u16x8, vd);
#pragma unroll
      for (int j = 0; j < 8; ++j) {
        int d = c16 * 8 + j;
        *(u16*)(vbase + d * 512 + ((p * 2) ^ ((d & 7) << 4))) = vv[j];
      }
    }
    const u16* qp = Q + (size_t)lrow * NE + n * EDIM + h * DDIM + lg * 8;
    bf16x8 aq0 = *(const bf16x8*)qp;
    bf16x8 aq1 = *(const bf16x8*)(qp + 32);
    __syncthreads();
    f32x4 s[16];
#pragma unroll
    for (int ni = 0; ni < 16; ++ni) { f32x4 zv = {0.f,0.f,0.f,0.f}; s[ni] = zv; }
#pragma unroll
    for (int ni = 0; ni < 16; ++ni) {
      int row = ni * 16 + lr;
      const char* kr = kbase + row * 128;
      bf16x8 b0 = *(const bf16x8*)(kr + ((16 * lg) ^ ((row & 7) << 4)));
      bf16x8 b1 = *(const bf16x8*)(kr + ((64 + 16 * lg) ^ ((row & 7) << 4)));
      s[ni] = mfma16(aq0, b0, s[ni]);
      s[ni] = mfma16(aq1, b1, s[ni]);
    }
    float mx[4], sm[4], inv[4];
#pragma unroll
    for (int j = 0; j < 4; ++j) mx[j] = -1e30f;
#pragma unroll
    for (int ni = 0; ni < 16; ++ni)
#pragma unroll
      for (int j = 0; j < 4; ++j) mx[j] = fmaxf(mx[j], s[ni][j]);
#pragma unroll
    for (int msk = 1; msk <= 8; msk <<= 1)
#pragma unroll
      for (int j = 0; j < 4; ++j) mx[j] = fmaxf(mx[j], __shfl_xor(mx[j], msk, 64));
#pragma unroll
    for (int j = 0; j < 4; ++j) sm[j] = 0.f;
#pragma unroll
    for (int ni = 0; ni < 16; ++ni)
#pragma unroll
      for (int j = 0; j < 4; ++j) {
        float e = __expf(s[ni][j] - mx[j]);
        s[ni][j] = e; sm[j] += e;
      }
#pragma unroll
    for (int msk = 1; msk <= 8; msk <<= 1)
#pragma unroll
      for (int j = 0; j < 4; ++j) sm[j] += __shfl_xor(sm[j], msk, 64);
#pragma unroll
    for (int j = 0; j < 4; ++j) inv[j] = 1.0f / sm[j];
#pragma unroll
    for (int ni = 0; ni < 16; ++ni)
#pragma unroll
      for (int j = 0; j < 4; ++j) {
        float pv = s[ni][j] * inv[j];
        macc[ni][j] += pv * 0.0625f;
        int r = lg * 4 + j;
        *(u16*)(pbase + r * 512 + ((ni * 32 + lr * 2) ^ ((r & 7) << 4))) = f2b(pv);
      }
    __syncthreads();
    f32x4 o[4];
#pragma unroll
    for (int ni2 = 0; ni2 < 4; ++ni2) { f32x4 zv = {0.f,0.f,0.f,0.f}; o[ni2] = zv; }
#pragma unroll
    for (int ks = 0; ks < 8; ++ks) {
      bf16x8 a = *(const bf16x8*)(pbase + lr * 512 + ((ks * 64 + 16 * lg) ^ ((lr & 7) << 4)));
#pragma unroll
      for (int ni2 = 0; ni2 < 4; ++ni2) {
        int d = ni2 * 16 + lr;
        bf16x8 b = *(const bf16x8*)(vbase + d * 512 + ((ks * 64 + 16 * lg) ^ ((d & 7) << 4)));
        o[ni2] = mfma16(a, b, o[ni2]);
      }
    }
#pragma unroll
    for (int ni2 = 0; ni2 < 4; ++ni2)
#pragma unroll
      for (int j = 0; j < 4; ++j) {
        int gl = l0 + w * 16 + lg * 4 + j;
        Aout[(size_t)gl * NE + n * EDIM + h * DDIM + ni2 * 16 + lr] = f2b(o[ni2][j]);
      }
  }
#pragma unroll
  for (int ni = 0; ni < 16; ++ni)
#pragma unroll
    for (int j = 0; j < 4; ++j) {
      int r = lg * 4 + j;
      AW[(size_t)n * (LSEQ * KPDIM) + (size_t)(l0 + w * 16 + r) * KPDIM + ni * 16 + lr]
          = macc[ni][j];
    }
}

// ---------------------------------------------------------------------------
extern "C" void kernel_launch(void* const* d_in, const int* in_sizes, int n_in,
                              void* d_out, int out_size, void* d_ws, size_t ws_size,
                              hipStream_t stream) {
  const float* query = (const float*)d_in[0];
  const float* key   = (const float*)d_in[1];
  const float* value = (const float*)d_in[2];
  const float* ipw   = (const float*)d_in[3];
  const float* ipb   = (const float*)d_in[4];
  const float* ew    = (const float*)d_in[5];
  const float* eb    = (const float*)d_in[6];
  const float* fw    = (const float*)d_in[7];
  const float* fb    = (const float*)d_in[8];
  const float* ow    = (const float*)d_in[9];
  const float* ob    = (const float*)d_in[10];

  char* ws = (char*)d_ws;
  size_t off = 0;
  auto alloc = [&](size_t bytes) {
    void* p = ws + off;
    off += (bytes + 255) & ~(size_t)255;
    return p;
  };
  u16* qp    = (u16*)alloc((size_t)MROWS * EDIM * 2);
  u16* kp    = (u16*)alloc((size_t)MROWS * EDIM * 2);
  u16* vp    = (u16*)alloc((size_t)MROWS * EDIM * 2);
  u16* ao    = (u16*)alloc((size_t)MROWS * EDIM * 2);
  u16* kc    = (u16*)alloc((size_t)NB * KPDIM * EDIM * 2);
  u16* vc    = (u16*)alloc((size_t)NB * KPDIM * EDIM * 2);
  u16* w_in  = (u16*)alloc((size_t)3 * EDIM * EDIM * 2);
  u16* w_eT  = (u16*)alloc((size_t)EDIM * 8 * EDIM * 2);
  u16* w_fT  = (u16*)alloc((size_t)EDIM * 8 * EDIM * 2);
  u16* w_out = (u16*)alloc((size_t)EDIM * EDIM * 2);
  float* bq  = (float*)alloc(EDIM * 4);
  size_t base_needed = off;

  // X region: qkv16 (100.7 MB) aliased with split-K partials (64 MB)
  size_t qkv16_b = (size_t)3 * MROWS * EDIM * 2;
  size_t part_b  = (size_t)2 * 4 * 2048 * 1024 * 4;
  bool bigX  = ws_size >= base_needed + qkv16_b;
  bool midX  = ws_size >= base_needed + part_b;
  char* X = (char*)alloc(bigX ? qkv16_b : (midX ? part_b : 0));
  u16* qkv16 = (u16*)X;
  float* part = (float*)X;

  float* out_f = (float*)d_out;                        // (L, N, E)
  float* aw_f  = (float*)d_out + (size_t)MROWS * EDIM; // (N, L, Kp)

  // weight prep
  wconv<<<dim3(3072), 256, 0, stream>>>(ipw, w_in, 786432, 262144, 0.125f);
  wconv<<<dim3(1024), 256, 0, stream>>>(ow, w_out, 262144, 0, 1.0f);
  wtrans<<<dim3(16384, 2), 64, 0, stream>>>(ew, fw, w_eT, w_fT);
  bscale<<<dim3(4), 256, 0, stream>>>(ipb, bq);

  // q/k/v projections
  if (bigX) {
    castqkv<<<dim3(8192, 3), 256, 0, stream>>>(query, key, value, qkv16);
    gemm256<0, 0><<<dim3(64, 4, 3), 512, 0, stream>>>(
        qkv16, qkv16 + (size_t)MROWS * EDIM, qkv16 + (size_t)2 * MROWS * EDIM,
        w_in, w_in + 1048576, w_in + 2097152,
        bq, ipb + 1024, ipb + 2048,
        qp, kp, vp, MROWS, 1024, 1);
  } else {
    gemm_bt<2, 0><<<dim3(128, 8, 3), 256, 0, stream>>>(
        query, key, value,
        w_in, w_in + 1048576, w_in + 2097152,
        bq, ipb + 1024, ipb + 2048,
        qp, kp, vp, MROWS, 1024, 1);
  }

  // conv compression of k and v
  if (bigX || midX) {
    gemm256<1, 2><<<dim3(8, 4, 8), 512, 0, stream>>>(
        kp, vp, vp,
        w_eT, w_fT, w_fT,
        eb, fb, fb,
        part, part + (size_t)4 * 2048 * 1024, part,
        NB * KPDIM, 8192, 4);
    redc<<<dim3(2048, 2), 256, 0, stream>>>(part, eb, fb, kc, vc);
  } else {
    gemm_bt<1, 0><<<dim3(16, 8, 2), 256, 0, stream>>>(
        kp, vp, vp,
        w_eT, w_fT, w_fT,
        eb, fb, fb,
        kc, vc, vc, NB * KPDIM, 8192, 1);
  }

  // fused attention + head-mean weights
  attn_fused<<<dim3(32, 8), 256, 0, stream>>>(qp, kc, vc, ao, aw_f);

  // output projection -> f32 d_out
  gemm256<0, 1><<<dim3(64, 4, 1), 512, 0, stream>>>(
      ao, ao, ao,
      w_out, w_out, w_out,
      ob, ob, ob,
      out_f, out_f, out_f, MROWS, 1024, 1);
}

// Round 4
// 523.610 us; speedup vs baseline: 1.3008x; 1.0320x over previous
//
#include <hip/hip_runtime.h>

typedef unsigned short u16;
typedef u16  u16x4 __attribute__((ext_vector_type(4)));
typedef u16  u16x8 __attribute__((ext_vector_type(8)));
typedef float f32x4 __attribute__((ext_vector_type(4)));
typedef int   i32x4 __attribute__((ext_vector_type(4)));
typedef __bf16 bf16x8 __attribute__((ext_vector_type(8)));

#define LSEQ 2048
#define NB 8
#define EDIM 1024
#define HNUM 16
#define DDIM 64
#define KPDIM 256
#define NE (NB*EDIM)       /* 8192 */
#define MROWS (LSEQ*NB)    /* 16384 */
#define AWSZ ((size_t)NB*LSEQ*KPDIM)  /* 4194304 */

__device__ __forceinline__ u16 f2b(float f) {
  unsigned u = __builtin_bit_cast(unsigned, f);
  u += 0x7fffu + ((u >> 16) & 1u);
  return (u16)(u >> 16);
}

__device__ __forceinline__ void gl_lds16(const void* g, void* l) {
  __builtin_amdgcn_global_load_lds(
      (const __attribute__((address_space(1))) void*)g,
      (__attribute__((address_space(3))) void*)l, 16, 0, 0);
}

__device__ __forceinline__ f32x4 mfma16(bf16x8 a, bf16x8 b, f32x4 c) {
  return __builtin_amdgcn_mfma_f32_16x16x32_bf16(a, b, c, 0, 0, 0);
}

// ---------------------------------------------------------------------------
// Weight prep kernels
// ---------------------------------------------------------------------------
__global__ void wconv(const float* __restrict__ src, u16* __restrict__ dst,
                      int n4, int scale_n4, float sc) {
  int i = blockIdx.x * blockDim.x + threadIdx.x;
  if (i >= n4) return;
  f32x4 v = ((const f32x4*)src)[i];
  float s = (i < scale_n4) ? sc : 1.0f;
  u16x4 o;
  o[0] = f2b(v[0] * s); o[1] = f2b(v[1] * s);
  o[2] = f2b(v[2] * s); o[3] = f2b(v[3] * s);
  ((u16x4*)dst)[i] = o;
}

// (O, I, 8) f32  ->  (O, t*E + i) bf16   (per-wave LDS transpose)
__global__ void wtrans(const float* __restrict__ ew, const float* __restrict__ fw,
                       u16* __restrict__ eT, u16* __restrict__ fT) {
  const float* src = blockIdx.y ? fw : ew;
  u16* dst = blockIdx.y ? fT : eT;
  int eo = blockIdx.x >> 4;
  int ei0 = (blockIdx.x & 15) * 64;
  int l = threadIdx.x;
  __shared__ u16 lds[8][64];
  const float* s = src + (size_t)eo * 8192 + (size_t)ei0 * 8 + l * 8;
  f32x4 a = *(const f32x4*)s;
  f32x4 b = *(const f32x4*)(s + 4);
  float v[8] = {a[0], a[1], a[2], a[3], b[0], b[1], b[2], b[3]};
#pragma unroll
  for (int t = 0; t < 8; ++t) lds[t][l] = f2b(v[t]);
  __syncthreads();
  int t = l >> 3, c = l & 7;
  i32x4 out = *(const i32x4*)&lds[t][c * 8];
  *(i32x4*)(dst + (size_t)eo * 8192 + t * 1024 + ei0 + c * 8) = out;
}

__global__ void bscale(const float* __restrict__ b, float* __restrict__ out) {
  int i = blockIdx.x * blockDim.x + threadIdx.x;
  if (i < EDIM) out[i] = b[i] * 0.125f;
}

// q/k/v f32 -> bf16, contiguous [3][MROWS][E]
__global__ void castqkv(const float* __restrict__ q, const float* __restrict__ k,
                        const float* __restrict__ v, u16* __restrict__ out) {
  const float* src = blockIdx.y == 0 ? q : (blockIdx.y == 1 ? k : v);
  size_t base = (size_t)blockIdx.y * ((size_t)MROWS * EDIM);
  size_t i = ((size_t)blockIdx.x * 256 + threadIdx.x) * 8;
  f32x4 v0 = *(const f32x4*)(src + i);
  f32x4 v1 = *(const f32x4*)(src + i + 4);
  u16x8 o;
  o[0] = f2b(v0[0]); o[1] = f2b(v0[1]); o[2] = f2b(v0[2]); o[3] = f2b(v0[3]);
  o[4] = f2b(v1[0]); o[5] = f2b(v1[1]); o[6] = f2b(v1[2]); o[7] = f2b(v1[3]);
  *(u16x8*)(out + base + i) = o;
}

// sum 4 split-K partials + bias -> bf16, scatter to head-major (N,H,Kp,D)
__global__ void redc(const float* __restrict__ part, const float* __restrict__ eb,
                     const float* __restrict__ fb, u16* __restrict__ kc,
                     u16* __restrict__ vc) {
  int zc = blockIdx.y;
  const float* p = part + (size_t)zc * 4 * 2048 * 1024;
  u16* out = zc ? vc : kc;
  const float* bias = zc ? fb : eb;
  size_t i = ((size_t)blockIdx.x * 256 + threadIdx.x) * 4;
  f32x4 s = *(const f32x4*)(p + i);
  s += *(const f32x4*)(p + 2097152 + i);
  s += *(const f32x4*)(p + 2 * 2097152 + i);
  s += *(const f32x4*)(p + 3 * 2097152 + i);
  int e = (int)(i & 1023);
  int row = (int)(i >> 10);           // n*256 + p
  int n = row >> 8, pp = row & 255;
  int h = e >> 6, d = e & 63;
  f32x4 b = *(const f32x4*)(bias + e);
  u16x4 o;
  o[0] = f2b(s[0] + b[0]); o[1] = f2b(s[1] + b[1]);
  o[2] = f2b(s[2] + b[2]); o[3] = f2b(s[3] + b[3]);
  *(u16x4*)(out + (((size_t)(n * HNUM + h) * KPDIM + pp) * DDIM + d)) = o;
}

// sum the 4 head-group AW partials
__global__ void awred(const float* __restrict__ awp, float* __restrict__ aw) {
  size_t i = ((size_t)blockIdx.x * 256 + threadIdx.x) * 4;
  f32x4 s = *(const f32x4*)(awp + i);
  s += *(const f32x4*)(awp + AWSZ + i);
  s += *(const f32x4*)(awp + 2 * AWSZ + i);
  s += *(const f32x4*)(awp + 3 * AWSZ + i);
  *(f32x4*)(aw + i) = s;
}

// ---------------------------------------------------------------------------
// 256x256 double-buffered 2-phase GEMM: C[m,o] = sum_k A[m,k]*B[o,k] (+bias)
//   AMODE 0: A bf16 rows contiguous (ld=K); AMODE 1: conv-gather
//   OUTMODE 0: bf16 C + bias; 1: f32 C + bias; 2: f32 split-K partial
// grid = (M/256, N/256, nz*kspl); block = 512 (8 waves, 2M x 4N)
// ---------------------------------------------------------------------------
template<int AMODE, int OUTMODE>
__global__ __launch_bounds__(512, 2)
void gemm256(const void* A0p, const void* A1p, const void* A2p,
             const u16* B0p, const u16* B1p, const u16* B2p,
             const float* b0p, const float* b1p, const float* b2p,
             void* C0p, void* C1p, void* C2p,
             int M, int K, int kspl) {
  const int zc = blockIdx.z / kspl, sp = blockIdx.z % kspl;
  const void* Ap = zc == 0 ? A0p : (zc == 1 ? A1p : A2p);
  const u16* Bp = zc == 0 ? B0p : (zc == 1 ? B1p : B2p);
  const float* biasp = zc == 0 ? b0p : (zc == 1 ? b1p : b2p);
  void* Cp = zc == 0 ? C0p : (zc == 1 ? C1p : C2p);

  __shared__ u16 lds[2][2][256 * 64];   // [buf][A=0/B=1][row*64+k]

  const int tid = threadIdx.x;
  const int w = tid >> 6, lane = tid & 63;
  const int lr = lane & 15, lg = lane >> 4;
  const int wr = w >> 2, wc = w & 3;            // 2M x 4N waves
  const int m0 = blockIdx.x * 256, n0 = blockIdx.y * 256;
  const int kper = K / kspl, kbase = sp * kper, nt = kper >> 6;

  f32x4 acc[8][4];
#pragma unroll
  for (int mi = 0; mi < 8; ++mi)
#pragma unroll
    for (int ni = 0; ni < 4; ++ni) {
      f32x4 zv = {0.f, 0.f, 0.f, 0.f};
      acc[mi][ni] = zv;
    }

  auto stage = [&](int buf, int k0) {
#pragma unroll
    for (int i = 0; i < 4; ++i) {
      int c = i * 512 + tid;                 // 0..2047
      int row = c >> 3, k8 = (c & 7) * 8;
      gl_lds16(Bp + (size_t)(n0 + row) * K + k0 + k8, &lds[buf][1][c * 8]);
    }
    if (AMODE == 0) {
      const u16* Ab = (const u16*)Ap;
#pragma unroll
      for (int i = 0; i < 4; ++i) {
        int c = i * 512 + tid;
        int row = c >> 3, k8 = (c & 7) * 8;
        gl_lds16(Ab + (size_t)(m0 + row) * K + k0 + k8, &lds[buf][0][c * 8]);
      }
    } else {  // conv gather: m=(nn,p), k=(t,ei)
      const u16* Ab = (const u16*)Ap;
#pragma unroll
      for (int i = 0; i < 4; ++i) {
        int c = i * 512 + tid;
        int row = c >> 3, k8 = (c & 7) * 8;
        int m = m0 + row;
        int nn = m >> 8, p = m & 255;
        int k = k0 + k8;
        gl_lds16(Ab + (size_t)(p * 8 + (k >> 10)) * NE + nn * EDIM + (k & 1023),
                 &lds[buf][0][c * 8]);
      }
    }
  };

  auto compute = [&](const u16* As, const u16* Bs) {
#pragma unroll
    for (int ks = 0; ks < 2; ++ks) {
      bf16x8 af[8], bfr[4];
#pragma unroll
      for (int mi = 0; mi < 8; ++mi)
        af[mi] = *(const bf16x8*)&As[(wr * 128 + mi * 16 + lr) * 64 + ks * 32 + lg * 8];
#pragma unroll
      for (int ni = 0; ni < 4; ++ni)
        bfr[ni] = *(const bf16x8*)&Bs[(wc * 64 + ni * 16 + lr) * 64 + ks * 32 + lg * 8];
#pragma unroll
      for (int mi = 0; mi < 8; ++mi)
#pragma unroll
        for (int ni = 0; ni < 4; ++ni)
          acc[mi][ni] = mfma16(af[mi], bfr[ni], acc[mi][ni]);
    }
  };

  stage(0, kbase);
  __syncthreads();
  int cur = 0;
  for (int kt = 0; kt < nt; ++kt) {
    if (kt + 1 < nt) stage(cur ^ 1, kbase + ((kt + 1) << 6));
    compute(&lds[cur][0][0], &lds[cur][1][0]);
    __syncthreads();
    cur ^= 1;
  }

#pragma unroll
  for (int ni = 0; ni < 4; ++ni) {
    const int col = n0 + wc * 64 + ni * 16 + lr;
    const float bv = (OUTMODE == 2) ? 0.f : biasp[col];
#pragma unroll
    for (int mi = 0; mi < 8; ++mi)
#pragma unroll
      for (int j = 0; j < 4; ++j) {
        const int row = m0 + wr * 128 + mi * 16 + lg * 4 + j;
        const float v = acc[mi][ni][j] + bv;
        if (OUTMODE == 2)
          ((float*)Cp)[(size_t)sp * M * 1024 + (size_t)row * 1024 + col] = v;
        else if (OUTMODE == 1)
          ((float*)Cp)[(size_t)row * 1024 + col] = v;
        else
          ((u16*)Cp)[(size_t)row * 1024 + col] = f2b(v);
      }
  }
}

// ---------------------------------------------------------------------------
// Legacy 128x128 GEMM — fallback paths only (small workspace)
//   OUTMODE 3: bf16 + bias scattered to head-major (compress fallback)
// ---------------------------------------------------------------------------
template<int AMODE, int OUTMODE>
__global__ __launch_bounds__(256)
void gemm_bt(const void* A0p, const void* A1p, const void* A2p,
             const u16* B0p, const u16* B1p, const u16* B2p,
             const float* b0p, const float* b1p, const float* b2p,
             void* C0p, void* C1p, void* C2p,
             int M, int K, int kspl) {
  const int zc = blockIdx.z / kspl;
  const int sp = blockIdx.z % kspl;
  const void* Ap = zc == 0 ? A0p : (zc == 1 ? A1p : A2p);
  const u16* Bp = zc == 0 ? B0p : (zc == 1 ? B1p : B2p);
  const float* biasp = zc == 0 ? b0p : (zc == 1 ? b1p : b2p);
  void* Cp = zc == 0 ? C0p : (zc == 1 ? C1p : C2p);

  __shared__ u16 Alds[128 * 64];
  __shared__ u16 Blds[128 * 64];

  const int tid = threadIdx.x;
  const int w = tid >> 6, lane = tid & 63;
  const int lr = lane & 15, lg = lane >> 4;
  const int m0 = blockIdx.x * 128, n0 = blockIdx.y * 128;
  const int wr = (w >> 1) * 64, wc = (w & 1) * 64;
  const int brow = lane >> 3;
  const int bcol = (lane & 7) * 8;

  f32x4 acc[4][4];
#pragma unroll
  for (int mi = 0; mi < 4; ++mi)
#pragma unroll
    for (int ni = 0; ni < 4; ++ni) {
      f32x4 zv = {0.f, 0.f, 0.f, 0.f};
      acc[mi][ni] = zv;
    }

  const int kper = K / kspl;
  const int ktn = kper >> 6;
  const int kb = sp * kper;
  for (int kt = 0; kt < ktn; ++kt) {
    const int k0 = kb + (kt << 6);
    __syncthreads();
#pragma unroll
    for (int i = 0; i < 4; ++i) {
      const int c = w * 4 + i;
      const int row = c * 8 + brow;
      gl_lds16(Bp + (size_t)(n0 + row) * K + k0 + bcol, &Blds[c * 512]);
    }
    if (AMODE == 2) {
      const float* Af = (const float*)Ap;
#pragma unroll
      for (int i = 0; i < 4; ++i) {
        const int c = i * 256 + tid;
        const int row = c >> 3, k8 = (c & 7) * 8;
        const float* s = Af + (size_t)(m0 + row) * K + k0 + k8;
        f32x4 v0 = *(const f32x4*)s;
        f32x4 v1 = *(const f32x4*)(s + 4);
        u16x8 pk;
        pk[0] = f2b(v0[0]); pk[1] = f2b(v0[1]); pk[2] = f2b(v0[2]); pk[3] = f2b(v0[3]);
        pk[4] = f2b(v1[0]); pk[5] = f2b(v1[1]); pk[6] = f2b(v1[2]); pk[7] = f2b(v1[3]);
        *(u16x8*)&Alds[row * 64 + k8] = pk;
      }
    } else if (AMODE == 0) {
      const u16* Ab = (const u16*)Ap;
#pragma unroll
      for (int i = 0; i < 4; ++i) {
        const int c = w * 4 + i;
        const int row = c * 8 + brow;
        gl_lds16(Ab + (size_t)(m0 + row) * K + k0 + bcol, &Alds[c * 512]);
      }
    } else {
      const u16* Ab = (const u16*)Ap;
#pragma unroll
      for (int i = 0; i < 4; ++i) {
        const int c = w * 4 + i;
        const int m = m0 + c * 8 + brow;
        const int nn = m >> 8, p = m & 255;
        const int k = k0 + bcol;
        gl_lds16(Ab + (size_t)(p * 8 + (k >> 10)) * NE + nn * EDIM + (k & 1023),
                 &Alds[c * 512]);
      }
    }
    __syncthreads();
#pragma unroll
    for (int ks = 0; ks < 2; ++ks) {
      bf16x8 af[4], bf[4];
#pragma unroll
      for (int mi = 0; mi < 4; ++mi)
        af[mi] = *(const bf16x8*)&Alds[(wr + mi * 16 + lr) * 64 + ks * 32 + lg * 8];
#pragma unroll
      for (int ni = 0; ni < 4; ++ni)
        bf[ni] = *(const bf16x8*)&Blds[(wc + ni * 16 + lr) * 64 + ks * 32 + lg * 8];
#pragma unroll
      for (int mi = 0; mi < 4; ++mi)
#pragma unroll
        for (int ni = 0; ni < 4; ++ni)
          acc[mi][ni] = mfma16(af[mi], bf[ni], acc[mi][ni]);
    }
  }
#pragma unroll
  for (int ni = 0; ni < 4; ++ni) {
    const int col = n0 + wc + ni * 16 + lr;
    const float bv = (OUTMODE == 2) ? 0.f : biasp[col];
#pragma unroll
    for (int mi = 0; mi < 4; ++mi)
#pragma unroll
      for (int j = 0; j < 4; ++j) {
        const int row = m0 + wr + mi * 16 + lg * 4 + j;
        const float v = acc[mi][ni][j] + bv;
        if (OUTMODE == 3) {
          const int nn = row >> 8, pp = row & 255, h = col >> 6, d = col & 63;
          ((u16*)Cp)[((size_t)(nn * HNUM + h) * KPDIM + pp) * DDIM + d] = f2b(v);
        } else if (OUTMODE == 2)
          ((float*)Cp)[(size_t)sp * M * 1024 + (size_t)row * 1024 + col] = v;
        else if (OUTMODE == 1)
          ((float*)Cp)[(size_t)row * 1024 + col] = v;
        else
          ((u16*)Cp)[(size_t)row * 1024 + col] = f2b(v);
      }
  }
}

// ---------------------------------------------------------------------------
// Fused attention v2: block = (64 q-rows, n, head-group), hpg heads each.
// Kc/Vc head-major (N,H,Kp,D) bf16. LDS 64 KB: Ares holds K then per-wave P;
// Bres holds V^T. 3 barriers per head. AWp = per-group partial (or final
// when gridDim.z==1).
// ---------------------------------------------------------------------------
__global__ __launch_bounds__(256)
void attn_fused(const u16* __restrict__ Q, const u16* __restrict__ Kc,
                const u16* __restrict__ Vc, u16* __restrict__ Aout,
                float* __restrict__ AWp, int hpg) {
  __shared__ u16 Ares[256 * 64];   // K tile [p][d] swizzled -> P quarters
  __shared__ u16 Bres[64 * 256];   // V^T [d][p] swizzled
  const int tid = threadIdx.x;
  const int w = tid >> 6, lane = tid & 63;
  const int lr = lane & 15, lg = lane >> 4;
  const int n = blockIdx.y;
  const int l0 = blockIdx.x * 64;
  const int lrow = l0 + w * 16 + lr;
  char* kbase = (char*)Ares;
  char* vbase = (char*)Bres;
  char* pbase = (char*)Ares + w * 8192;   // 16 rows x 256 x 2B per wave

  f32x4 macc[16];
#pragma unroll
  for (int ni = 0; ni < 16; ++ni) { f32x4 zv = {0.f,0.f,0.f,0.f}; macc[ni] = zv; }

  for (int hh = 0; hh < hpg; ++hh) {
    const int h = blockIdx.z * hpg + hh;
    const u16* kh = Kc + (size_t)(n * HNUM + h) * (KPDIM * DDIM);
    const u16* vh = Vc + (size_t)(n * HNUM + h) * (KPDIM * DDIM);
    __syncthreads();   // prev head fully consumed (PV done in all waves)
    // ---- stage K: [p][d] swizzled rows, 16B chunks ----
#pragma unroll
    for (int it = 0; it < 8; ++it) {
      int c = it * 256 + tid, p = c >> 3, c16 = c & 7;
      i32x4 kd = *(const i32x4*)(kh + p * 64 + c16 * 8);
      *(i32x4*)(kbase + p * 128 + ((c16 * 16) ^ ((p & 7) << 4))) = kd;
    }
    // ---- stage V transposed [d][p] swizzled, p-pairs packed as u32 ----
#pragma unroll
    for (int it = 0; it < 4; ++it) {
      int c = it * 256 + tid, p2 = c >> 3, c16 = c & 7, p = p2 * 2;
      u16x8 v0 = *(const u16x8*)(vh + p * 64 + c16 * 8);
      u16x8 v1 = *(const u16x8*)(vh + (p + 1) * 64 + c16 * 8);
#pragma unroll
      for (int j = 0; j < 8; ++j) {
        int d = c16 * 8 + j;
        unsigned pk = (unsigned)v0[j] | ((unsigned)v1[j] << 16);
        *(unsigned*)(vbase + d * 512 + ((p * 2) ^ ((d & 7) << 4))) = pk;
      }
    }
    // ---- q fragments ----
    const u16* qp = Q + (size_t)lrow * NE + n * EDIM + h * DDIM + lg * 8;
    bf16x8 aq0 = *(const bf16x8*)qp;
    bf16x8 aq1 = *(const bf16x8*)(qp + 32);
    __syncthreads();   // K, V staged
    // ---- S = q @ k^T : 16 rows x 256 cols per wave ----
    f32x4 s[16];
#pragma unroll
    for (int ni = 0; ni < 16; ++ni) { f32x4 zv = {0.f,0.f,0.f,0.f}; s[ni] = zv; }
#pragma unroll
    for (int ni = 0; ni < 16; ++ni) {
      int row = ni * 16 + lr;
      const char* kr = kbase + row * 128;
      bf16x8 b0 = *(const bf16x8*)(kr + ((16 * lg) ^ ((row & 7) << 4)));
      bf16x8 b1 = *(const bf16x8*)(kr + ((64 + 16 * lg) ^ ((row & 7) << 4)));
      s[ni] = mfma16(aq0, b0, s[ni]);
      s[ni] = mfma16(aq1, b1, s[ni]);
    }
    // ---- softmax (row r = lg*4+j lives in 16-lane group lg) ----
    float mx[4], sm[4], inv[4];
#pragma unroll
    for (int j = 0; j < 4; ++j) mx[j] = -1e30f;
#pragma unroll
    for (int ni = 0; ni < 16; ++ni)
#pragma unroll
      for (int j = 0; j < 4; ++j) mx[j] = fmaxf(mx[j], s[ni][j]);
#pragma unroll
    for (int msk = 1; msk <= 8; msk <<= 1)
#pragma unroll
      for (int j = 0; j < 4; ++j) mx[j] = fmaxf(mx[j], __shfl_xor(mx[j], msk, 64));
#pragma unroll
    for (int j = 0; j < 4; ++j) sm[j] = 0.f;
#pragma unroll
    for (int ni = 0; ni < 16; ++ni)
#pragma unroll
      for (int j = 0; j < 4; ++j) {
        float e = __expf(s[ni][j] - mx[j]);
        s[ni][j] = e; sm[j] += e;
      }
#pragma unroll
    for (int msk = 1; msk <= 8; msk <<= 1)
#pragma unroll
      for (int j = 0; j < 4; ++j) sm[j] += __shfl_xor(sm[j], msk, 64);
#pragma unroll
    for (int j = 0; j < 4; ++j) inv[j] = 1.0f / sm[j];
    __syncthreads();   // all waves finished reading K from Ares
    // ---- normalize, head-mean, store P (bf16, per-wave quarter of Ares) ----
#pragma unroll
    for (int ni = 0; ni < 16; ++ni)
#pragma unroll
      for (int j = 0; j < 4; ++j) {
        float pv = s[ni][j] * inv[j];
        macc[ni][j] += pv * 0.0625f;
        int r = lg * 4 + j;
        *(u16*)(pbase + r * 512 + ((ni * 32 + lr * 2) ^ ((r & 7) << 4))) = f2b(pv);
      }
    // ---- O = P @ V  (P wave-private; no barrier needed) ----
    f32x4 o[4];
#pragma unroll
    for (int ni2 = 0; ni2 < 4; ++ni2) { f32x4 zv = {0.f,0.f,0.f,0.f}; o[ni2] = zv; }
#pragma unroll
    for (int ks = 0; ks < 8; ++ks) {
      bf16x8 a = *(const bf16x8*)(pbase + lr * 512 + ((ks * 64 + 16 * lg) ^ ((lr & 7) << 4)));
#pragma unroll
      for (int ni2 = 0; ni2 < 4; ++ni2) {
        int d = ni2 * 16 + lr;
        bf16x8 b = *(const bf16x8*)(vbase + d * 512 + ((ks * 64 + 16 * lg) ^ ((d & 7) << 4)));
        o[ni2] = mfma16(a, b, o[ni2]);
      }
    }
    // ---- write O tile ----
#pragma unroll
    for (int ni2 = 0; ni2 < 4; ++ni2)
#pragma unroll
      for (int j = 0; j < 4; ++j) {
        int gl = l0 + w * 16 + lg * 4 + j;
        Aout[(size_t)gl * NE + n * EDIM + h * DDIM + ni2 * 16 + lr] = f2b(o[ni2][j]);
      }
  }
  // ---- write head-mean attention weight partial ----
  float* awo = AWp + (size_t)blockIdx.z * AWSZ + (size_t)n * (LSEQ * KPDIM);
#pragma unroll
  for (int ni = 0; ni < 16; ++ni)
#pragma unroll
    for (int j = 0; j < 4; ++j) {
      int r = lg * 4 + j;
      awo[(size_t)(l0 + w * 16 + r) * KPDIM + ni * 16 + lr] = macc[ni][j];
    }
}

// ---------------------------------------------------------------------------
extern "C" void kernel_launch(void* const* d_in, const int* in_sizes, int n_in,
                              void* d_out, int out_size, void* d_ws, size_t ws_size,
                              hipStream_t stream) {
  const float* query = (const float*)d_in[0];
  const float* key   = (const float*)d_in[1];
  const float* value = (const float*)d_in[2];
  const float* ipw   = (const float*)d_in[3];
  const float* ipb   = (const float*)d_in[4];
  const float* ew    = (const float*)d_in[5];
  const float* eb    = (const float*)d_in[6];
  const float* fw    = (const float*)d_in[7];
  const float* fb    = (const float*)d_in[8];
  const float* ow    = (const float*)d_in[9];
  const float* ob    = (const float*)d_in[10];

  char* ws = (char*)d_ws;
  size_t off = 0;
  auto alloc = [&](size_t bytes) {
    void* p = ws + off;
    off += (bytes + 255) & ~(size_t)255;
    return p;
  };
  u16* qp    = (u16*)alloc((size_t)MROWS * EDIM * 2);
  u16* kp    = (u16*)alloc((size_t)MROWS * EDIM * 2);
  u16* vp    = (u16*)alloc((size_t)MROWS * EDIM * 2);
  u16* ao    = (u16*)alloc((size_t)MROWS * EDIM * 2);
  u16* kc    = (u16*)alloc((size_t)NB * KPDIM * EDIM * 2);   // head-major (N,H,Kp,D)
  u16* vc    = (u16*)alloc((size_t)NB * KPDIM * EDIM * 2);
  u16* w_in  = (u16*)alloc((size_t)3 * EDIM * EDIM * 2);
  u16* w_eT  = (u16*)alloc((size_t)EDIM * 8 * EDIM * 2);
  u16* w_fT  = (u16*)alloc((size_t)EDIM * 8 * EDIM * 2);
  u16* w_out = (u16*)alloc((size_t)EDIM * EDIM * 2);
  float* bq  = (float*)alloc(EDIM * 4);
  size_t base_needed = off;

  // X region, aliased in sequence: qkv16 (100.7 MB) -> split-K partials
  // (64 MB) -> AW head-group partials (67.1 MB). Lifetimes do not overlap.
  size_t qkv16_b = (size_t)3 * MROWS * EDIM * 2;
  size_t part_b  = (size_t)2 * 4 * 2048 * 1024 * 4;
  bool bigX  = ws_size >= base_needed + qkv16_b;
  bool midX  = ws_size >= base_needed + part_b;
  char* X = (char*)alloc(bigX ? qkv16_b : (midX ? part_b : 0));
  u16* qkv16 = (u16*)X;
  float* part = (float*)X;
  float* awp  = (float*)X;

  float* out_f = (float*)d_out;                        // (L, N, E)
  float* aw_f  = (float*)d_out + (size_t)MROWS * EDIM; // (N, L, Kp)

  // weight prep
  wconv<<<dim3(3072), 256, 0, stream>>>(ipw, w_in, 786432, 262144, 0.125f);
  wconv<<<dim3(1024), 256, 0, stream>>>(ow, w_out, 262144, 0, 1.0f);
  wtrans<<<dim3(16384, 2), 64, 0, stream>>>(ew, fw, w_eT, w_fT);
  bscale<<<dim3(4), 256, 0, stream>>>(ipb, bq);

  // q/k/v projections
  if (bigX) {
    castqkv<<<dim3(8192, 3), 256, 0, stream>>>(query, key, value, qkv16);
    gemm256<0, 0><<<dim3(64, 4, 3), 512, 0, stream>>>(
        qkv16, qkv16 + (size_t)MROWS * EDIM, qkv16 + (size_t)2 * MROWS * EDIM,
        w_in, w_in + 1048576, w_in + 2097152,
        bq, ipb + 1024, ipb + 2048,
        qp, kp, vp, MROWS, 1024, 1);
  } else {
    gemm_bt<2, 0><<<dim3(128, 8, 3), 256, 0, stream>>>(
        query, key, value,
        w_in, w_in + 1048576, w_in + 2097152,
        bq, ipb + 1024, ipb + 2048,
        qp, kp, vp, MROWS, 1024, 1);
  }

  // conv compression of k and v -> head-major kc/vc
  if (bigX || midX) {
    gemm256<1, 2><<<dim3(8, 4, 8), 512, 0, stream>>>(
        kp, vp, vp,
        w_eT, w_fT, w_fT,
        eb, fb, fb,
        part, part + (size_t)4 * 2048 * 1024, part,
        NB * KPDIM, 8192, 4);
    redc<<<dim3(2048, 2), 256, 0, stream>>>(part, eb, fb, kc, vc);
  } else {
    gemm_bt<1, 3><<<dim3(16, 8, 2), 256, 0, stream>>>(
        kp, vp, vp,
        w_eT, w_fT, w_fT,
        eb, fb, fb,
        kc, vc, vc, NB * KPDIM, 8192, 1);
  }

  // fused attention + head-mean weights
  if (bigX) {
    attn_fused<<<dim3(32, 8, 4), 256, 0, stream>>>(qp, kc, vc, ao, awp, 4);
    awred<<<dim3(4096), 256, 0, stream>>>(awp, aw_f);
  } else {
    attn_fused<<<dim3(32, 8, 1), 256, 0, stream>>>(qp, kc, vc, ao, aw_f, 16);
  }

  // output projection -> f32 d_out
  gemm256<0, 1><<<dim3(64, 4, 1), 512, 0, stream>>>(
      ao, ao, ao,
      w_out, w_out, w_out,
      ob, ob, ob,
      out_f, out_f, out_f, MROWS, 1024, 1);
}

// Round 5
// 517.687 us; speedup vs baseline: 1.3157x; 1.0114x over previous
//
#include <hip/hip_runtime.h>

typedef unsigned short u16;
typedef u16  u16x4 __attribute__((ext_vector_type(4)));
typedef u16  u16x8 __attribute__((ext_vector_type(8)));
typedef float f32x4 __attribute__((ext_vector_type(4)));
typedef int   i32x4 __attribute__((ext_vector_type(4)));
typedef __bf16 bf16x8 __attribute__((ext_vector_type(8)));

#define LSEQ 2048
#define NB 8
#define EDIM 1024
#define HNUM 16
#define DDIM 64
#define KPDIM 256
#define NE (NB*EDIM)       /* 8192 */
#define MROWS (LSEQ*NB)    /* 16384 */
#define AWSZ ((size_t)NB*LSEQ*KPDIM)  /* 4194304 */

__device__ __forceinline__ u16 f2b(float f) {
  unsigned u = __builtin_bit_cast(unsigned, f);
  u += 0x7fffu + ((u >> 16) & 1u);
  return (u16)(u >> 16);
}

__device__ __forceinline__ void gl_lds16(const void* g, void* l) {
  __builtin_amdgcn_global_load_lds(
      (const __attribute__((address_space(1))) void*)g,
      (__attribute__((address_space(3))) void*)l, 16, 0, 0);
}

__device__ __forceinline__ f32x4 mfma16(bf16x8 a, bf16x8 b, f32x4 c) {
  return __builtin_amdgcn_mfma_f32_16x16x32_bf16(a, b, c, 0, 0, 0);
}

// raw barrier fenced against compiler motion (no implicit waitcnt drain)
#define SBAR() do { __builtin_amdgcn_sched_barrier(0); \
                    __builtin_amdgcn_s_barrier(); \
                    __builtin_amdgcn_sched_barrier(0); } while (0)
#define WAITVM8() do { __builtin_amdgcn_sched_barrier(0); \
                       asm volatile("s_waitcnt vmcnt(8)" ::: "memory"); \
                       __builtin_amdgcn_sched_barrier(0); } while (0)
#define WAITVM0() do { __builtin_amdgcn_sched_barrier(0); \
                       asm volatile("s_waitcnt vmcnt(0)" ::: "memory"); \
                       __builtin_amdgcn_sched_barrier(0); } while (0)

// ---------------------------------------------------------------------------
// Weight prep kernels
// ---------------------------------------------------------------------------
__global__ void wconv(const float* __restrict__ src, u16* __restrict__ dst,
                      int n4, int scale_n4, float sc) {
  int i = blockIdx.x * blockDim.x + threadIdx.x;
  if (i >= n4) return;
  f32x4 v = ((const f32x4*)src)[i];
  float s = (i < scale_n4) ? sc : 1.0f;
  u16x4 o;
  o[0] = f2b(v[0] * s); o[1] = f2b(v[1] * s);
  o[2] = f2b(v[2] * s); o[3] = f2b(v[3] * s);
  ((u16x4*)dst)[i] = o;
}

// (O, I, 8) f32  ->  (O, t*E + i) bf16   (per-wave LDS transpose)
__global__ void wtrans(const float* __restrict__ ew, const float* __restrict__ fw,
                       u16* __restrict__ eT, u16* __restrict__ fT) {
  const float* src = blockIdx.y ? fw : ew;
  u16* dst = blockIdx.y ? fT : eT;
  int eo = blockIdx.x >> 4;
  int ei0 = (blockIdx.x & 15) * 64;
  int l = threadIdx.x;
  __shared__ u16 lds[8][64];
  const float* s = src + (size_t)eo * 8192 + (size_t)ei0 * 8 + l * 8;
  f32x4 a = *(const f32x4*)s;
  f32x4 b = *(const f32x4*)(s + 4);
  float v[8] = {a[0], a[1], a[2], a[3], b[0], b[1], b[2], b[3]};
#pragma unroll
  for (int t = 0; t < 8; ++t) lds[t][l] = f2b(v[t]);
  __syncthreads();
  int t = l >> 3, c = l & 7;
  i32x4 out = *(const i32x4*)&lds[t][c * 8];
  *(i32x4*)(dst + (size_t)eo * 8192 + t * 1024 + ei0 + c * 8) = out;
}

__global__ void bscale(const float* __restrict__ b, float* __restrict__ out) {
  int i = blockIdx.x * blockDim.x + threadIdx.x;
  if (i < EDIM) out[i] = b[i] * 0.125f;
}

// q/k/v f32 -> bf16, contiguous [3][MROWS][E]
__global__ void castqkv(const float* __restrict__ q, const float* __restrict__ k,
                        const float* __restrict__ v, u16* __restrict__ out) {
  const float* src = blockIdx.y == 0 ? q : (blockIdx.y == 1 ? k : v);
  size_t base = (size_t)blockIdx.y * ((size_t)MROWS * EDIM);
  size_t i = ((size_t)blockIdx.x * 256 + threadIdx.x) * 8;
  f32x4 v0 = *(const f32x4*)(src + i);
  f32x4 v1 = *(const f32x4*)(src + i + 4);
  u16x8 o;
  o[0] = f2b(v0[0]); o[1] = f2b(v0[1]); o[2] = f2b(v0[2]); o[3] = f2b(v0[3]);
  o[4] = f2b(v1[0]); o[5] = f2b(v1[1]); o[6] = f2b(v1[2]); o[7] = f2b(v1[3]);
  *(u16x8*)(out + base + i) = o;
}

// sum 4 split-K partials + bias -> bf16, scatter to head-major (N,H,Kp,D)
__global__ void redc(const float* __restrict__ part, const float* __restrict__ eb,
                     const float* __restrict__ fb, u16* __restrict__ kc,
                     u16* __restrict__ vc) {
  int zc = blockIdx.y;
  const float* p = part + (size_t)zc * 4 * 2048 * 1024;
  u16* out = zc ? vc : kc;
  const float* bias = zc ? fb : eb;
  size_t i = ((size_t)blockIdx.x * 256 + threadIdx.x) * 4;
  f32x4 s = *(const f32x4*)(p + i);
  s += *(const f32x4*)(p + 2097152 + i);
  s += *(const f32x4*)(p + 2 * 2097152 + i);
  s += *(const f32x4*)(p + 3 * 2097152 + i);
  int e = (int)(i & 1023);
  int row = (int)(i >> 10);           // n*256 + p
  int n = row >> 8, pp = row & 255;
  int h = e >> 6, d = e & 63;
  f32x4 b = *(const f32x4*)(bias + e);
  u16x4 o;
  o[0] = f2b(s[0] + b[0]); o[1] = f2b(s[1] + b[1]);
  o[2] = f2b(s[2] + b[2]); o[3] = f2b(s[3] + b[3]);
  *(u16x4*)(out + (((size_t)(n * HNUM + h) * KPDIM + pp) * DDIM + d)) = o;
}

// sum the 4 head-group AW partials
__global__ void awred(const float* __restrict__ awp, float* __restrict__ aw) {
  size_t i = ((size_t)blockIdx.x * 256 + threadIdx.x) * 4;
  f32x4 s = *(const f32x4*)(awp + i);
  s += *(const f32x4*)(awp + AWSZ + i);
  s += *(const f32x4*)(awp + 2 * AWSZ + i);
  s += *(const f32x4*)(awp + 3 * AWSZ + i);
  *(f32x4*)(aw + i) = s;
}

// ---------------------------------------------------------------------------
// 256x256 GEMM, 4-phase counted-vmcnt schedule (T3+T4), LDS XOR-swizzle (T2),
// setprio around MFMA (T5).  C[m,o] = sum_k A[m,k]*B[o,k] (+bias)
//   AMODE 0: A bf16 rows contiguous (ld=K); AMODE 1: conv-gather
//   OUTMODE 0: bf16 C + bias; 1: f32 C + bias; 2: f32 split-K partial
// grid = (M/256, N/256, nz*kspl); block = 512 (8 waves, 2M x 4N)
//
// Schedule per K-tile t (buf b=t&1), 4 phases x {ds_read quadrant; SBAR;
// setprio(1); 16 MFMA; setprio(0); SBAR}:
//   P0: read a0 (A rows wr*128+[0,64)), b0 (B rows wc*64+[0,32)) -> acc[0..3][0..1]
//   P1: read b1 (B rows wc*64+[32,64))                           -> acc[0..3][2..3]
//   P2: read a1 (A rows wr*128+[64,128))                         -> acc[4..7][2..3]
//   P3: stage(t+2 -> buf b); regs only                           -> acc[4..7][0..1]
//       then s_waitcnt vmcnt(8) (t+1's 8 loads landed; t+2's stay in flight); SBAR
// Hazard proof: (1) reads of tile t's buf are covered by the t-1 boundary
// vmcnt(8)+barrier (per-wave vmcnt + barrier rendezvous => all waves' loads
// landed). (2) stage(t+2) into buf b is issued after P2's trailing barrier;
// every phase's MFMA lgkm-drains that phase's ds_reads before its trailing
// barrier, so all reads of buf b completed block-wide. (3) WAW: t's loads all
// landed by the t-1 boundary, before t+2's stage issues. All branches are
// block-uniform. vmcnt decrements in issue order (m135 semantics).
// T2: global SOURCE pre-swizzled (chunk j -> j^(row&7)), LDS dest linear
// (global_load_lds requirement), read side applies the same XOR (involution).
// ---------------------------------------------------------------------------
template<int AMODE, int OUTMODE>
__global__ __launch_bounds__(512, 2)
void gemm256(const void* A0p, const void* A1p, const void* A2p,
             const u16* B0p, const u16* B1p, const u16* B2p,
             const float* b0p, const float* b1p, const float* b2p,
             void* C0p, void* C1p, void* C2p,
             int M, int K, int kspl) {
  const int zc = blockIdx.z / kspl, sp = blockIdx.z % kspl;
  const void* Ap = zc == 0 ? A0p : (zc == 1 ? A1p : A2p);
  const u16* Bp = zc == 0 ? B0p : (zc == 1 ? B1p : B2p);
  const float* biasp = zc == 0 ? b0p : (zc == 1 ? b1p : b2p);
  void* Cp = zc == 0 ? C0p : (zc == 1 ? C1p : C2p);

  __shared__ u16 lds[2][2][256 * 64];   // [buf][A=0/B=1][row*64 + swz-chunk*8]

  const int tid = threadIdx.x;
  const int w = tid >> 6, lane = tid & 63;
  const int lr = lane & 15, lg = lane >> 4;
  const int wr = w >> 2, wc = w & 3;            // 2M x 4N waves
  const int m0 = blockIdx.x * 256, n0 = blockIdx.y * 256;
  const int kper = K / kspl, kbase = sp * kper, nt = kper >> 6;

  f32x4 acc[8][4];
#pragma unroll
  for (int mi = 0; mi < 8; ++mi)
#pragma unroll
    for (int ni = 0; ni < 4; ++ni) {
      f32x4 zv = {0.f, 0.f, 0.f, 0.f};
      acc[mi][ni] = zv;
    }

  auto stage = [&](int buf, int kt) {
    const int k0 = kbase + (kt << 6);
#pragma unroll
    for (int i = 0; i < 4; ++i) {
      int c = i * 512 + tid;                 // 0..2047
      int row = c >> 3, j = c & 7, js = j ^ (row & 7);
      gl_lds16(Bp + (size_t)(n0 + row) * K + k0 + js * 8, &lds[buf][1][c * 8]);
    }
    if (AMODE == 0) {
      const u16* Ab = (const u16*)Ap;
#pragma unroll
      for (int i = 0; i < 4; ++i) {
        int c = i * 512 + tid;
        int row = c >> 3, j = c & 7, js = j ^ (row & 7);
        gl_lds16(Ab + (size_t)(m0 + row) * K + k0 + js * 8, &lds[buf][0][c * 8]);
      }
    } else {  // conv gather: m=(nn,p), k=(t,ei); k0 mult of 64 so no 1024-cross
      const u16* Ab = (const u16*)Ap;
#pragma unroll
      for (int i = 0; i < 4; ++i) {
        int c = i * 512 + tid;
        int row = c >> 3, j = c & 7, js = j ^ (row & 7);
        int m = m0 + row;
        int nn = m >> 8, p = m & 255;
        int k = k0 + js * 8;
        gl_lds16(Ab + (size_t)(p * 8 + (k >> 10)) * NE + nn * EDIM + (k & 1023),
                 &lds[buf][0][c * 8]);
      }
    }
  };

  auto LDA = [&](int buf, int row, int ks) -> bf16x8 {
    return *(const bf16x8*)&lds[buf][0][row * 64 + (((ks * 4 + lg) ^ (row & 7)) << 3)];
  };
  auto LDB = [&](int buf, int row, int ks) -> bf16x8 {
    return *(const bf16x8*)&lds[buf][1][row * 64 + (((ks * 4 + lg) ^ (row & 7)) << 3)];
  };

  // prologue: tiles 0 and 1 in flight; wait tile 0 (8 newest may fly)
  stage(0, 0);
  if (nt > 1) { stage(1, 1); WAITVM8(); } else { WAITVM0(); }
  SBAR();

  for (int t = 0; t < nt; ++t) {
    const int b = t & 1;
    bf16x8 a0[4][2], a1[4][2], bq0[2][2], bq1[2][2];
    // ---- P0 ----
#pragma unroll
    for (int mi = 0; mi < 4; ++mi)
#pragma unroll
      for (int ks = 0; ks < 2; ++ks)
        a0[mi][ks] = LDA(b, wr * 128 + mi * 16 + lr, ks);
#pragma unroll
    for (int ni = 0; ni < 2; ++ni)
#pragma unroll
      for (int ks = 0; ks < 2; ++ks)
        bq0[ni][ks] = LDB(b, wc * 64 + ni * 16 + lr, ks);
    SBAR();
    __builtin_amdgcn_s_setprio(1);
#pragma unroll
    for (int mi = 0; mi < 4; ++mi)
#pragma unroll
      for (int ni = 0; ni < 2; ++ni)
#pragma unroll
        for (int ks = 0; ks < 2; ++ks)
          acc[mi][ni] = mfma16(a0[mi][ks], bq0[ni][ks], acc[mi][ni]);
    __builtin_amdgcn_s_setprio(0);
    SBAR();
    // ---- P1 ----
#pragma unroll
    for (int ni = 0; ni < 2; ++ni)
#pragma unroll
      for (int ks = 0; ks < 2; ++ks)
        bq1[ni][ks] = LDB(b, wc * 64 + (ni + 2) * 16 + lr, ks);
    SBAR();
    __builtin_amdgcn_s_setprio(1);
#pragma unroll
    for (int mi = 0; mi < 4; ++mi)
#pragma unroll
      for (int ni = 0; ni < 2; ++ni)
#pragma unroll
        for (int ks = 0; ks < 2; ++ks)
          acc[mi][ni + 2] = mfma16(a0[mi][ks], bq1[ni][ks], acc[mi][ni + 2]);
    __builtin_amdgcn_s_setprio(0);
    SBAR();
    // ---- P2 ----
#pragma unroll
    for (int mi = 0; mi < 4; ++mi)
#pragma unroll
      for (int ks = 0; ks < 2; ++ks)
        a1[mi][ks] = LDA(b, wr * 128 + 64 + mi * 16 + lr, ks);
    SBAR();
    __builtin_amdgcn_s_setprio(1);
#pragma unroll
    for (int mi = 0; mi < 4; ++mi)
#pragma unroll
      for (int ni = 0; ni < 2; ++ni)
#pragma unroll
        for (int ks = 0; ks < 2; ++ks)
          acc[mi + 4][ni + 2] = mfma16(a1[mi][ks], bq1[ni][ks], acc[mi + 4][ni + 2]);
    __builtin_amdgcn_s_setprio(0);
    SBAR();
    // ---- P3 ----
    if (t + 2 < nt) stage(b, t + 2);
    SBAR();
    __builtin_amdgcn_s_setprio(1);
#pragma unroll
    for (int mi = 0; mi < 4; ++mi)
#pragma unroll
      for (int ni = 0; ni < 2; ++ni)
#pragma unroll
        for (int ks = 0; ks < 2; ++ks)
          acc[mi + 4][ni] = mfma16(a1[mi][ks], bq0[ni][ks], acc[mi + 4][ni]);
    __builtin_amdgcn_s_setprio(0);
    // ---- boundary: tile t+1 must be landed; keep t+2 in flight ----
    if (t + 1 < nt) {
      if (t + 2 < nt) { WAITVM8(); } else { WAITVM0(); }
    }
    SBAR();
  }

  // ---- epilogue ----
#pragma unroll
  for (int ni = 0; ni < 4; ++ni) {
    const int col = n0 + wc * 64 + ni * 16 + lr;
    const float bv = (OUTMODE == 2) ? 0.f : biasp[col];
#pragma unroll
    for (int mi = 0; mi < 8; ++mi)
#pragma unroll
      for (int j = 0; j < 4; ++j) {
        const int row = m0 + wr * 128 + mi * 16 + lg * 4 + j;
        const float v = acc[mi][ni][j] + bv;
        if (OUTMODE == 2)
          ((float*)Cp)[(size_t)sp * M * 1024 + (size_t)row * 1024 + col] = v;
        else if (OUTMODE == 1)
          ((float*)Cp)[(size_t)row * 1024 + col] = v;
        else
          ((u16*)Cp)[(size_t)row * 1024 + col] = f2b(v);
      }
  }
}

// ---------------------------------------------------------------------------
// Legacy 128x128 GEMM — fallback paths only (small workspace)
//   OUTMODE 3: bf16 + bias scattered to head-major (compress fallback)
// ---------------------------------------------------------------------------
template<int AMODE, int OUTMODE>
__global__ __launch_bounds__(256)
void gemm_bt(const void* A0p, const void* A1p, const void* A2p,
             const u16* B0p, const u16* B1p, const u16* B2p,
             const float* b0p, const float* b1p, const float* b2p,
             void* C0p, void* C1p, void* C2p,
             int M, int K, int kspl) {
  const int zc = blockIdx.z / kspl;
  const int sp = blockIdx.z % kspl;
  const void* Ap = zc == 0 ? A0p : (zc == 1 ? A1p : A2p);
  const u16* Bp = zc == 0 ? B0p : (zc == 1 ? B1p : B2p);
  const float* biasp = zc == 0 ? b0p : (zc == 1 ? b1p : b2p);
  void* Cp = zc == 0 ? C0p : (zc == 1 ? C1p : C2p);

  __shared__ u16 Alds[128 * 64];
  __shared__ u16 Blds[128 * 64];

  const int tid = threadIdx.x;
  const int w = tid >> 6, lane = tid & 63;
  const int lr = lane & 15, lg = lane >> 4;
  const int m0 = blockIdx.x * 128, n0 = blockIdx.y * 128;
  const int wr = (w >> 1) * 64, wc = (w & 1) * 64;
  const int brow = lane >> 3;
  const int bcol = (lane & 7) * 8;

  f32x4 acc[4][4];
#pragma unroll
  for (int mi = 0; mi < 4; ++mi)
#pragma unroll
    for (int ni = 0; ni < 4; ++ni) {
      f32x4 zv = {0.f, 0.f, 0.f, 0.f};
      acc[mi][ni] = zv;
    }

  const int kper = K / kspl;
  const int ktn = kper >> 6;
  const int kb = sp * kper;
  for (int kt = 0; kt < ktn; ++kt) {
    const int k0 = kb + (kt << 6);
    __syncthreads();
#pragma unroll
    for (int i = 0; i < 4; ++i) {
      const int c = w * 4 + i;
      const int row = c * 8 + brow;
      gl_lds16(Bp + (size_t)(n0 + row) * K + k0 + bcol, &Blds[c * 512]);
    }
    if (AMODE == 2) {
      const float* Af = (const float*)Ap;
#pragma unroll
      for (int i = 0; i < 4; ++i) {
        const int c = i * 256 + tid;
        const int row = c >> 3, k8 = (c & 7) * 8;
        const float* s = Af + (size_t)(m0 + row) * K + k0 + k8;
        f32x4 v0 = *(const f32x4*)s;
        f32x4 v1 = *(const f32x4*)(s + 4);
        u16x8 pk;
        pk[0] = f2b(v0[0]); pk[1] = f2b(v0[1]); pk[2] = f2b(v0[2]); pk[3] = f2b(v0[3]);
        pk[4] = f2b(v1[0]); pk[5] = f2b(v1[1]); pk[6] = f2b(v1[2]); pk[7] = f2b(v1[3]);
        *(u16x8*)&Alds[row * 64 + k8] = pk;
      }
    } else if (AMODE == 0) {
      const u16* Ab = (const u16*)Ap;
#pragma unroll
      for (int i = 0; i < 4; ++i) {
        const int c = w * 4 + i;
        const int row = c * 8 + brow;
        gl_lds16(Ab + (size_t)(m0 + row) * K + k0 + bcol, &Alds[c * 512]);
      }
    } else {
      const u16* Ab = (const u16*)Ap;
#pragma unroll
      for (int i = 0; i < 4; ++i) {
        const int c = w * 4 + i;
        const int m = m0 + c * 8 + brow;
        const int nn = m >> 8, p = m & 255;
        const int k = k0 + bcol;
        gl_lds16(Ab + (size_t)(p * 8 + (k >> 10)) * NE + nn * EDIM + (k & 1023),
                 &Alds[c * 512]);
      }
    }
    __syncthreads();
#pragma unroll
    for (int ks = 0; ks < 2; ++ks) {
      bf16x8 af[4], bf[4];
#pragma unroll
      for (int mi = 0; mi < 4; ++mi)
        af[mi] = *(const bf16x8*)&Alds[(wr + mi * 16 + lr) * 64 + ks * 32 + lg * 8];
#pragma unroll
      for (int ni = 0; ni < 4; ++ni)
        bf[ni] = *(const bf16x8*)&Blds[(wc + ni * 16 + lr) * 64 + ks * 32 + lg * 8];
#pragma unroll
      for (int mi = 0; mi < 4; ++mi)
#pragma unroll
        for (int ni = 0; ni < 4; ++ni)
          acc[mi][ni] = mfma16(af[mi], bf[ni], acc[mi][ni]);
    }
  }
#pragma unroll
  for (int ni = 0; ni < 4; ++ni) {
    const int col = n0 + wc + ni * 16 + lr;
    const float bv = (OUTMODE == 2) ? 0.f : biasp[col];
#pragma unroll
    for (int mi = 0; mi < 4; ++mi)
#pragma unroll
      for (int j = 0; j < 4; ++j) {
        const int row = m0 + wr + mi * 16 + lg * 4 + j;
        const float v = acc[mi][ni][j] + bv;
        if (OUTMODE == 3) {
          const int nn = row >> 8, pp = row & 255, h = col >> 6, d = col & 63;
          ((u16*)Cp)[((size_t)(nn * HNUM + h) * KPDIM + pp) * DDIM + d] = f2b(v);
        } else if (OUTMODE == 2)
          ((float*)Cp)[(size_t)sp * M * 1024 + (size_t)row * 1024 + col] = v;
        else if (OUTMODE == 1)
          ((float*)Cp)[(size_t)row * 1024 + col] = v;
        else
          ((u16*)Cp)[(size_t)row * 1024 + col] = f2b(v);
      }
  }
}

// ---------------------------------------------------------------------------
// Fused attention v2: block = (64 q-rows, n, head-group), hpg heads each.
// ---------------------------------------------------------------------------
__global__ __launch_bounds__(256)
void attn_fused(const u16* __restrict__ Q, const u16* __restrict__ Kc,
                const u16* __restrict__ Vc, u16* __restrict__ Aout,
                float* __restrict__ AWp, int hpg) {
  __shared__ u16 Ares[256 * 64];   // K tile [p][d] swizzled -> P quarters
  __shared__ u16 Bres[64 * 256];   // V^T [d][p] swizzled
  const int tid = threadIdx.x;
  const int w = tid >> 6, lane = tid & 63;
  const int lr = lane & 15, lg = lane >> 4;
  const int n = blockIdx.y;
  const int l0 = blockIdx.x * 64;
  const int lrow = l0 + w * 16 + lr;
  char* kbase = (char*)Ares;
  char* vbase = (char*)Bres;
  char* pbase = (char*)Ares + w * 8192;   // 16 rows x 256 x 2B per wave

  f32x4 macc[16];
#pragma unroll
  for (int ni = 0; ni < 16; ++ni) { f32x4 zv = {0.f,0.f,0.f,0.f}; macc[ni] = zv; }

  for (int hh = 0; hh < hpg; ++hh) {
    const int h = blockIdx.z * hpg + hh;
    const u16* kh = Kc + (size_t)(n * HNUM + h) * (KPDIM * DDIM);
    const u16* vh = Vc + (size_t)(n * HNUM + h) * (KPDIM * DDIM);
    __syncthreads();   // prev head fully consumed (PV done in all waves)
    // ---- stage K: [p][d] swizzled rows, 16B chunks ----
#pragma unroll
    for (int it = 0; it < 8; ++it) {
      int c = it * 256 + tid, p = c >> 3, c16 = c & 7;
      i32x4 kd = *(const i32x4*)(kh + p * 64 + c16 * 8);
      *(i32x4*)(kbase + p * 128 + ((c16 * 16) ^ ((p & 7) << 4))) = kd;
    }
    // ---- stage V transposed [d][p] swizzled, p-pairs packed as u32 ----
#pragma unroll
    for (int it = 0; it < 4; ++it) {
      int c = it * 256 + tid, p2 = c >> 3, c16 = c & 7, p = p2 * 2;
      u16x8 v0 = *(const u16x8*)(vh + p * 64 + c16 * 8);
      u16x8 v1 = *(const u16x8*)(vh + (p + 1) * 64 + c16 * 8);
#pragma unroll
      for (int j = 0; j < 8; ++j) {
        int d = c16 * 8 + j;
        unsigned pk = (unsigned)v0[j] | ((unsigned)v1[j] << 16);
        *(unsigned*)(vbase + d * 512 + ((p * 2) ^ ((d & 7) << 4))) = pk;
      }
    }
    // ---- q fragments ----
    const u16* qp = Q + (size_t)lrow * NE + n * EDIM + h * DDIM + lg * 8;
    bf16x8 aq0 = *(const bf16x8*)qp;
    bf16x8 aq1 = *(const bf16x8*)(qp + 32);
    __syncthreads();   // K, V staged
    // ---- S = q @ k^T ----
    f32x4 s[16];
#pragma unroll
    for (int ni = 0; ni < 16; ++ni) { f32x4 zv = {0.f,0.f,0.f,0.f}; s[ni] = zv; }
#pragma unroll
    for (int ni = 0; ni < 16; ++ni) {
      int row = ni * 16 + lr;
      const char* kr = kbase + row * 128;
      bf16x8 b0 = *(const bf16x8*)(kr + ((16 * lg) ^ ((row & 7) << 4)));
      bf16x8 b1 = *(const bf16x8*)(kr + ((64 + 16 * lg) ^ ((row & 7) << 4)));
      s[ni] = mfma16(aq0, b0, s[ni]);
      s[ni] = mfma16(aq1, b1, s[ni]);
    }
    // ---- softmax ----
    float mx[4], sm[4], inv[4];
#pragma unroll
    for (int j = 0; j < 4; ++j) mx[j] = -1e30f;
#pragma unroll
    for (int ni = 0; ni < 16; ++ni)
#pragma unroll
      for (int j = 0; j < 4; ++j) mx[j] = fmaxf(mx[j], s[ni][j]);
#pragma unroll
    for (int msk = 1; msk <= 8; msk <<= 1)
#pragma unroll
      for (int j = 0; j < 4; ++j) mx[j] = fmaxf(mx[j], __shfl_xor(mx[j], msk, 64));
#pragma unroll
    for (int j = 0; j < 4; ++j) sm[j] = 0.f;
#pragma unroll
    for (int ni = 0; ni < 16; ++ni)
#pragma unroll
      for (int j = 0; j < 4; ++j) {
        float e = __expf(s[ni][j] - mx[j]);
        s[ni][j] = e; sm[j] += e;
      }
#pragma unroll
    for (int msk = 1; msk <= 8; msk <<= 1)
#pragma unroll
      for (int j = 0; j < 4; ++j) sm[j] += __shfl_xor(sm[j], msk, 64);
#pragma unroll
    for (int j = 0; j < 4; ++j) inv[j] = 1.0f / sm[j];
    __syncthreads();   // all waves finished reading K from Ares
    // ---- normalize, head-mean, store P (bf16, per-wave quarter of Ares) ----
#pragma unroll
    for (int ni = 0; ni < 16; ++ni)
#pragma unroll
      for (int j = 0; j < 4; ++j) {
        float pv = s[ni][j] * inv[j];
        macc[ni][j] += pv * 0.0625f;
        int r = lg * 4 + j;
        *(u16*)(pbase + r * 512 + ((ni * 32 + lr * 2) ^ ((r & 7) << 4))) = f2b(pv);
      }
    // ---- O = P @ V  (P wave-private; no barrier needed) ----
    f32x4 o[4];
#pragma unroll
    for (int ni2 = 0; ni2 < 4; ++ni2) { f32x4 zv = {0.f,0.f,0.f,0.f}; o[ni2] = zv; }
#pragma unroll
    for (int ks = 0; ks < 8; ++ks) {
      bf16x8 a = *(const bf16x8*)(pbase + lr * 512 + ((ks * 64 + 16 * lg) ^ ((lr & 7) << 4)));
#pragma unroll
      for (int ni2 = 0; ni2 < 4; ++ni2) {
        int d = ni2 * 16 + lr;
        bf16x8 b = *(const bf16x8*)(vbase + d * 512 + ((ks * 64 + 16 * lg) ^ ((d & 7) << 4)));
        o[ni2] = mfma16(a, b, o[ni2]);
      }
    }
    // ---- write O tile ----
#pragma unroll
    for (int ni2 = 0; ni2 < 4; ++ni2)
#pragma unroll
      for (int j = 0; j < 4; ++j) {
        int gl = l0 + w * 16 + lg * 4 + j;
        Aout[(size_t)gl * NE + n * EDIM + h * DDIM + ni2 * 16 + lr] = f2b(o[ni2][j]);
      }
  }
  // ---- write head-mean attention weight partial ----
  float* awo = AWp + (size_t)blockIdx.z * AWSZ + (size_t)n * (LSEQ * KPDIM);
#pragma unroll
  for (int ni = 0; ni < 16; ++ni)
#pragma unroll
    for (int j = 0; j < 4; ++j) {
      int r = lg * 4 + j;
      awo[(size_t)(l0 + w * 16 + r) * KPDIM + ni * 16 + lr] = macc[ni][j];
    }
}

// ---------------------------------------------------------------------------
extern "C" void kernel_launch(void* const* d_in, const int* in_sizes, int n_in,
                              void* d_out, int out_size, void* d_ws, size_t ws_size,
                              hipStream_t stream) {
  const float* query = (const float*)d_in[0];
  const float* key   = (const float*)d_in[1];
  const float* value = (const float*)d_in[2];
  const float* ipw   = (const float*)d_in[3];
  const float* ipb   = (const float*)d_in[4];
  const float* ew    = (const float*)d_in[5];
  const float* eb    = (const float*)d_in[6];
  const float* fw    = (const float*)d_in[7];
  const float* fb    = (const float*)d_in[8];
  const float* ow    = (const float*)d_in[9];
  const float* ob    = (const float*)d_in[10];

  char* ws = (char*)d_ws;
  size_t off = 0;
  auto alloc = [&](size_t bytes) {
    void* p = ws + off;
    off += (bytes + 255) & ~(size_t)255;
    return p;
  };
  u16* qp    = (u16*)alloc((size_t)MROWS * EDIM * 2);
  u16* kp    = (u16*)alloc((size_t)MROWS * EDIM * 2);
  u16* vp    = (u16*)alloc((size_t)MROWS * EDIM * 2);
  u16* ao    = (u16*)alloc((size_t)MROWS * EDIM * 2);
  u16* kc    = (u16*)alloc((size_t)NB * KPDIM * EDIM * 2);   // head-major (N,H,Kp,D)
  u16* vc    = (u16*)alloc((size_t)NB * KPDIM * EDIM * 2);
  u16* w_in  = (u16*)alloc((size_t)3 * EDIM * EDIM * 2);
  u16* w_eT  = (u16*)alloc((size_t)EDIM * 8 * EDIM * 2);
  u16* w_fT  = (u16*)alloc((size_t)EDIM * 8 * EDIM * 2);
  u16* w_out = (u16*)alloc((size_t)EDIM * EDIM * 2);
  float* bq  = (float*)alloc(EDIM * 4);
  size_t base_needed = off;

  // X region, aliased in sequence: qkv16 (100.7 MB) -> split-K partials
  // (64 MB) -> AW head-group partials (67.1 MB). Lifetimes do not overlap.
  size_t qkv16_b = (size_t)3 * MROWS * EDIM * 2;
  size_t part_b  = (size_t)2 * 4 * 2048 * 1024 * 4;
  bool bigX  = ws_size >= base_needed + qkv16_b;
  bool midX  = ws_size >= base_needed + part_b;
  char* X = (char*)alloc(bigX ? qkv16_b : (midX ? part_b : 0));
  u16* qkv16 = (u16*)X;
  float* part = (float*)X;
  float* awp  = (float*)X;

  float* out_f = (float*)d_out;                        // (L, N, E)
  float* aw_f  = (float*)d_out + (size_t)MROWS * EDIM; // (N, L, Kp)

  // weight prep
  wconv<<<dim3(3072), 256, 0, stream>>>(ipw, w_in, 786432, 262144, 0.125f);
  wconv<<<dim3(1024), 256, 0, stream>>>(ow, w_out, 262144, 0, 1.0f);
  wtrans<<<dim3(16384, 2), 64, 0, stream>>>(ew, fw, w_eT, w_fT);
  bscale<<<dim3(4), 256, 0, stream>>>(ipb, bq);

  // q/k/v projections
  if (bigX) {
    castqkv<<<dim3(8192, 3), 256, 0, stream>>>(query, key, value, qkv16);
    gemm256<0, 0><<<dim3(64, 4, 3), 512, 0, stream>>>(
        qkv16, qkv16 + (size_t)MROWS * EDIM, qkv16 + (size_t)2 * MROWS * EDIM,
        w_in, w_in + 1048576, w_in + 2097152,
        bq, ipb + 1024, ipb + 2048,
        qp, kp, vp, MROWS, 1024, 1);
  } else {
    gemm_bt<2, 0><<<dim3(128, 8, 3), 256, 0, stream>>>(
        query, key, value,
        w_in, w_in + 1048576, w_in + 2097152,
        bq, ipb + 1024, ipb + 2048,
        qp, kp, vp, MROWS, 1024, 1);
  }

  // conv compression of k and v -> head-major kc/vc
  if (bigX || midX) {
    gemm256<1, 2><<<dim3(8, 4, 8), 512, 0, stream>>>(
        kp, vp, vp,
        w_eT, w_fT, w_fT,
        eb, fb, fb,
        part, part + (size_t)4 * 2048 * 1024, part,
        NB * KPDIM, 8192, 4);
    redc<<<dim3(2048, 2), 256, 0, stream>>>(part, eb, fb, kc, vc);
  } else {
    gemm_bt<1, 3><<<dim3(16, 8, 2), 256, 0, stream>>>(
        kp, vp, vp,
        w_eT, w_fT, w_fT,
        eb, fb, fb,
        kc, vc, vc, NB * KPDIM, 8192, 1);
  }

  // fused attention + head-mean weights
  if (bigX) {
    attn_fused<<<dim3(32, 8, 4), 256, 0, stream>>>(qp, kc, vc, ao, awp, 4);
    awred<<<dim3(4096), 256, 0, stream>>>(awp, aw_f);
  } else {
    attn_fused<<<dim3(32, 8, 1), 256, 0, stream>>>(qp, kc, vc, ao, aw_f, 16);
  }

  // output projection -> f32 d_out
  gemm256<0, 1><<<dim3(64, 4, 1), 512, 0, stream>>>(
      ao, ao, ao,
      w_out, w_out, w_out,
      ob, ob, ob,
      out_f, out_f, out_f, MROWS, 1024, 1);
}

// Round 6
// 490.312 us; speedup vs baseline: 1.3891x; 1.0558x over previous
//
#include <hip/hip_runtime.h>

typedef unsigned short u16;
typedef u16  u16x4 __attribute__((ext_vector_type(4)));
typedef u16  u16x8 __attribute__((ext_vector_type(8)));
typedef float f32x4 __attribute__((ext_vector_type(4)));
typedef int   i32x4 __attribute__((ext_vector_type(4)));
typedef __bf16 bf16x8 __attribute__((ext_vector_type(8)));

#define LSEQ 2048
#define NB 8
#define EDIM 1024
#define HNUM 16
#define DDIM 64
#define KPDIM 256
#define NE (NB*EDIM)       /* 8192 */
#define MROWS (LSEQ*NB)    /* 16384 */
#define AWSZ ((size_t)NB*LSEQ*KPDIM)  /* 4194304 */

__device__ __forceinline__ u16 f2b(float f) {
  unsigned u = __builtin_bit_cast(unsigned, f);
  u += 0x7fffu + ((u >> 16) & 1u);
  return (u16)(u >> 16);
}

__device__ __forceinline__ void gl_lds16(const void* g, void* l) {
  __builtin_amdgcn_global_load_lds(
      (const __attribute__((address_space(1))) void*)g,
      (__attribute__((address_space(3))) void*)l, 16, 0, 0);
}

__device__ __forceinline__ f32x4 mfma16(bf16x8 a, bf16x8 b, f32x4 c) {
  return __builtin_amdgcn_mfma_f32_16x16x32_bf16(a, b, c, 0, 0, 0);
}

// raw barrier + counted waits, NO sched_barrier fences (m141 lesson).
// "memory" clobber blocks memory-op motion; MFMA/read deps are SSA-tracked.
#define BAR()  __builtin_amdgcn_s_barrier()
#define WVM8() asm volatile("s_waitcnt vmcnt(8)" ::: "memory")
#define WVM0() asm volatile("s_waitcnt vmcnt(0)" ::: "memory")

// ---------------------------------------------------------------------------
// Weight prep kernels
// ---------------------------------------------------------------------------
__global__ void wconv(const float* __restrict__ src, u16* __restrict__ dst,
                      int n4, int scale_n4, float sc) {
  int i = blockIdx.x * blockDim.x + threadIdx.x;
  if (i >= n4) return;
  f32x4 v = ((const f32x4*)src)[i];
  float s = (i < scale_n4) ? sc : 1.0f;
  u16x4 o;
  o[0] = f2b(v[0] * s); o[1] = f2b(v[1] * s);
  o[2] = f2b(v[2] * s); o[3] = f2b(v[3] * s);
  ((u16x4*)dst)[i] = o;
}

// (O, I, 8) f32  ->  (O, t*E + i) bf16   (per-wave LDS transpose)
__global__ void wtrans(const float* __restrict__ ew, const float* __restrict__ fw,
                       u16* __restrict__ eT, u16* __restrict__ fT) {
  const float* src = blockIdx.y ? fw : ew;
  u16* dst = blockIdx.y ? fT : eT;
  int eo = blockIdx.x >> 4;
  int ei0 = (blockIdx.x & 15) * 64;
  int l = threadIdx.x;
  __shared__ u16 lds[8][64];
  const float* s = src + (size_t)eo * 8192 + (size_t)ei0 * 8 + l * 8;
  f32x4 a = *(const f32x4*)s;
  f32x4 b = *(const f32x4*)(s + 4);
  float v[8] = {a[0], a[1], a[2], a[3], b[0], b[1], b[2], b[3]};
#pragma unroll
  for (int t = 0; t < 8; ++t) lds[t][l] = f2b(v[t]);
  __syncthreads();
  int t = l >> 3, c = l & 7;
  i32x4 out = *(const i32x4*)&lds[t][c * 8];
  *(i32x4*)(dst + (size_t)eo * 8192 + t * 1024 + ei0 + c * 8) = out;
}

__global__ void bscale(const float* __restrict__ b, float* __restrict__ out) {
  int i = blockIdx.x * blockDim.x + threadIdx.x;
  if (i < EDIM) out[i] = b[i] * 0.125f;
}

// q/k/v f32 -> bf16, contiguous [3][MROWS][E]
__global__ void castqkv(const float* __restrict__ q, const float* __restrict__ k,
                        const float* __restrict__ v, u16* __restrict__ out) {
  const float* src = blockIdx.y == 0 ? q : (blockIdx.y == 1 ? k : v);
  size_t base = (size_t)blockIdx.y * ((size_t)MROWS * EDIM);
  size_t i = ((size_t)blockIdx.x * 256 + threadIdx.x) * 8;
  f32x4 v0 = *(const f32x4*)(src + i);
  f32x4 v1 = *(const f32x4*)(src + i + 4);
  u16x8 o;
  o[0] = f2b(v0[0]); o[1] = f2b(v0[1]); o[2] = f2b(v0[2]); o[3] = f2b(v0[3]);
  o[4] = f2b(v1[0]); o[5] = f2b(v1[1]); o[6] = f2b(v1[2]); o[7] = f2b(v1[3]);
  *(u16x8*)(out + base + i) = o;
}

// sum 4 split-K partials + bias -> bf16.
// K -> head-major (N,H,Kp,D), coalesced.
// V -> TRANSPOSED head-major (N,H,D,Kp) with 16B-chunk swizzle baked in:
//      u16 idx = (n*16+h)*16384 + d*256 + ((p>>3)^(d&7))*8 + (p&7)
// so attention can stage V with a straight linear global_load_lds.
__global__ void redc(const float* __restrict__ part, const float* __restrict__ eb,
                     const float* __restrict__ fb, u16* __restrict__ kc,
                     u16* __restrict__ vcT) {
  int zc = blockIdx.y;
  const float* p = part + (size_t)zc * 4 * 2048 * 1024;
  const float* bias = zc ? fb : eb;
  size_t i = ((size_t)blockIdx.x * 256 + threadIdx.x) * 4;
  f32x4 s = *(const f32x4*)(p + i);
  s += *(const f32x4*)(p + 2097152 + i);
  s += *(const f32x4*)(p + 2 * 2097152 + i);
  s += *(const f32x4*)(p + 3 * 2097152 + i);
  int e = (int)(i & 1023);
  int row = (int)(i >> 10);           // n*256 + p
  int n = row >> 8, pp = row & 255;
  int h = e >> 6, d = e & 63;         // e 4-aligned => d in {0,4,..,60}, h fixed
  f32x4 b = *(const f32x4*)(bias + e);
  if (zc == 0) {
    u16x4 o;
    o[0] = f2b(s[0] + b[0]); o[1] = f2b(s[1] + b[1]);
    o[2] = f2b(s[2] + b[2]); o[3] = f2b(s[3] + b[3]);
    *(u16x4*)(kc + (((size_t)(n * HNUM + h) * KPDIM + pp) * DDIM + d)) = o;
  } else {
    size_t base = (size_t)(n * HNUM + h) * (DDIM * KPDIM);
#pragma unroll
    for (int q = 0; q < 4; ++q) {
      int dq = d + q;
      vcT[base + dq * 256 + (((pp >> 3) ^ (dq & 7)) * 8) + (pp & 7)] =
          f2b(s[q] + b[q]);
    }
  }
}

// sum the 4 head-group AW partials
__global__ void awred(const float* __restrict__ awp, float* __restrict__ aw) {
  size_t i = ((size_t)blockIdx.x * 256 + threadIdx.x) * 4;
  f32x4 s = *(const f32x4*)(awp + i);
  s += *(const f32x4*)(awp + AWSZ + i);
  s += *(const f32x4*)(awp + 2 * AWSZ + i);
  s += *(const f32x4*)(awp + 3 * AWSZ + i);
  *(f32x4*)(aw + i) = s;
}

// ---------------------------------------------------------------------------
// 256x256 GEMM, 4-phase counted-vmcnt schedule (T3+T4), LDS XOR-swizzle (T2),
// setprio (T5). Raw s_barrier, NO sched_barrier fences — compiler keeps its
// fine-grained lgkmcnt scheduling (m97/m141).
//   AMODE 0: A bf16 rows contiguous (ld=K); AMODE 1: conv-gather
//   OUTMODE 0: bf16 C + bias; 1: f32 C + bias; 2: f32 split-K partial
// grid = (M/256, N/256, nz*kspl); block = 512 (8 waves, 2M x 4N)
// Hazard proof (unchanged from r5): reads of tile t covered by the t-1
// boundary vmcnt+barrier; stage(t+2->buf b) only after P2's trailing barrier
// (all waves' reads of b drained via their MFMA SSA deps + barrier); asm
// "memory" waits stop load/store motion; MFMA/read order is SSA-enforced.
// ---------------------------------------------------------------------------
template<int AMODE, int OUTMODE>
__global__ __launch_bounds__(512, 2)
void gemm256(const void* A0p, const void* A1p, const void* A2p,
             const u16* B0p, const u16* B1p, const u16* B2p,
             const float* b0p, const float* b1p, const float* b2p,
             void* C0p, void* C1p, void* C2p,
             int M, int K, int kspl) {
  const int zc = blockIdx.z / kspl, sp = blockIdx.z % kspl;
  const void* Ap = zc == 0 ? A0p : (zc == 1 ? A1p : A2p);
  const u16* Bp = zc == 0 ? B0p : (zc == 1 ? B1p : B2p);
  const float* biasp = zc == 0 ? b0p : (zc == 1 ? b1p : b2p);
  void* Cp = zc == 0 ? C0p : (zc == 1 ? C1p : C2p);

  __shared__ u16 lds[2][2][256 * 64];   // [buf][A=0/B=1][row*64 + swz-chunk*8]

  const int tid = threadIdx.x;
  const int w = tid >> 6, lane = tid & 63;
  const int lr = lane & 15, lg = lane >> 4;
  const int wr = w >> 2, wc = w & 3;            // 2M x 4N waves
  const int m0 = blockIdx.x * 256, n0 = blockIdx.y * 256;
  const int kper = K / kspl, kbase = sp * kper, nt = kper >> 6;

  f32x4 acc[8][4];
#pragma unroll
  for (int mi = 0; mi < 8; ++mi)
#pragma unroll
    for (int ni = 0; ni < 4; ++ni) {
      f32x4 zv = {0.f, 0.f, 0.f, 0.f};
      acc[mi][ni] = zv;
    }

  auto stage = [&](int buf, int kt) {
    const int k0 = kbase + (kt << 6);
#pragma unroll
    for (int i = 0; i < 4; ++i) {
      int c = i * 512 + tid;                 // 0..2047
      int row = c >> 3, j = c & 7, js = j ^ (row & 7);
      gl_lds16(Bp + (size_t)(n0 + row) * K + k0 + js * 8, &lds[buf][1][c * 8]);
    }
    if (AMODE == 0) {
      const u16* Ab = (const u16*)Ap;
#pragma unroll
      for (int i = 0; i < 4; ++i) {
        int c = i * 512 + tid;
        int row = c >> 3, j = c & 7, js = j ^ (row & 7);
        gl_lds16(Ab + (size_t)(m0 + row) * K + k0 + js * 8, &lds[buf][0][c * 8]);
      }
    } else {  // conv gather: m=(nn,p), k=(t,ei); k0 mult of 64 so no 1024-cross
      const u16* Ab = (const u16*)Ap;
#pragma unroll
      for (int i = 0; i < 4; ++i) {
        int c = i * 512 + tid;
        int row = c >> 3, j = c & 7, js = j ^ (row & 7);
        int m = m0 + row;
        int nn = m >> 8, p = m & 255;
        int k = k0 + js * 8;
        gl_lds16(Ab + (size_t)(p * 8 + (k >> 10)) * NE + nn * EDIM + (k & 1023),
                 &lds[buf][0][c * 8]);
      }
    }
  };

  auto LDA = [&](int buf, int row, int ks) -> bf16x8 {
    return *(const bf16x8*)&lds[buf][0][row * 64 + (((ks * 4 + lg) ^ (row & 7)) << 3)];
  };
  auto LDB = [&](int buf, int row, int ks) -> bf16x8 {
    return *(const bf16x8*)&lds[buf][1][row * 64 + (((ks * 4 + lg) ^ (row & 7)) << 3)];
  };

  // prologue: tiles 0 and 1 in flight; tile 0 must be landed
  stage(0, 0);
  if (nt > 1) { stage(1, 1); WVM8(); } else { WVM0(); }
  BAR();

  for (int t = 0; t < nt; ++t) {
    const int b = t & 1;
    bf16x8 a0[4][2], a1[4][2], bq0[2][2], bq1[2][2];
    // ---- P0 ----
#pragma unroll
    for (int mi = 0; mi < 4; ++mi)
#pragma unroll
      for (int ks = 0; ks < 2; ++ks)
        a0[mi][ks] = LDA(b, wr * 128 + mi * 16 + lr, ks);
#pragma unroll
    for (int ni = 0; ni < 2; ++ni)
#pragma unroll
      for (int ks = 0; ks < 2; ++ks)
        bq0[ni][ks] = LDB(b, wc * 64 + ni * 16 + lr, ks);
    BAR();
    __builtin_amdgcn_s_setprio(1);
#pragma unroll
    for (int mi = 0; mi < 4; ++mi)
#pragma unroll
      for (int ni = 0; ni < 2; ++ni)
#pragma unroll
        for (int ks = 0; ks < 2; ++ks)
          acc[mi][ni] = mfma16(a0[mi][ks], bq0[ni][ks], acc[mi][ni]);
    __builtin_amdgcn_s_setprio(0);
    BAR();
    // ---- P1 ----
#pragma unroll
    for (int ni = 0; ni < 2; ++ni)
#pragma unroll
      for (int ks = 0; ks < 2; ++ks)
        bq1[ni][ks] = LDB(b, wc * 64 + (ni + 2) * 16 + lr, ks);
    BAR();
    __builtin_amdgcn_s_setprio(1);
#pragma unroll
    for (int mi = 0; mi < 4; ++mi)
#pragma unroll
      for (int ni = 0; ni < 2; ++ni)
#pragma unroll
        for (int ks = 0; ks < 2; ++ks)
          acc[mi][ni + 2] = mfma16(a0[mi][ks], bq1[ni][ks], acc[mi][ni + 2]);
    __builtin_amdgcn_s_setprio(0);
    BAR();
    // ---- P2 ----
#pragma unroll
    for (int mi = 0; mi < 4; ++mi)
#pragma unroll
      for (int ks = 0; ks < 2; ++ks)
        a1[mi][ks] = LDA(b, wr * 128 + 64 + mi * 16 + lr, ks);
    BAR();
    __builtin_amdgcn_s_setprio(1);
#pragma unroll
    for (int mi = 0; mi < 4; ++mi)
#pragma unroll
      for (int ni = 0; ni < 2; ++ni)
#pragma unroll
        for (int ks = 0; ks < 2; ++ks)
          acc[mi + 4][ni + 2] = mfma16(a1[mi][ks], bq1[ni][ks], acc[mi + 4][ni + 2]);
    __builtin_amdgcn_s_setprio(0);
    BAR();
    // ---- P3 ----
    if (t + 2 < nt) stage(b, t + 2);
    BAR();
    __builtin_amdgcn_s_setprio(1);
#pragma unroll
    for (int mi = 0; mi < 4; ++mi)
#pragma unroll
      for (int ni = 0; ni < 2; ++ni)
#pragma unroll
        for (int ks = 0; ks < 2; ++ks)
          acc[mi + 4][ni] = mfma16(a1[mi][ks], bq0[ni][ks], acc[mi + 4][ni]);
    __builtin_amdgcn_s_setprio(0);
    // ---- boundary: tile t+1 landed; keep t+2's 8 loads in flight ----
    if (t + 1 < nt) {
      if (t + 2 < nt) { WVM8(); } else { WVM0(); }
    }
    BAR();
  }

  // ---- epilogue ----
#pragma unroll
  for (int ni = 0; ni < 4; ++ni) {
    const int col = n0 + wc * 64 + ni * 16 + lr;
    const float bv = (OUTMODE == 2) ? 0.f : biasp[col];
#pragma unroll
    for (int mi = 0; mi < 8; ++mi)
#pragma unroll
      for (int j = 0; j < 4; ++j) {
        const int row = m0 + wr * 128 + mi * 16 + lg * 4 + j;
        const float v = acc[mi][ni][j] + bv;
        if (OUTMODE == 2)
          ((float*)Cp)[(size_t)sp * M * 1024 + (size_t)row * 1024 + col] = v;
        else if (OUTMODE == 1)
          ((float*)Cp)[(size_t)row * 1024 + col] = v;
        else
          ((u16*)Cp)[(size_t)row * 1024 + col] = f2b(v);
      }
  }
}

// ---------------------------------------------------------------------------
// Legacy 128x128 GEMM — fallback paths only (small workspace)
//   OUTMODE 3: bf16+bias -> head-major (N,H,Kp,D)
//   OUTMODE 4: bf16+bias -> transposed swizzled (N,H,D,Kp)  (V^T fallback)
// ---------------------------------------------------------------------------
template<int AMODE, int OUTMODE>
__global__ __launch_bounds__(256)
void gemm_bt(const void* A0p, const void* A1p, const void* A2p,
             const u16* B0p, const u16* B1p, const u16* B2p,
             const float* b0p, const float* b1p, const float* b2p,
             void* C0p, void* C1p, void* C2p,
             int M, int K, int kspl) {
  const int zc = blockIdx.z / kspl;
  const int sp = blockIdx.z % kspl;
  const void* Ap = zc == 0 ? A0p : (zc == 1 ? A1p : A2p);
  const u16* Bp = zc == 0 ? B0p : (zc == 1 ? B1p : B2p);
  const float* biasp = zc == 0 ? b0p : (zc == 1 ? b1p : b2p);
  void* Cp = zc == 0 ? C0p : (zc == 1 ? C1p : C2p);

  __shared__ u16 Alds[128 * 64];
  __shared__ u16 Blds[128 * 64];

  const int tid = threadIdx.x;
  const int w = tid >> 6, lane = tid & 63;
  const int lr = lane & 15, lg = lane >> 4;
  const int m0 = blockIdx.x * 128, n0 = blockIdx.y * 128;
  const int wr = (w >> 1) * 64, wc = (w & 1) * 64;
  const int brow = lane >> 3;
  const int bcol = (lane & 7) * 8;

  f32x4 acc[4][4];
#pragma unroll
  for (int mi = 0; mi < 4; ++mi)
#pragma unroll
    for (int ni = 0; ni < 4; ++ni) {
      f32x4 zv = {0.f, 0.f, 0.f, 0.f};
      acc[mi][ni] = zv;
    }

  const int kper = K / kspl;
  const int ktn = kper >> 6;
  const int kb = sp * kper;
  for (int kt = 0; kt < ktn; ++kt) {
    const int k0 = kb + (kt << 6);
    __syncthreads();
#pragma unroll
    for (int i = 0; i < 4; ++i) {
      const int c = w * 4 + i;
      const int row = c * 8 + brow;
      gl_lds16(Bp + (size_t)(n0 + row) * K + k0 + bcol, &Blds[c * 512]);
    }
    if (AMODE == 2) {
      const float* Af = (const float*)Ap;
#pragma unroll
      for (int i = 0; i < 4; ++i) {
        const int c = i * 256 + tid;
        const int row = c >> 3, k8 = (c & 7) * 8;
        const float* s = Af + (size_t)(m0 + row) * K + k0 + k8;
        f32x4 v0 = *(const f32x4*)s;
        f32x4 v1 = *(const f32x4*)(s + 4);
        u16x8 pk;
        pk[0] = f2b(v0[0]); pk[1] = f2b(v0[1]); pk[2] = f2b(v0[2]); pk[3] = f2b(v0[3]);
        pk[4] = f2b(v1[0]); pk[5] = f2b(v1[1]); pk[6] = f2b(v1[2]); pk[7] = f2b(v1[3]);
        *(u16x8*)&Alds[row * 64 + k8] = pk;
      }
    } else if (AMODE == 0) {
      const u16* Ab = (const u16*)Ap;
#pragma unroll
      for (int i = 0; i < 4; ++i) {
        const int c = w * 4 + i;
        const int row = c * 8 + brow;
        gl_lds16(Ab + (size_t)(m0 + row) * K + k0 + bcol, &Alds[c * 512]);
      }
    } else {
      const u16* Ab = (const u16*)Ap;
#pragma unroll
      for (int i = 0; i < 4; ++i) {
        const int c = w * 4 + i;
        const int m = m0 + c * 8 + brow;
        const int nn = m >> 8, p = m & 255;
        const int k = k0 + bcol;
        gl_lds16(Ab + (size_t)(p * 8 + (k >> 10)) * NE + nn * EDIM + (k & 1023),
                 &Alds[c * 512]);
      }
    }
    __syncthreads();
#pragma unroll
    for (int ks = 0; ks < 2; ++ks) {
      bf16x8 af[4], bf[4];
#pragma unroll
      for (int mi = 0; mi < 4; ++mi)
        af[mi] = *(const bf16x8*)&Alds[(wr + mi * 16 + lr) * 64 + ks * 32 + lg * 8];
#pragma unroll
      for (int ni = 0; ni < 4; ++ni)
        bf[ni] = *(const bf16x8*)&Blds[(wc + ni * 16 + lr) * 64 + ks * 32 + lg * 8];
#pragma unroll
      for (int mi = 0; mi < 4; ++mi)
#pragma unroll
        for (int ni = 0; ni < 4; ++ni)
          acc[mi][ni] = mfma16(af[mi], bf[ni], acc[mi][ni]);
    }
  }
#pragma unroll
  for (int ni = 0; ni < 4; ++ni) {
    const int col = n0 + wc + ni * 16 + lr;
    const float bv = (OUTMODE == 2) ? 0.f : biasp[col];
#pragma unroll
    for (int mi = 0; mi < 4; ++mi)
#pragma unroll
      for (int j = 0; j < 4; ++j) {
        const int row = m0 + wr + mi * 16 + lg * 4 + j;
        const float v = acc[mi][ni][j] + bv;
        if (OUTMODE == 4) {
          const int nn = row >> 8, pp = row & 255, h = col >> 6, d = col & 63;
          ((u16*)Cp)[(size_t)(nn * HNUM + h) * (DDIM * KPDIM) + d * 256 +
                     (((pp >> 3) ^ (d & 7)) * 8) + (pp & 7)] = f2b(v);
        } else if (OUTMODE == 3) {
          const int nn = row >> 8, pp = row & 255, h = col >> 6, d = col & 63;
          ((u16*)Cp)[((size_t)(nn * HNUM + h) * KPDIM + pp) * DDIM + d] = f2b(v);
        } else if (OUTMODE == 2)
          ((float*)Cp)[(size_t)sp * M * 1024 + (size_t)row * 1024 + col] = v;
        else if (OUTMODE == 1)
          ((float*)Cp)[(size_t)row * 1024 + col] = v;
        else
          ((u16*)Cp)[(size_t)row * 1024 + col] = f2b(v);
      }
  }
}

// ---------------------------------------------------------------------------
// Fused attention v3: block = (64 q-rows, n, head-group), hpg heads each.
// Kc (N,H,Kp,D); VcT (N,H,D,Kp) PRE-transposed + chunk-swizzled in global.
// Both K and V staged via async global_load_lds (source-swizzled K, linear V).
// LDS 64 KB: Ares = K then per-wave P overlay; Bres = V^T.
// ---------------------------------------------------------------------------
__global__ __launch_bounds__(256)
void attn_fused(const u16* __restrict__ Q, const u16* __restrict__ Kc,
                const u16* __restrict__ VcT, u16* __restrict__ Aout,
                float* __restrict__ AWp, int hpg) {
  __shared__ u16 Ares[256 * 64];   // K [p][d] chunk-swizzled -> P quarters
  __shared__ u16 Bres[64 * 256];   // V^T [d][p] chunk-swizzled
  const int tid = threadIdx.x;
  const int w = tid >> 6, lane = tid & 63;
  const int lr = lane & 15, lg = lane >> 4;
  const int n = blockIdx.y;
  const int l0 = blockIdx.x * 64;
  const int lrow = l0 + w * 16 + lr;
  char* kbase = (char*)Ares;
  char* vbase = (char*)Bres;
  char* pbase = (char*)Ares + w * 8192;   // 16 rows x 256 x 2B per wave

  f32x4 macc[16];
#pragma unroll
  for (int ni = 0; ni < 16; ++ni) { f32x4 zv = {0.f,0.f,0.f,0.f}; macc[ni] = zv; }

  for (int hh = 0; hh < hpg; ++hh) {
    const int h = blockIdx.z * hpg + hh;
    const u16* kh = Kc + (size_t)(n * HNUM + h) * (KPDIM * DDIM);
    const u16* vh = VcT + (size_t)(n * HNUM + h) * (DDIM * KPDIM);
    __syncthreads();   // prev head fully consumed (P + V reads drained)
    // ---- stage K via gl_lds: dest linear, source chunk pre-swizzled ----
#pragma unroll
    for (int it = 0; it < 8; ++it) {
      int c = it * 256 + tid;            // chunk: row p = c>>3, j = c&7
      int p = c >> 3, j = c & 7;
      gl_lds16(kh + p * 64 + ((j ^ (p & 7)) << 3), kbase + c * 16);
    }
    // ---- stage V^T via gl_lds: straight linear copy (swizzle in global) ----
#pragma unroll
    for (int it = 0; it < 8; ++it) {
      int c = it * 256 + tid;
      gl_lds16(vh + c * 8, vbase + c * 16);
    }
    // ---- q fragments ----
    const u16* qp = Q + (size_t)lrow * NE + n * EDIM + h * DDIM + lg * 8;
    bf16x8 aq0 = *(const bf16x8*)qp;
    bf16x8 aq1 = *(const bf16x8*)(qp + 32);
    __syncthreads();   // drains vmcnt(0): K,V staged
    // ---- S = q @ k^T : 16 rows x 256 cols per wave ----
    f32x4 s[16];
#pragma unroll
    for (int ni = 0; ni < 16; ++ni) { f32x4 zv = {0.f,0.f,0.f,0.f}; s[ni] = zv; }
#pragma unroll
    for (int ni = 0; ni < 16; ++ni) {
      int row = ni * 16 + lr;
      const char* kr = kbase + row * 128;
      bf16x8 b0 = *(const bf16x8*)(kr + ((lg ^ (row & 7)) << 4));
      bf16x8 b1 = *(const bf16x8*)(kr + (((4 + lg) ^ (row & 7)) << 4));
      s[ni] = mfma16(aq0, b0, s[ni]);
      s[ni] = mfma16(aq1, b1, s[ni]);
    }
    // ---- softmax (row r = lg*4+j lives in 16-lane group lg) ----
    float mx[4], sm[4], inv[4];
#pragma unroll
    for (int j = 0; j < 4; ++j) mx[j] = -1e30f;
#pragma unroll
    for (int ni = 0; ni < 16; ++ni)
#pragma unroll
      for (int j = 0; j < 4; ++j) mx[j] = fmaxf(mx[j], s[ni][j]);
#pragma unroll
    for (int msk = 1; msk <= 8; msk <<= 1)
#pragma unroll
      for (int j = 0; j < 4; ++j) mx[j] = fmaxf(mx[j], __shfl_xor(mx[j], msk, 64));
#pragma unroll
    for (int j = 0; j < 4; ++j) sm[j] = 0.f;
#pragma unroll
    for (int ni = 0; ni < 16; ++ni)
#pragma unroll
      for (int j = 0; j < 4; ++j) {
        float e = __expf(s[ni][j] - mx[j]);
        s[ni][j] = e; sm[j] += e;
      }
#pragma unroll
    for (int msk = 1; msk <= 8; msk <<= 1)
#pragma unroll
      for (int j = 0; j < 4; ++j) sm[j] += __shfl_xor(sm[j], msk, 64);
#pragma unroll
    for (int j = 0; j < 4; ++j) inv[j] = 1.0f / sm[j];
    __syncthreads();   // all waves finished reading K from Ares
    // ---- normalize, head-mean, store P (bf16, per-wave quarter of Ares) ----
#pragma unroll
    for (int ni = 0; ni < 16; ++ni)
#pragma unroll
      for (int j = 0; j < 4; ++j) {
        float pv = s[ni][j] * inv[j];
        macc[ni][j] += pv * 0.0625f;
        int r = lg * 4 + j;
        *(u16*)(pbase + r * 512 + ((ni * 32 + lr * 2) ^ ((r & 7) << 4))) = f2b(pv);
      }
    // ---- O = P @ V  (P wave-private; no barrier needed) ----
    f32x4 o[4];
#pragma unroll
    for (int ni2 = 0; ni2 < 4; ++ni2) { f32x4 zv = {0.f,0.f,0.f,0.f}; o[ni2] = zv; }
#pragma unroll
    for (int ks = 0; ks < 8; ++ks) {
      bf16x8 a = *(const bf16x8*)(pbase + lr * 512 + ((ks * 64 + 16 * lg) ^ ((lr & 7) << 4)));
#pragma unroll
      for (int ni2 = 0; ni2 < 4; ++ni2) {
        int d = ni2 * 16 + lr;
        bf16x8 b = *(const bf16x8*)(vbase + d * 512 + (((ks * 4 + lg) ^ (d & 7)) << 4));
        o[ni2] = mfma16(a, b, o[ni2]);
      }
    }
    // ---- write O tile ----
#pragma unroll
    for (int ni2 = 0; ni2 < 4; ++ni2)
#pragma unroll
      for (int j = 0; j < 4; ++j) {
        int gl = l0 + w * 16 + lg * 4 + j;
        Aout[(size_t)gl * NE + n * EDIM + h * DDIM + ni2 * 16 + lr] = f2b(o[ni2][j]);
      }
  }
  // ---- write head-mean attention weight partial ----
  float* awo = AWp + (size_t)blockIdx.z * AWSZ + (size_t)n * (LSEQ * KPDIM);
#pragma unroll
  for (int ni = 0; ni < 16; ++ni)
#pragma unroll
    for (int j = 0; j < 4; ++j) {
      int r = lg * 4 + j;
      awo[(size_t)(l0 + w * 16 + r) * KPDIM + ni * 16 + lr] = macc[ni][j];
    }
}

// ---------------------------------------------------------------------------
extern "C" void kernel_launch(void* const* d_in, const int* in_sizes, int n_in,
                              void* d_out, int out_size, void* d_ws, size_t ws_size,
                              hipStream_t stream) {
  const float* query = (const float*)d_in[0];
  const float* key   = (const float*)d_in[1];
  const float* value = (const float*)d_in[2];
  const float* ipw   = (const float*)d_in[3];
  const float* ipb   = (const float*)d_in[4];
  const float* ew    = (const float*)d_in[5];
  const float* eb    = (const float*)d_in[6];
  const float* fw    = (const float*)d_in[7];
  const float* fb    = (const float*)d_in[8];
  const float* ow    = (const float*)d_in[9];
  const float* ob    = (const float*)d_in[10];

  char* ws = (char*)d_ws;
  size_t off = 0;
  auto alloc = [&](size_t bytes) {
    void* p = ws + off;
    off += (bytes + 255) & ~(size_t)255;
    return p;
  };
  u16* qp    = (u16*)alloc((size_t)MROWS * EDIM * 2);
  u16* kp    = (u16*)alloc((size_t)MROWS * EDIM * 2);
  u16* vp    = (u16*)alloc((size_t)MROWS * EDIM * 2);
  u16* ao    = (u16*)alloc((size_t)MROWS * EDIM * 2);
  u16* kc    = (u16*)alloc((size_t)NB * KPDIM * EDIM * 2);   // (N,H,Kp,D)
  u16* vcT   = (u16*)alloc((size_t)NB * KPDIM * EDIM * 2);   // (N,H,D,Kp) swz
  u16* w_in  = (u16*)alloc((size_t)3 * EDIM * EDIM * 2);
  u16* w_eT  = (u16*)alloc((size_t)EDIM * 8 * EDIM * 2);
  u16* w_fT  = (u16*)alloc((size_t)EDIM * 8 * EDIM * 2);
  u16* w_out = (u16*)alloc((size_t)EDIM * EDIM * 2);
  float* bq  = (float*)alloc(EDIM * 4);
  size_t base_needed = off;

  // X region, aliased in sequence: qkv16 (100.7 MB) -> split-K partials
  // (64 MB) -> AW head-group partials (67.1 MB). Lifetimes do not overlap.
  size_t qkv16_b = (size_t)3 * MROWS * EDIM * 2;
  size_t part_b  = (size_t)2 * 4 * 2048 * 1024 * 4;
  bool bigX  = ws_size >= base_needed + qkv16_b;
  bool midX  = ws_size >= base_needed + part_b;
  char* X = (char*)alloc(bigX ? qkv16_b : (midX ? part_b : 0));
  u16* qkv16 = (u16*)X;
  float* part = (float*)X;
  float* awp  = (float*)X;

  float* out_f = (float*)d_out;                        // (L, N, E)
  float* aw_f  = (float*)d_out + (size_t)MROWS * EDIM; // (N, L, Kp)

  // weight prep
  wconv<<<dim3(3072), 256, 0, stream>>>(ipw, w_in, 786432, 262144, 0.125f);
  wconv<<<dim3(1024), 256, 0, stream>>>(ow, w_out, 262144, 0, 1.0f);
  wtrans<<<dim3(16384, 2), 64, 0, stream>>>(ew, fw, w_eT, w_fT);
  bscale<<<dim3(4), 256, 0, stream>>>(ipb, bq);

  // q/k/v projections
  if (bigX) {
    castqkv<<<dim3(8192, 3), 256, 0, stream>>>(query, key, value, qkv16);
    gemm256<0, 0><<<dim3(64, 4, 3), 512, 0, stream>>>(
        qkv16, qkv16 + (size_t)MROWS * EDIM, qkv16 + (size_t)2 * MROWS * EDIM,
        w_in, w_in + 1048576, w_in + 2097152,
        bq, ipb + 1024, ipb + 2048,
        qp, kp, vp, MROWS, 1024, 1);
  } else {
    gemm_bt<2, 0><<<dim3(128, 8, 3), 256, 0, stream>>>(
        query, key, value,
        w_in, w_in + 1048576, w_in + 2097152,
        bq, ipb + 1024, ipb + 2048,
        qp, kp, vp, MROWS, 1024, 1);
  }

  // conv compression of k and v -> kc (head-major) / vcT (transposed swz)
  if (bigX || midX) {
    gemm256<1, 2><<<dim3(8, 4, 8), 512, 0, stream>>>(
        kp, vp, vp,
        w_eT, w_fT, w_fT,
        eb, fb, fb,
        part, part + (size_t)4 * 2048 * 1024, part,
        NB * KPDIM, 8192, 4);
    redc<<<dim3(2048, 2), 256, 0, stream>>>(part, eb, fb, kc, vcT);
  } else {
    gemm_bt<1, 3><<<dim3(16, 8, 1), 256, 0, stream>>>(
        kp, kp, kp, w_eT, w_eT, w_eT, eb, eb, eb,
        kc, kc, kc, NB * KPDIM, 8192, 1);
    gemm_bt<1, 4><<<dim3(16, 8, 1), 256, 0, stream>>>(
        vp, vp, vp, w_fT, w_fT, w_fT, fb, fb, fb,
        vcT, vcT, vcT, NB * KPDIM, 8192, 1);
  }

  // fused attention + head-mean weights
  if (bigX) {
    attn_fused<<<dim3(32, 8, 4), 256, 0, stream>>>(qp, kc, vcT, ao, awp, 4);
    awred<<<dim3(4096), 256, 0, stream>>>(awp, aw_f);
  } else {
    attn_fused<<<dim3(32, 8, 1), 256, 0, stream>>>(qp, kc, vcT, ao, aw_f, 16);
  }

  // output projection -> f32 d_out
  gemm256<0, 1><<<dim3(64, 4, 1), 512, 0, stream>>>(
      ao, ao, ao,
      w_out, w_out, w_out,
      ob, ob, ob,
      out_f, out_f, out_f, MROWS, 1024, 1);
}

// Round 8
// 451.790 us; speedup vs baseline: 1.5076x; 1.0853x over previous
//
#include <hip/hip_runtime.h>

typedef unsigned short u16;
typedef u16  u16x4 __attribute__((ext_vector_type(4)));
typedef u16  u16x8 __attribute__((ext_vector_type(8)));
typedef float f32x4 __attribute__((ext_vector_type(4)));
typedef int   i32x4 __attribute__((ext_vector_type(4)));
typedef __bf16 bf16x8 __attribute__((ext_vector_type(8)));

#define LSEQ 2048
#define NB 8
#define EDIM 1024
#define HNUM 16
#define DDIM 64
#define KPDIM 256
#define NE (NB*EDIM)       /* 8192 */
#define MROWS (LSEQ*NB)    /* 16384 */
#define AWSZ ((size_t)NB*LSEQ*KPDIM)  /* 4194304 */

__device__ __forceinline__ u16 f2b(float f) {
  unsigned u = __builtin_bit_cast(unsigned, f);
  u += 0x7fffu + ((u >> 16) & 1u);
  return (u16)(u >> 16);
}

__device__ __forceinline__ void gl_lds16(const void* g, void* l) {
  __builtin_amdgcn_global_load_lds(
      (const __attribute__((address_space(1))) void*)g,
      (__attribute__((address_space(3))) void*)l, 16, 0, 0);
}

__device__ __forceinline__ f32x4 mfma16(bf16x8 a, bf16x8 b, f32x4 c) {
  return __builtin_amdgcn_mfma_f32_16x16x32_bf16(a, b, c, 0, 0, 0);
}

#define BAR()   __builtin_amdgcn_s_barrier()
#define LGKM0() asm volatile("s_waitcnt lgkmcnt(0)" ::: "memory")
#define WVM6()  asm volatile("s_waitcnt vmcnt(6)" ::: "memory")
#define WVM0()  asm volatile("s_waitcnt vmcnt(0)" ::: "memory")

// ---------------------------------------------------------------------------
// Weight prep kernels
// ---------------------------------------------------------------------------
__global__ void wconv(const float* __restrict__ src, u16* __restrict__ dst,
                      int n4, int scale_n4, float sc) {
  int i = blockIdx.x * blockDim.x + threadIdx.x;
  if (i >= n4) return;
  f32x4 v = ((const f32x4*)src)[i];
  float s = (i < scale_n4) ? sc : 1.0f;
  u16x4 o;
  o[0] = f2b(v[0] * s); o[1] = f2b(v[1] * s);
  o[2] = f2b(v[2] * s); o[3] = f2b(v[3] * s);
  ((u16x4*)dst)[i] = o;
}

// (O, I, 8) f32  ->  (O, t*E + i) bf16   (per-wave LDS transpose)
__global__ void wtrans(const float* __restrict__ ew, const float* __restrict__ fw,
                       u16* __restrict__ eT, u16* __restrict__ fT) {
  const float* src = blockIdx.y ? fw : ew;
  u16* dst = blockIdx.y ? fT : eT;
  int eo = blockIdx.x >> 4;
  int ei0 = (blockIdx.x & 15) * 64;
  int l = threadIdx.x;
  __shared__ u16 lds[8][64];
  const float* s = src + (size_t)eo * 8192 + (size_t)ei0 * 8 + l * 8;
  f32x4 a = *(const f32x4*)s;
  f32x4 b = *(const f32x4*)(s + 4);
  float v[8] = {a[0], a[1], a[2], a[3], b[0], b[1], b[2], b[3]};
#pragma unroll
  for (int t = 0; t < 8; ++t) lds[t][l] = f2b(v[t]);
  __syncthreads();
  int t = l >> 3, c = l & 7;
  i32x4 out = *(const i32x4*)&lds[t][c * 8];
  *(i32x4*)(dst + (size_t)eo * 8192 + t * 1024 + ei0 + c * 8) = out;
}

__global__ void bscale(const float* __restrict__ b, float* __restrict__ out) {
  int i = blockIdx.x * blockDim.x + threadIdx.x;
  if (i < EDIM) out[i] = b[i] * 0.125f;
}

// q/k/v f32 -> bf16, contiguous [3][MROWS][E]
__global__ void castqkv(const float* __restrict__ q, const float* __restrict__ k,
                        const float* __restrict__ v, u16* __restrict__ out) {
  const float* src = blockIdx.y == 0 ? q : (blockIdx.y == 1 ? k : v);
  size_t base = (size_t)blockIdx.y * ((size_t)MROWS * EDIM);
  size_t i = ((size_t)blockIdx.x * 256 + threadIdx.x) * 8;
  f32x4 v0 = *(const f32x4*)(src + i);
  f32x4 v1 = *(const f32x4*)(src + i + 4);
  u16x8 o;
  o[0] = f2b(v0[0]); o[1] = f2b(v0[1]); o[2] = f2b(v0[2]); o[3] = f2b(v0[3]);
  o[4] = f2b(v1[0]); o[5] = f2b(v1[1]); o[6] = f2b(v1[2]); o[7] = f2b(v1[3]);
  *(u16x8*)(out + base + i) = o;
}

// sum 4 split-K partials + bias -> bf16.
// K -> head-major (N,H,Kp,D). V -> transposed (N,H,D,Kp) chunk-swizzled.
__global__ void redc(const float* __restrict__ part, const float* __restrict__ eb,
                     const float* __restrict__ fb, u16* __restrict__ kc,
                     u16* __restrict__ vcT) {
  int zc = blockIdx.y;
  const float* p = part + (size_t)zc * 4 * 2048 * 1024;
  const float* bias = zc ? fb : eb;
  size_t i = ((size_t)blockIdx.x * 256 + threadIdx.x) * 4;
  f32x4 s = *(const f32x4*)(p + i);
  s += *(const f32x4*)(p + 2097152 + i);
  s += *(const f32x4*)(p + 2 * 2097152 + i);
  s += *(const f32x4*)(p + 3 * 2097152 + i);
  int e = (int)(i & 1023);
  int row = (int)(i >> 10);           // n*256 + p
  int n = row >> 8, pp = row & 255;
  int h = e >> 6, d = e & 63;
  f32x4 b = *(const f32x4*)(bias + e);
  if (zc == 0) {
    u16x4 o;
    o[0] = f2b(s[0] + b[0]); o[1] = f2b(s[1] + b[1]);
    o[2] = f2b(s[2] + b[2]); o[3] = f2b(s[3] + b[3]);
    *(u16x4*)(kc + (((size_t)(n * HNUM + h) * KPDIM + pp) * DDIM + d)) = o;
  } else {
    size_t base = (size_t)(n * HNUM + h) * (DDIM * KPDIM);
#pragma unroll
    for (int q = 0; q < 4; ++q) {
      int dq = d + q;
      vcT[base + dq * 256 + (((pp >> 3) ^ (dq & 7)) * 8) + (pp & 7)] =
          f2b(s[q] + b[q]);
    }
  }
}

// sum the 4 head-group AW partials
__global__ void awred(const float* __restrict__ awp, float* __restrict__ aw) {
  size_t i = ((size_t)blockIdx.x * 256 + threadIdx.x) * 4;
  f32x4 s = *(const f32x4*)(awp + i);
  s += *(const f32x4*)(awp + AWSZ + i);
  s += *(const f32x4*)(awp + 2 * AWSZ + i);
  s += *(const f32x4*)(awp + 3 * AWSZ + i);
  *(f32x4*)(aw + i) = s;
}

// ---------------------------------------------------------------------------
// 256x256 GEMM — 8-phase ring schedule, FIXED stage slots (r7 race repair).
// Reader map per buffer (8 waves, 2M x 4N):
//   A half0 read in ph1 (wr=0 rows 0-63) AND ph3 (wr=0 rows 64-127)
//   A half1 read in ph1 (wr=1 rows 128-191) AND ph3 (wr=1 rows 192-255)
//   B half0 read in ph1+ph2 (wc=0,1); B half1 read in ph1+ph2 (wc=2,3)
// => free slots: B0 after ph2, B1 after ph2, A0 after ph3, A1 after ph3
// Stage slots (buf0/tile t+2): B0@ph3, {B1,A0}@ph4, A1@ph5
// Stage slots (buf1/tile t+3): B0@ph7, {B1,A0}@ph8, A1@next-ph1
// vmcnt ledger (+2 ph1, +2 ph3, +4 ph4, +2 ph5, +2 ph7, +4 ph8):
//   end-ph4: 14 outstanding, vmcnt(6) retires exactly all of tile t+1
//   end-ph8: 14 outstanding, vmcnt(6) retires exactly all of tile t+2
// Tail: vmcnt(0) when the next tile wasn't staged. All branches block-uniform.
// T2 swizzle: global source chunk j^=(row&7), linear LDS dest, read-side XOR.
// XCD swizzle: bijective chunked remap on flattened blockIdx (nwg%8==0).
//   AMODE 0: A bf16 rows contiguous (ld=K); AMODE 1: conv-gather
//   OUTMODE 0: bf16 C+bias; 1: f32 C+bias; 2: f32 split-K partial
// grid = (M/256, N/256, nz*kspl); block = 512 (8 waves, 2M x 4N); nt even
// ---------------------------------------------------------------------------
template<int AMODE, int OUTMODE>
__global__ __launch_bounds__(512, 2)
void gemm256(const void* A0p, const void* A1p, const void* A2p,
             const u16* B0p, const u16* B1p, const u16* B2p,
             const float* b0p, const float* b1p, const float* b2p,
             void* C0p, void* C1p, void* C2p,
             int M, int K, int kspl) {
  // ---- XCD-aware block remap (bijective; grids here are %8==0) ----
  int bid = blockIdx.x + gridDim.x * (blockIdx.y + gridDim.y * blockIdx.z);
  const int nwg = gridDim.x * gridDim.y * gridDim.z;
  if ((nwg & 7) == 0) bid = (bid & 7) * (nwg >> 3) + (bid >> 3);
  const int bx = bid % gridDim.x;
  const int rem = bid / gridDim.x;
  const int by = rem % gridDim.y;
  const int bz = rem / gridDim.y;

  const int zc = bz / kspl, sp = bz % kspl;
  const void* Ap = zc == 0 ? A0p : (zc == 1 ? A1p : A2p);
  const u16* Bp = zc == 0 ? B0p : (zc == 1 ? B1p : B2p);
  const float* biasp = zc == 0 ? b0p : (zc == 1 ? b1p : b2p);
  void* Cp = zc == 0 ? C0p : (zc == 1 ? C1p : C2p);

  __shared__ u16 lds[2][2][2][128 * 64];  // [buf][A=0/B=1][half][r*64+swzchunk*8]

  const int tid = threadIdx.x;
  const int w = tid >> 6, lane = tid & 63;
  const int lr = lane & 15, lg = lane >> 4;
  const int wr = w >> 2, wc = w & 3;            // 2M x 4N waves
  const int m0 = bx * 256, n0 = by * 256;
  const int kper = K / kspl, kbase = sp * kper, nt = kper >> 6;

  f32x4 acc[8][4];
#pragma unroll
  for (int mi = 0; mi < 8; ++mi)
#pragma unroll
    for (int ni = 0; ni < 4; ++ni) {
      f32x4 zv = {0.f, 0.f, 0.f, 0.f};
      acc[mi][ni] = zv;
    }

  // stage one 16KB half: op (0=A,1=B), half (0/1 = rows 0-127/128-255), tile kt
  auto stage_half = [&](int buf, int op, int half, int kt) {
    const int k0 = kbase + (kt << 6);
#pragma unroll
    for (int i = 0; i < 2; ++i) {
      int c = i * 512 + tid;               // 0..1023
      int r = c >> 3, j = c & 7, js = j ^ (r & 7);
      int row = half * 128 + r;
      u16* dst = &lds[buf][op][half][c * 8];
      if (op == 1) {
        gl_lds16(Bp + (size_t)(n0 + row) * K + k0 + js * 8, dst);
      } else if (AMODE == 0) {
        gl_lds16((const u16*)Ap + (size_t)(m0 + row) * K + k0 + js * 8, dst);
      } else {  // conv gather: m=(nn,p), k=(t,ei); k0 mult of 64, no 1024-cross
        int m = m0 + row;
        int nn = m >> 8, p = m & 255;
        int k = k0 + js * 8;
        gl_lds16((const u16*)Ap + (size_t)(p * 8 + (k >> 10)) * NE +
                 nn * EDIM + (k & 1023), dst);
      }
    }
  };

  auto LDA = [&](int buf, int row, int ks) -> bf16x8 {
    return *(const bf16x8*)&lds[buf][0][row >> 7]
        [(row & 127) * 64 + (((ks * 4 + lg) ^ (row & 7)) << 3)];
  };
  auto LDB = [&](int buf, int row, int ks) -> bf16x8 {
    return *(const bf16x8*)&lds[buf][1][row >> 7]
        [(row & 127) * 64 + (((ks * 4 + lg) ^ (row & 7)) << 3)];
  };

  // ---- prologue: T0 all 4 halves -> buf0; T1 B0,B1,A0 -> buf1 ----
  stage_half(0, 0, 0, 0); stage_half(0, 1, 0, 0);
  stage_half(0, 1, 1, 0); stage_half(0, 0, 1, 0);
  if (nt > 1) {
    stage_half(1, 1, 0, 1); stage_half(1, 1, 1, 1); stage_half(1, 0, 0, 1);
    WVM6();
  } else {
    WVM0();
  }
  BAR();

  for (int t = 0; t < nt; t += 2) {
    bf16x8 a0[4][2], a1[4][2], b0f[2][2], b1f[2][2];
    // ================= tile t (buf0) =================
    // ---- ph1: reads a0 (A rows wr*128+[0,64)), b0 (B rows wc*64+[0,32)) ----
#pragma unroll
    for (int mi = 0; mi < 4; ++mi)
#pragma unroll
      for (int ks = 0; ks < 2; ++ks)
        a0[mi][ks] = LDA(0, wr * 128 + mi * 16 + lr, ks);
#pragma unroll
    for (int ni = 0; ni < 2; ++ni)
#pragma unroll
      for (int ks = 0; ks < 2; ++ks)
        b0f[ni][ks] = LDB(0, wc * 64 + ni * 16 + lr, ks);
    stage_half(1, 0, 1, t + 1);            // (t+1).A1 (buf1.A1 free since prev ph7)
    BAR(); LGKM0();
    __builtin_amdgcn_s_setprio(1);
#pragma unroll
    for (int mi = 0; mi < 4; ++mi)
#pragma unroll
      for (int ni = 0; ni < 2; ++ni)
#pragma unroll
        for (int ks = 0; ks < 2; ++ks)
          acc[mi][ni] = mfma16(a0[mi][ks], b0f[ni][ks], acc[mi][ni]);
    __builtin_amdgcn_s_setprio(0);
    BAR();
    // ---- ph2: reads b1 (B rows wc*64+[32,64)); no stage ----
#pragma unroll
    for (int ni = 0; ni < 2; ++ni)
#pragma unroll
      for (int ks = 0; ks < 2; ++ks)
        b1f[ni][ks] = LDB(0, wc * 64 + (ni + 2) * 16 + lr, ks);
    BAR(); LGKM0();
    __builtin_amdgcn_s_setprio(1);
#pragma unroll
    for (int mi = 0; mi < 4; ++mi)
#pragma unroll
      for (int ni = 0; ni < 2; ++ni)
#pragma unroll
        for (int ks = 0; ks < 2; ++ks)
          acc[mi][ni + 2] = mfma16(a0[mi][ks], b1f[ni][ks], acc[mi][ni + 2]);
    __builtin_amdgcn_s_setprio(0);
    BAR();
    // ---- ph3: reads a1 (A rows wr*128+64+[0,64)) ----
#pragma unroll
    for (int mi = 0; mi < 4; ++mi)
#pragma unroll
      for (int ks = 0; ks < 2; ++ks)
        a1[mi][ks] = LDA(0, wr * 128 + 64 + mi * 16 + lr, ks);
    if (t + 2 < nt) stage_half(0, 1, 0, t + 2);   // (t+2).B0 (free after ph2)
    BAR(); LGKM0();
    __builtin_amdgcn_s_setprio(1);
#pragma unroll
    for (int mi = 0; mi < 4; ++mi)
#pragma unroll
      for (int ni = 0; ni < 2; ++ni)
#pragma unroll
        for (int ks = 0; ks < 2; ++ks)
          acc[mi + 4][ni + 2] = mfma16(a1[mi][ks], b1f[ni][ks], acc[mi + 4][ni + 2]);
    __builtin_amdgcn_s_setprio(0);
    BAR();
    // ---- ph4: regs only; stage B1+A0 (both free: B1 after ph2, A0 after ph3) --
    if (t + 2 < nt) { stage_half(0, 1, 1, t + 2); stage_half(0, 0, 0, t + 2); }
    BAR();
    __builtin_amdgcn_s_setprio(1);
#pragma unroll
    for (int mi = 0; mi < 4; ++mi)
#pragma unroll
      for (int ni = 0; ni < 2; ++ni)
#pragma unroll
        for (int ks = 0; ks < 2; ++ks)
          acc[mi + 4][ni] = mfma16(a1[mi][ks], b0f[ni][ks], acc[mi + 4][ni]);
    __builtin_amdgcn_s_setprio(0);
    // boundary: tile t+1 must be fully landed; keep (t+2) stages in flight
    if (t + 2 < nt) { WVM6(); } else { WVM0(); }
    BAR();
    // ================= tile t+1 (buf1) =================
    // ---- ph5 ----
#pragma unroll
    for (int mi = 0; mi < 4; ++mi)
#pragma unroll
      for (int ks = 0; ks < 2; ++ks)
        a0[mi][ks] = LDA(1, wr * 128 + mi * 16 + lr, ks);
#pragma unroll
    for (int ni = 0; ni < 2; ++ni)
#pragma unroll
      for (int ks = 0; ks < 2; ++ks)
        b0f[ni][ks] = LDB(1, wc * 64 + ni * 16 + lr, ks);
    if (t + 2 < nt) stage_half(0, 0, 1, t + 2);   // (t+2).A1 (free after ph3)
    BAR(); LGKM0();
    __builtin_amdgcn_s_setprio(1);
#pragma unroll
    for (int mi = 0; mi < 4; ++mi)
#pragma unroll
      for (int ni = 0; ni < 2; ++ni)
#pragma unroll
        for (int ks = 0; ks < 2; ++ks)
          acc[mi][ni] = mfma16(a0[mi][ks], b0f[ni][ks], acc[mi][ni]);
    __builtin_amdgcn_s_setprio(0);
    BAR();
    // ---- ph6: no stage ----
#pragma unroll
    for (int ni = 0; ni < 2; ++ni)
#pragma unroll
      for (int ks = 0; ks < 2; ++ks)
        b1f[ni][ks] = LDB(1, wc * 64 + (ni + 2) * 16 + lr, ks);
    BAR(); LGKM0();
    __builtin_amdgcn_s_setprio(1);
#pragma unroll
    for (int mi = 0; mi < 4; ++mi)
#pragma unroll
      for (int ni = 0; ni < 2; ++ni)
#pragma unroll
        for (int ks = 0; ks < 2; ++ks)
          acc[mi][ni + 2] = mfma16(a0[mi][ks], b1f[ni][ks], acc[mi][ni + 2]);
    __builtin_amdgcn_s_setprio(0);
    BAR();
    // ---- ph7 ----
#pragma unroll
    for (int mi = 0; mi < 4; ++mi)
#pragma unroll
      for (int ks = 0; ks < 2; ++ks)
        a1[mi][ks] = LDA(1, wr * 128 + 64 + mi * 16 + lr, ks);
    if (t + 3 < nt) stage_half(1, 1, 0, t + 3);   // (t+3).B0 (free after ph6)
    BAR(); LGKM0();
    __builtin_amdgcn_s_setprio(1);
#pragma unroll
    for (int mi = 0; mi < 4; ++mi)
#pragma unroll
      for (int ni = 0; ni < 2; ++ni)
#pragma unroll
        for (int ks = 0; ks < 2; ++ks)
          acc[mi + 4][ni + 2] = mfma16(a1[mi][ks], b1f[ni][ks], acc[mi + 4][ni + 2]);
    __builtin_amdgcn_s_setprio(0);
    BAR();
    // ---- ph8: regs only; stage B1'+A0' (B1 free after ph6, A0 after ph7) ----
    if (t + 3 < nt) { stage_half(1, 1, 1, t + 3); stage_half(1, 0, 0, t + 3); }
    BAR();
    __builtin_amdgcn_s_setprio(1);
#pragma unroll
    for (int mi = 0; mi < 4; ++mi)
#pragma unroll
      for (int ni = 0; ni < 2; ++ni)
#pragma unroll
        for (int ks = 0; ks < 2; ++ks)
          acc[mi + 4][ni] = mfma16(a1[mi][ks], b0f[ni][ks], acc[mi + 4][ni]);
    __builtin_amdgcn_s_setprio(0);
    // boundary: tile t+2 must be fully landed; keep (t+3) stages in flight
    if (t + 3 < nt) { WVM6(); } else { WVM0(); }
    BAR();
  }

  // ---- epilogue ----
#pragma unroll
  for (int ni = 0; ni < 4; ++ni) {
    const int col = n0 + wc * 64 + ni * 16 + lr;
    const float bv = (OUTMODE == 2) ? 0.f : biasp[col];
#pragma unroll
    for (int mi = 0; mi < 8; ++mi)
#pragma unroll
      for (int j = 0; j < 4; ++j) {
        const int row = m0 + wr * 128 + mi * 16 + lg * 4 + j;
        const float v = acc[mi][ni][j] + bv;
        if (OUTMODE == 2)
          ((float*)Cp)[(size_t)sp * M * 1024 + (size_t)row * 1024 + col] = v;
        else if (OUTMODE == 1)
          ((float*)Cp)[(size_t)row * 1024 + col] = v;
        else
          ((u16*)Cp)[(size_t)row * 1024 + col] = f2b(v);
      }
  }
}

// ---------------------------------------------------------------------------
// Legacy 128x128 GEMM — fallback paths only (small workspace)
//   OUTMODE 3: bf16+bias -> head-major (N,H,Kp,D)
//   OUTMODE 4: bf16+bias -> transposed swizzled (N,H,D,Kp)
// ---------------------------------------------------------------------------
template<int AMODE, int OUTMODE>
__global__ __launch_bounds__(256)
void gemm_bt(const void* A0p, const void* A1p, const void* A2p,
             const u16* B0p, const u16* B1p, const u16* B2p,
             const float* b0p, const float* b1p, const float* b2p,
             void* C0p, void* C1p, void* C2p,
             int M, int K, int kspl) {
  const int zc = blockIdx.z / kspl;
  const int sp = blockIdx.z % kspl;
  const void* Ap = zc == 0 ? A0p : (zc == 1 ? A1p : A2p);
  const u16* Bp = zc == 0 ? B0p : (zc == 1 ? B1p : B2p);
  const float* biasp = zc == 0 ? b0p : (zc == 1 ? b1p : b2p);
  void* Cp = zc == 0 ? C0p : (zc == 1 ? C1p : C2p);

  __shared__ u16 Alds[128 * 64];
  __shared__ u16 Blds[128 * 64];

  const int tid = threadIdx.x;
  const int w = tid >> 6, lane = tid & 63;
  const int lr = lane & 15, lg = lane >> 4;
  const int m0 = blockIdx.x * 128, n0 = blockIdx.y * 128;
  const int wr = (w >> 1) * 64, wc = (w & 1) * 64;
  const int brow = lane >> 3;
  const int bcol = (lane & 7) * 8;

  f32x4 acc[4][4];
#pragma unroll
  for (int mi = 0; mi < 4; ++mi)
#pragma unroll
    for (int ni = 0; ni < 4; ++ni) {
      f32x4 zv = {0.f, 0.f, 0.f, 0.f};
      acc[mi][ni] = zv;
    }

  const int kper = K / kspl;
  const int ktn = kper >> 6;
  const int kb = sp * kper;
  for (int kt = 0; kt < ktn; ++kt) {
    const int k0 = kb + (kt << 6);
    __syncthreads();
#pragma unroll
    for (int i = 0; i < 4; ++i) {
      const int c = w * 4 + i;
      const int row = c * 8 + brow;
      gl_lds16(Bp + (size_t)(n0 + row) * K + k0 + bcol, &Blds[c * 512]);
    }
    if (AMODE == 2) {
      const float* Af = (const float*)Ap;
#pragma unroll
      for (int i = 0; i < 4; ++i) {
        const int c = i * 256 + tid;
        const int row = c >> 3, k8 = (c & 7) * 8;
        const float* s = Af + (size_t)(m0 + row) * K + k0 + k8;
        f32x4 v0 = *(const f32x4*)s;
        f32x4 v1 = *(const f32x4*)(s + 4);
        u16x8 pk;
        pk[0] = f2b(v0[0]); pk[1] = f2b(v0[1]); pk[2] = f2b(v0[2]); pk[3] = f2b(v0[3]);
        pk[4] = f2b(v1[0]); pk[5] = f2b(v1[1]); pk[6] = f2b(v1[2]); pk[7] = f2b(v1[3]);
        *(u16x8*)&Alds[row * 64 + k8] = pk;
      }
    } else if (AMODE == 0) {
      const u16* Ab = (const u16*)Ap;
#pragma unroll
      for (int i = 0; i < 4; ++i) {
        const int c = w * 4 + i;
        const int row = c * 8 + brow;
        gl_lds16(Ab + (size_t)(m0 + row) * K + k0 + bcol, &Alds[c * 512]);
      }
    } else {
      const u16* Ab = (const u16*)Ap;
#pragma unroll
      for (int i = 0; i < 4; ++i) {
        const int c = w * 4 + i;
        const int m = m0 + c * 8 + brow;
        const int nn = m >> 8, p = m & 255;
        const int k = k0 + bcol;
        gl_lds16(Ab + (size_t)(p * 8 + (k >> 10)) * NE + nn * EDIM + (k & 1023),
                 &Alds[c * 512]);
      }
    }
    __syncthreads();
#pragma unroll
    for (int ks = 0; ks < 2; ++ks) {
      bf16x8 af[4], bf[4];
#pragma unroll
      for (int mi = 0; mi < 4; ++mi)
        af[mi] = *(const bf16x8*)&Alds[(wr + mi * 16 + lr) * 64 + ks * 32 + lg * 8];
#pragma unroll
      for (int ni = 0; ni < 4; ++ni)
        bf[ni] = *(const bf16x8*)&Blds[(wc + ni * 16 + lr) * 64 + ks * 32 + lg * 8];
#pragma unroll
      for (int mi = 0; mi < 4; ++mi)
#pragma unroll
        for (int ni = 0; ni < 4; ++ni)
          acc[mi][ni] = mfma16(af[mi], bf[ni], acc[mi][ni]);
    }
  }
#pragma unroll
  for (int ni = 0; ni < 4; ++ni) {
    const int col = n0 + wc + ni * 16 + lr;
    const float bv = (OUTMODE == 2) ? 0.f : biasp[col];
#pragma unroll
    for (int mi = 0; mi < 4; ++mi)
#pragma unroll
      for (int j = 0; j < 4; ++j) {
        const int row = m0 + wr + mi * 16 + lg * 4 + j;
        const float v = acc[mi][ni][j] + bv;
        if (OUTMODE == 4) {
          const int nn = row >> 8, pp = row & 255, h = col >> 6, d = col & 63;
          ((u16*)Cp)[(size_t)(nn * HNUM + h) * (DDIM * KPDIM) + d * 256 +
                     (((pp >> 3) ^ (d & 7)) * 8) + (pp & 7)] = f2b(v);
        } else if (OUTMODE == 3) {
          const int nn = row >> 8, pp = row & 255, h = col >> 6, d = col & 63;
          ((u16*)Cp)[((size_t)(nn * HNUM + h) * KPDIM + pp) * DDIM + d] = f2b(v);
        } else if (OUTMODE == 2)
          ((float*)Cp)[(size_t)sp * M * 1024 + (size_t)row * 1024 + col] = v;
        else if (OUTMODE == 1)
          ((float*)Cp)[(size_t)row * 1024 + col] = v;
        else
          ((u16*)Cp)[(size_t)row * 1024 + col] = f2b(v);
      }
  }
}

// ---------------------------------------------------------------------------
// Fused attention v3: block = (64 q-rows, n, head-group), hpg heads each.
// Kc (N,H,Kp,D); VcT (N,H,D,Kp) pre-transposed + chunk-swizzled in global.
// ---------------------------------------------------------------------------
__global__ __launch_bounds__(256)
void attn_fused(const u16* __restrict__ Q, const u16* __restrict__ Kc,
                const u16* __restrict__ VcT, u16* __restrict__ Aout,
                float* __restrict__ AWp, int hpg) {
  __shared__ u16 Ares[256 * 64];   // K [p][d] chunk-swizzled -> P quarters
  __shared__ u16 Bres[64 * 256];   // V^T [d][p] chunk-swizzled
  const int tid = threadIdx.x;
  const int w = tid >> 6, lane = tid & 63;
  const int lr = lane & 15, lg = lane >> 4;
  const int n = blockIdx.y;
  const int l0 = blockIdx.x * 64;
  const int lrow = l0 + w * 16 + lr;
  char* kbase = (char*)Ares;
  char* vbase = (char*)Bres;
  char* pbase = (char*)Ares + w * 8192;

  f32x4 macc[16];
#pragma unroll
  for (int ni = 0; ni < 16; ++ni) { f32x4 zv = {0.f,0.f,0.f,0.f}; macc[ni] = zv; }

  for (int hh = 0; hh < hpg; ++hh) {
    const int h = blockIdx.z * hpg + hh;
    const u16* kh = Kc + (size_t)(n * HNUM + h) * (KPDIM * DDIM);
    const u16* vh = VcT + (size_t)(n * HNUM + h) * (DDIM * KPDIM);
    __syncthreads();
#pragma unroll
    for (int it = 0; it < 8; ++it) {
      int c = it * 256 + tid;
      int p = c >> 3, j = c & 7;
      gl_lds16(kh + p * 64 + ((j ^ (p & 7)) << 3), kbase + c * 16);
    }
#pragma unroll
    for (int it = 0; it < 8; ++it) {
      int c = it * 256 + tid;
      gl_lds16(vh + c * 8, vbase + c * 16);
    }
    const u16* qp = Q + (size_t)lrow * NE + n * EDIM + h * DDIM + lg * 8;
    bf16x8 aq0 = *(const bf16x8*)qp;
    bf16x8 aq1 = *(const bf16x8*)(qp + 32);
    __syncthreads();
    f32x4 s[16];
#pragma unroll
    for (int ni = 0; ni < 16; ++ni) { f32x4 zv = {0.f,0.f,0.f,0.f}; s[ni] = zv; }
#pragma unroll
    for (int ni = 0; ni < 16; ++ni) {
      int row = ni * 16 + lr;
      const char* kr = kbase + row * 128;
      bf16x8 b0 = *(const bf16x8*)(kr + ((lg ^ (row & 7)) << 4));
      bf16x8 b1 = *(const bf16x8*)(kr + (((4 + lg) ^ (row & 7)) << 4));
      s[ni] = mfma16(aq0, b0, s[ni]);
      s[ni] = mfma16(aq1, b1, s[ni]);
    }
    float mx[4], sm[4], inv[4];
#pragma unroll
    for (int j = 0; j < 4; ++j) mx[j] = -1e30f;
#pragma unroll
    for (int ni = 0; ni < 16; ++ni)
#pragma unroll
      for (int j = 0; j < 4; ++j) mx[j] = fmaxf(mx[j], s[ni][j]);
#pragma unroll
    for (int msk = 1; msk <= 8; msk <<= 1)
#pragma unroll
      for (int j = 0; j < 4; ++j) mx[j] = fmaxf(mx[j], __shfl_xor(mx[j], msk, 64));
#pragma unroll
    for (int j = 0; j < 4; ++j) sm[j] = 0.f;
#pragma unroll
    for (int ni = 0; ni < 16; ++ni)
#pragma unroll
      for (int j = 0; j < 4; ++j) {
        float e = __expf(s[ni][j] - mx[j]);
        s[ni][j] = e; sm[j] += e;
      }
#pragma unroll
    for (int msk = 1; msk <= 8; msk <<= 1)
#pragma unroll
      for (int j = 0; j < 4; ++j) sm[j] += __shfl_xor(sm[j], msk, 64);
#pragma unroll
    for (int j = 0; j < 4; ++j) inv[j] = 1.0f / sm[j];
    __syncthreads();
#pragma unroll
    for (int ni = 0; ni < 16; ++ni)
#pragma unroll
      for (int j = 0; j < 4; ++j) {
        float pv = s[ni][j] * inv[j];
        macc[ni][j] += pv * 0.0625f;
        int r = lg * 4 + j;
        *(u16*)(pbase + r * 512 + ((ni * 32 + lr * 2) ^ ((r & 7) << 4))) = f2b(pv);
      }
    f32x4 o[4];
#pragma unroll
    for (int ni2 = 0; ni2 < 4; ++ni2) { f32x4 zv = {0.f,0.f,0.f,0.f}; o[ni2] = zv; }
#pragma unroll
    for (int ks = 0; ks < 8; ++ks) {
      bf16x8 a = *(const bf16x8*)(pbase + lr * 512 + ((ks * 64 + 16 * lg) ^ ((lr & 7) << 4)));
#pragma unroll
      for (int ni2 = 0; ni2 < 4; ++ni2) {
        int d = ni2 * 16 + lr;
        bf16x8 b = *(const bf16x8*)(vbase + d * 512 + (((ks * 4 + lg) ^ (d & 7)) << 4));
        o[ni2] = mfma16(a, b, o[ni2]);
      }
    }
#pragma unroll
    for (int ni2 = 0; ni2 < 4; ++ni2)
#pragma unroll
      for (int j = 0; j < 4; ++j) {
        int gl = l0 + w * 16 + lg * 4 + j;
        Aout[(size_t)gl * NE + n * EDIM + h * DDIM + ni2 * 16 + lr] = f2b(o[ni2][j]);
      }
  }
  float* awo = AWp + (size_t)blockIdx.z * AWSZ + (size_t)n * (LSEQ * KPDIM);
#pragma unroll
  for (int ni = 0; ni < 16; ++ni)
#pragma unroll
    for (int j = 0; j < 4; ++j) {
      int r = lg * 4 + j;
      awo[(size_t)(l0 + w * 16 + r) * KPDIM + ni * 16 + lr] = macc[ni][j];
    }
}

// ---------------------------------------------------------------------------
extern "C" void kernel_launch(void* const* d_in, const int* in_sizes, int n_in,
                              void* d_out, int out_size, void* d_ws, size_t ws_size,
                              hipStream_t stream) {
  const float* query = (const float*)d_in[0];
  const float* key   = (const float*)d_in[1];
  const float* value = (const float*)d_in[2];
  const float* ipw   = (const float*)d_in[3];
  const float* ipb   = (const float*)d_in[4];
  const float* ew    = (const float*)d_in[5];
  const float* eb    = (const float*)d_in[6];
  const float* fw    = (const float*)d_in[7];
  const float* fb    = (const float*)d_in[8];
  const float* ow    = (const float*)d_in[9];
  const float* ob    = (const float*)d_in[10];

  char* ws = (char*)d_ws;
  size_t off = 0;
  auto alloc = [&](size_t bytes) {
    void* p = ws + off;
    off += (bytes + 255) & ~(size_t)255;
    return p;
  };
  u16* qp    = (u16*)alloc((size_t)MROWS * EDIM * 2);
  u16* kp    = (u16*)alloc((size_t)MROWS * EDIM * 2);
  u16* vp    = (u16*)alloc((size_t)MROWS * EDIM * 2);
  u16* ao    = (u16*)alloc((size_t)MROWS * EDIM * 2);
  u16* kc    = (u16*)alloc((size_t)NB * KPDIM * EDIM * 2);   // (N,H,Kp,D)
  u16* vcT   = (u16*)alloc((size_t)NB * KPDIM * EDIM * 2);   // (N,H,D,Kp) swz
  u16* w_in  = (u16*)alloc((size_t)3 * EDIM * EDIM * 2);
  u16* w_eT  = (u16*)alloc((size_t)EDIM * 8 * EDIM * 2);
  u16* w_fT  = (u16*)alloc((size_t)EDIM * 8 * EDIM * 2);
  u16* w_out = (u16*)alloc((size_t)EDIM * EDIM * 2);
  float* bq  = (float*)alloc(EDIM * 4);
  size_t base_needed = off;

  size_t qkv16_b = (size_t)3 * MROWS * EDIM * 2;
  size_t part_b  = (size_t)2 * 4 * 2048 * 1024 * 4;
  bool bigX  = ws_size >= base_needed + qkv16_b;
  bool midX  = ws_size >= base_needed + part_b;
  char* X = (char*)alloc(bigX ? qkv16_b : (midX ? part_b : 0));
  u16* qkv16 = (u16*)X;
  float* part = (float*)X;
  float* awp  = (float*)X;

  float* out_f = (float*)d_out;                        // (L, N, E)
  float* aw_f  = (float*)d_out + (size_t)MROWS * EDIM; // (N, L, Kp)

  // weight prep
  wconv<<<dim3(3072), 256, 0, stream>>>(ipw, w_in, 786432, 262144, 0.125f);
  wconv<<<dim3(1024), 256, 0, stream>>>(ow, w_out, 262144, 0, 1.0f);
  wtrans<<<dim3(16384, 2), 64, 0, stream>>>(ew, fw, w_eT, w_fT);
  bscale<<<dim3(4), 256, 0, stream>>>(ipb, bq);

  // q/k/v projections
  if (bigX) {
    castqkv<<<dim3(8192, 3), 256, 0, stream>>>(query, key, value, qkv16);
    gemm256<0, 0><<<dim3(64, 4, 3), 512, 0, stream>>>(
        qkv16, qkv16 + (size_t)MROWS * EDIM, qkv16 + (size_t)2 * MROWS * EDIM,
        w_in, w_in + 1048576, w_in + 2097152,
        bq, ipb + 1024, ipb + 2048,
        qp, kp, vp, MROWS, 1024, 1);
  } else {
    gemm_bt<2, 0><<<dim3(128, 8, 3), 256, 0, stream>>>(
        query, key, value,
        w_in, w_in + 1048576, w_in + 2097152,
        bq, ipb + 1024, ipb + 2048,
        qp, kp, vp, MROWS, 1024, 1);
  }

  // conv compression of k and v -> kc (head-major) / vcT (transposed swz)
  if (bigX || midX) {
    gemm256<1, 2><<<dim3(8, 4, 8), 512, 0, stream>>>(
        kp, vp, vp,
        w_eT, w_fT, w_fT,
        eb, fb, fb,
        part, part + (size_t)4 * 2048 * 1024, part,
        NB * KPDIM, 8192, 4);
    redc<<<dim3(2048, 2), 256, 0, stream>>>(part, eb, fb, kc, vcT);
  } else {
    gemm_bt<1, 3><<<dim3(16, 8, 1), 256, 0, stream>>>(
        kp, kp, kp, w_eT, w_eT, w_eT, eb, eb, eb,
        kc, kc, kc, NB * KPDIM, 8192, 1);
    gemm_bt<1, 4><<<dim3(16, 8, 1), 256, 0, stream>>>(
        vp, vp, vp, w_fT, w_fT, w_fT, fb, fb, fb,
        vcT, vcT, vcT, NB * KPDIM, 8192, 1);
  }

  // fused attention + head-mean weights
  if (bigX) {
    attn_fused<<<dim3(32, 8, 4), 256, 0, stream>>>(qp, kc, vcT, ao, awp, 4);
    awred<<<dim3(4096), 256, 0, stream>>>(awp, aw_f);
  } else {
    attn_fused<<<dim3(32, 8, 1), 256, 0, stream>>>(qp, kc, vcT, ao, aw_f, 16);
  }

  // output projection -> f32 d_out
  gemm256<0, 1><<<dim3(64, 4, 1), 512, 0, stream>>>(
      ao, ao, ao,
      w_out, w_out, w_out,
      ob, ob, ob,
      out_f, out_f, out_f, MROWS, 1024, 1);
}

// Round 9
// 437.897 us; speedup vs baseline: 1.5554x; 1.0317x over previous
//
#include <hip/hip_runtime.h>

typedef unsigned short u16;
typedef u16  u16x4 __attribute__((ext_vector_type(4)));
typedef u16  u16x8 __attribute__((ext_vector_type(8)));
typedef float f32x4 __attribute__((ext_vector_type(4)));
typedef int   i32x4 __attribute__((ext_vector_type(4)));
typedef __bf16 bf16x8 __attribute__((ext_vector_type(8)));

#define LSEQ 2048
#define NB 8
#define EDIM 1024
#define HNUM 16
#define DDIM 64
#define KPDIM 256
#define NE (NB*EDIM)       /* 8192 */
#define MROWS (LSEQ*NB)    /* 16384 */
#define AWSZ ((size_t)NB*LSEQ*KPDIM)  /* 4194304 */

__device__ __forceinline__ u16 f2b(float f) {
  unsigned u = __builtin_bit_cast(unsigned, f);
  u += 0x7fffu + ((u >> 16) & 1u);
  return (u16)(u >> 16);
}

__device__ __forceinline__ void gl_lds16(const void* g, void* l) {
  __builtin_amdgcn_global_load_lds(
      (const __attribute__((address_space(1))) void*)g,
      (__attribute__((address_space(3))) void*)l, 16, 0, 0);
}

__device__ __forceinline__ f32x4 mfma16(bf16x8 a, bf16x8 b, f32x4 c) {
  return __builtin_amdgcn_mfma_f32_16x16x32_bf16(a, b, c, 0, 0, 0);
}

#define BAR()   __builtin_amdgcn_s_barrier()
#define LGKM0() asm volatile("s_waitcnt lgkmcnt(0)" ::: "memory")
#define WVM6()  asm volatile("s_waitcnt vmcnt(6)" ::: "memory")
#define WVM0()  asm volatile("s_waitcnt vmcnt(0)" ::: "memory")

// ---------------------------------------------------------------------------
// Weight prep kernels
// ---------------------------------------------------------------------------
__global__ void wconv(const float* __restrict__ src, u16* __restrict__ dst,
                      int n4, int scale_n4, float sc) {
  int i = blockIdx.x * blockDim.x + threadIdx.x;
  if (i >= n4) return;
  f32x4 v = ((const f32x4*)src)[i];
  float s = (i < scale_n4) ? sc : 1.0f;
  u16x4 o;
  o[0] = f2b(v[0] * s); o[1] = f2b(v[1] * s);
  o[2] = f2b(v[2] * s); o[3] = f2b(v[3] * s);
  ((u16x4*)dst)[i] = o;
}

// (O, I, 8) f32  ->  (O, t*E + i) bf16   (per-wave LDS transpose)
__global__ void wtrans(const float* __restrict__ ew, const float* __restrict__ fw,
                       u16* __restrict__ eT, u16* __restrict__ fT) {
  const float* src = blockIdx.y ? fw : ew;
  u16* dst = blockIdx.y ? fT : eT;
  int eo = blockIdx.x >> 4;
  int ei0 = (blockIdx.x & 15) * 64;
  int l = threadIdx.x;
  __shared__ u16 lds[8][64];
  const float* s = src + (size_t)eo * 8192 + (size_t)ei0 * 8 + l * 8;
  f32x4 a = *(const f32x4*)s;
  f32x4 b = *(const f32x4*)(s + 4);
  float v[8] = {a[0], a[1], a[2], a[3], b[0], b[1], b[2], b[3]};
#pragma unroll
  for (int t = 0; t < 8; ++t) lds[t][l] = f2b(v[t]);
  __syncthreads();
  int t = l >> 3, c = l & 7;
  i32x4 out = *(const i32x4*)&lds[t][c * 8];
  *(i32x4*)(dst + (size_t)eo * 8192 + t * 1024 + ei0 + c * 8) = out;
}

__global__ void bscale(const float* __restrict__ b, float* __restrict__ out) {
  int i = blockIdx.x * blockDim.x + threadIdx.x;
  if (i < EDIM) out[i] = b[i] * 0.125f;
}

// q/k/v f32 -> bf16, contiguous [3][MROWS][E]
__global__ void castqkv(const float* __restrict__ q, const float* __restrict__ k,
                        const float* __restrict__ v, u16* __restrict__ out) {
  const float* src = blockIdx.y == 0 ? q : (blockIdx.y == 1 ? k : v);
  size_t base = (size_t)blockIdx.y * ((size_t)MROWS * EDIM);
  size_t i = ((size_t)blockIdx.x * 256 + threadIdx.x) * 8;
  f32x4 v0 = *(const f32x4*)(src + i);
  f32x4 v1 = *(const f32x4*)(src + i + 4);
  u16x8 o;
  o[0] = f2b(v0[0]); o[1] = f2b(v0[1]); o[2] = f2b(v0[2]); o[3] = f2b(v0[3]);
  o[4] = f2b(v1[0]); o[5] = f2b(v1[1]); o[6] = f2b(v1[2]); o[7] = f2b(v1[3]);
  *(u16x8*)(out + base + i) = o;
}

// sum 4 split-K partials + bias -> bf16.
// K -> head-major (N,H,Kp,D). V -> transposed (N,H,D,Kp) chunk-swizzled.
__global__ void redc(const float* __restrict__ part, const float* __restrict__ eb,
                     const float* __restrict__ fb, u16* __restrict__ kc,
                     u16* __restrict__ vcT) {
  int zc = blockIdx.y;
  const float* p = part + (size_t)zc * 4 * 2048 * 1024;
  const float* bias = zc ? fb : eb;
  size_t i = ((size_t)blockIdx.x * 256 + threadIdx.x) * 4;
  f32x4 s = *(const f32x4*)(p + i);
  s += *(const f32x4*)(p + 2097152 + i);
  s += *(const f32x4*)(p + 2 * 2097152 + i);
  s += *(const f32x4*)(p + 3 * 2097152 + i);
  int e = (int)(i & 1023);
  int row = (int)(i >> 10);           // n*256 + p
  int n = row >> 8, pp = row & 255;
  int h = e >> 6, d = e & 63;
  f32x4 b = *(const f32x4*)(bias + e);
  if (zc == 0) {
    u16x4 o;
    o[0] = f2b(s[0] + b[0]); o[1] = f2b(s[1] + b[1]);
    o[2] = f2b(s[2] + b[2]); o[3] = f2b(s[3] + b[3]);
    *(u16x4*)(kc + (((size_t)(n * HNUM + h) * KPDIM + pp) * DDIM + d)) = o;
  } else {
    size_t base = (size_t)(n * HNUM + h) * (DDIM * KPDIM);
#pragma unroll
    for (int q = 0; q < 4; ++q) {
      int dq = d + q;
      vcT[base + dq * 256 + (((pp >> 3) ^ (dq & 7)) * 8) + (pp & 7)] =
          f2b(s[q] + b[q]);
    }
  }
}

// sum the 4 head-group AW partials
__global__ void awred(const float* __restrict__ awp, float* __restrict__ aw) {
  size_t i = ((size_t)blockIdx.x * 256 + threadIdx.x) * 4;
  f32x4 s = *(const f32x4*)(awp + i);
  s += *(const f32x4*)(awp + AWSZ + i);
  s += *(const f32x4*)(awp + 2 * AWSZ + i);
  s += *(const f32x4*)(awp + 3 * AWSZ + i);
  *(f32x4*)(aw + i) = s;
}

// ---------------------------------------------------------------------------
// 256x256 GEMM — 8-phase ring schedule (r8, verified) + coalesced bf16
// epilogue (r9). NO XCD swizzle (r9: all inputs L3-resident; swizzle cost
// 202 vs 74 MB FETCH — m160's L3-fit case).
// Reader/stage ring and vmcnt ledger identical to r8 (see comments there).
//   AMODE 0: A bf16 rows contiguous (ld=K); AMODE 1: conv-gather
//   OUTMODE 0: bf16 C+bias (LDS-bounced coalesced write);
//           1: f32 C+bias; 2: f32 split-K partial
// grid = (M/256, N/256, nz*kspl); block = 512 (8 waves, 2M x 4N); nt even
// ---------------------------------------------------------------------------
template<int AMODE, int OUTMODE>
__global__ __launch_bounds__(512, 2)
void gemm256(const void* A0p, const void* A1p, const void* A2p,
             const u16* B0p, const u16* B1p, const u16* B2p,
             const float* b0p, const float* b1p, const float* b2p,
             void* C0p, void* C1p, void* C2p,
             int M, int K, int kspl) {
  const int zc = blockIdx.z / kspl, sp = blockIdx.z % kspl;
  const void* Ap = zc == 0 ? A0p : (zc == 1 ? A1p : A2p);
  const u16* Bp = zc == 0 ? B0p : (zc == 1 ? B1p : B2p);
  const float* biasp = zc == 0 ? b0p : (zc == 1 ? b1p : b2p);
  void* Cp = zc == 0 ? C0p : (zc == 1 ? C1p : C2p);

  __shared__ u16 lds[2][2][2][128 * 64];  // [buf][A=0/B=1][half][r*64+swzchunk*8]

  const int tid = threadIdx.x;
  const int w = tid >> 6, lane = tid & 63;
  const int lr = lane & 15, lg = lane >> 4;
  const int wr = w >> 2, wc = w & 3;            // 2M x 4N waves
  const int m0 = blockIdx.x * 256, n0 = blockIdx.y * 256;
  const int kper = K / kspl, kbase = sp * kper, nt = kper >> 6;

  f32x4 acc[8][4];
#pragma unroll
  for (int mi = 0; mi < 8; ++mi)
#pragma unroll
    for (int ni = 0; ni < 4; ++ni) {
      f32x4 zv = {0.f, 0.f, 0.f, 0.f};
      acc[mi][ni] = zv;
    }

  // stage one 16KB half: op (0=A,1=B), half (0/1 = rows 0-127/128-255), tile kt
  auto stage_half = [&](int buf, int op, int half, int kt) {
    const int k0 = kbase + (kt << 6);
#pragma unroll
    for (int i = 0; i < 2; ++i) {
      int c = i * 512 + tid;               // 0..1023
      int r = c >> 3, j = c & 7, js = j ^ (r & 7);
      int row = half * 128 + r;
      u16* dst = &lds[buf][op][half][c * 8];
      if (op == 1) {
        gl_lds16(Bp + (size_t)(n0 + row) * K + k0 + js * 8, dst);
      } else if (AMODE == 0) {
        gl_lds16((const u16*)Ap + (size_t)(m0 + row) * K + k0 + js * 8, dst);
      } else {  // conv gather: m=(nn,p), k=(t,ei); k0 mult of 64, no 1024-cross
        int m = m0 + row;
        int nn = m >> 8, p = m & 255;
        int k = k0 + js * 8;
        gl_lds16((const u16*)Ap + (size_t)(p * 8 + (k >> 10)) * NE +
                 nn * EDIM + (k & 1023), dst);
      }
    }
  };

  auto LDA = [&](int buf, int row, int ks) -> bf16x8 {
    return *(const bf16x8*)&lds[buf][0][row >> 7]
        [(row & 127) * 64 + (((ks * 4 + lg) ^ (row & 7)) << 3)];
  };
  auto LDB = [&](int buf, int row, int ks) -> bf16x8 {
    return *(const bf16x8*)&lds[buf][1][row >> 7]
        [(row & 127) * 64 + (((ks * 4 + lg) ^ (row & 7)) << 3)];
  };

  // ---- prologue: T0 all 4 halves -> buf0; T1 B0,B1,A0 -> buf1 ----
  stage_half(0, 0, 0, 0); stage_half(0, 1, 0, 0);
  stage_half(0, 1, 1, 0); stage_half(0, 0, 1, 0);
  if (nt > 1) {
    stage_half(1, 1, 0, 1); stage_half(1, 1, 1, 1); stage_half(1, 0, 0, 1);
    WVM6();
  } else {
    WVM0();
  }
  BAR();

  for (int t = 0; t < nt; t += 2) {
    bf16x8 a0[4][2], a1[4][2], b0f[2][2], b1f[2][2];
    // ================= tile t (buf0) =================
    // ---- ph1: reads a0 (A rows wr*128+[0,64)), b0 (B rows wc*64+[0,32)) ----
#pragma unroll
    for (int mi = 0; mi < 4; ++mi)
#pragma unroll
      for (int ks = 0; ks < 2; ++ks)
        a0[mi][ks] = LDA(0, wr * 128 + mi * 16 + lr, ks);
#pragma unroll
    for (int ni = 0; ni < 2; ++ni)
#pragma unroll
      for (int ks = 0; ks < 2; ++ks)
        b0f[ni][ks] = LDB(0, wc * 64 + ni * 16 + lr, ks);
    stage_half(1, 0, 1, t + 1);            // (t+1).A1 (buf1.A1 free since prev ph7)
    BAR(); LGKM0();
    __builtin_amdgcn_s_setprio(1);
#pragma unroll
    for (int mi = 0; mi < 4; ++mi)
#pragma unroll
      for (int ni = 0; ni < 2; ++ni)
#pragma unroll
        for (int ks = 0; ks < 2; ++ks)
          acc[mi][ni] = mfma16(a0[mi][ks], b0f[ni][ks], acc[mi][ni]);
    __builtin_amdgcn_s_setprio(0);
    BAR();
    // ---- ph2: reads b1 (B rows wc*64+[32,64)); no stage ----
#pragma unroll
    for (int ni = 0; ni < 2; ++ni)
#pragma unroll
      for (int ks = 0; ks < 2; ++ks)
        b1f[ni][ks] = LDB(0, wc * 64 + (ni + 2) * 16 + lr, ks);
    BAR(); LGKM0();
    __builtin_amdgcn_s_setprio(1);
#pragma unroll
    for (int mi = 0; mi < 4; ++mi)
#pragma unroll
      for (int ni = 0; ni < 2; ++ni)
#pragma unroll
        for (int ks = 0; ks < 2; ++ks)
          acc[mi][ni + 2] = mfma16(a0[mi][ks], b1f[ni][ks], acc[mi][ni + 2]);
    __builtin_amdgcn_s_setprio(0);
    BAR();
    // ---- ph3: reads a1 (A rows wr*128+64+[0,64)) ----
#pragma unroll
    for (int mi = 0; mi < 4; ++mi)
#pragma unroll
      for (int ks = 0; ks < 2; ++ks)
        a1[mi][ks] = LDA(0, wr * 128 + 64 + mi * 16 + lr, ks);
    if (t + 2 < nt) stage_half(0, 1, 0, t + 2);   // (t+2).B0 (free after ph2)
    BAR(); LGKM0();
    __builtin_amdgcn_s_setprio(1);
#pragma unroll
    for (int mi = 0; mi < 4; ++mi)
#pragma unroll
      for (int ni = 0; ni < 2; ++ni)
#pragma unroll
        for (int ks = 0; ks < 2; ++ks)
          acc[mi + 4][ni + 2] = mfma16(a1[mi][ks], b1f[ni][ks], acc[mi + 4][ni + 2]);
    __builtin_amdgcn_s_setprio(0);
    BAR();
    // ---- ph4: regs only; stage B1+A0 (both free: B1 after ph2, A0 after ph3) --
    if (t + 2 < nt) { stage_half(0, 1, 1, t + 2); stage_half(0, 0, 0, t + 2); }
    BAR();
    __builtin_amdgcn_s_setprio(1);
#pragma unroll
    for (int mi = 0; mi < 4; ++mi)
#pragma unroll
      for (int ni = 0; ni < 2; ++ni)
#pragma unroll
        for (int ks = 0; ks < 2; ++ks)
          acc[mi + 4][ni] = mfma16(a1[mi][ks], b0f[ni][ks], acc[mi + 4][ni]);
    __builtin_amdgcn_s_setprio(0);
    // boundary: tile t+1 must be fully landed; keep (t+2) stages in flight
    if (t + 2 < nt) { WVM6(); } else { WVM0(); }
    BAR();
    // ================= tile t+1 (buf1) =================
    // ---- ph5 ----
#pragma unroll
    for (int mi = 0; mi < 4; ++mi)
#pragma unroll
      for (int ks = 0; ks < 2; ++ks)
        a0[mi][ks] = LDA(1, wr * 128 + mi * 16 + lr, ks);
#pragma unroll
    for (int ni = 0; ni < 2; ++ni)
#pragma unroll
      for (int ks = 0; ks < 2; ++ks)
        b0f[ni][ks] = LDB(1, wc * 64 + ni * 16 + lr, ks);
    if (t + 2 < nt) stage_half(0, 0, 1, t + 2);   // (t+2).A1 (free after ph3)
    BAR(); LGKM0();
    __builtin_amdgcn_s_setprio(1);
#pragma unroll
    for (int mi = 0; mi < 4; ++mi)
#pragma unroll
      for (int ni = 0; ni < 2; ++ni)
#pragma unroll
        for (int ks = 0; ks < 2; ++ks)
          acc[mi][ni] = mfma16(a0[mi][ks], b0f[ni][ks], acc[mi][ni]);
    __builtin_amdgcn_s_setprio(0);
    BAR();
    // ---- ph6: no stage ----
#pragma unroll
    for (int ni = 0; ni < 2; ++ni)
#pragma unroll
      for (int ks = 0; ks < 2; ++ks)
        b1f[ni][ks] = LDB(1, wc * 64 + (ni + 2) * 16 + lr, ks);
    BAR(); LGKM0();
    __builtin_amdgcn_s_setprio(1);
#pragma unroll
    for (int mi = 0; mi < 4; ++mi)
#pragma unroll
      for (int ni = 0; ni < 2; ++ni)
#pragma unroll
        for (int ks = 0; ks < 2; ++ks)
          acc[mi][ni + 2] = mfma16(a0[mi][ks], b1f[ni][ks], acc[mi][ni + 2]);
    __builtin_amdgcn_s_setprio(0);
    BAR();
    // ---- ph7 ----
#pragma unroll
    for (int mi = 0; mi < 4; ++mi)
#pragma unroll
      for (int ks = 0; ks < 2; ++ks)
        a1[mi][ks] = LDA(1, wr * 128 + 64 + mi * 16 + lr, ks);
    if (t + 3 < nt) stage_half(1, 1, 0, t + 3);   // (t+3).B0 (free after ph6)
    BAR(); LGKM0();
    __builtin_amdgcn_s_setprio(1);
#pragma unroll
    for (int mi = 0; mi < 4; ++mi)
#pragma unroll
      for (int ni = 0; ni < 2; ++ni)
#pragma unroll
        for (int ks = 0; ks < 2; ++ks)
          acc[mi + 4][ni + 2] = mfma16(a1[mi][ks], b1f[ni][ks], acc[mi + 4][ni + 2]);
    __builtin_amdgcn_s_setprio(0);
    BAR();
    // ---- ph8: regs only; stage B1'+A0' (B1 free after ph6, A0 after ph7) ----
    if (t + 3 < nt) { stage_half(1, 1, 1, t + 3); stage_half(1, 0, 0, t + 3); }
    BAR();
    __builtin_amdgcn_s_setprio(1);
#pragma unroll
    for (int mi = 0; mi < 4; ++mi)
#pragma unroll
      for (int ni = 0; ni < 2; ++ni)
#pragma unroll
        for (int ks = 0; ks < 2; ++ks)
          acc[mi + 4][ni] = mfma16(a1[mi][ks], b0f[ni][ks], acc[mi + 4][ni]);
    __builtin_amdgcn_s_setprio(0);
    // boundary: tile t+2 must be fully landed; keep (t+3) stages in flight
    if (t + 3 < nt) { WVM6(); } else { WVM0(); }
    BAR();
  }

  // ---- epilogue ----
  if (OUTMODE == 0) {
    // LDS-bounce: tile -> LDS (bf16, 128 KB exactly), then fully-coalesced
    // 16B/lane global stores (fixes the 2x write amplification of 32B
    // segment stores). __syncthreads = full fence: loop LDS is dead, and
    // compiler cannot reorder the cw stores above it.
    __syncthreads();
    u16* cw = (u16*)&lds[0][0][0][0];       // [256][256] u16
#pragma unroll
    for (int ni = 0; ni < 4; ++ni) {
      const int col = wc * 64 + ni * 16 + lr;
      const float bv = biasp[n0 + col];
#pragma unroll
      for (int mi = 0; mi < 8; ++mi)
#pragma unroll
        for (int j = 0; j < 4; ++j) {
          const int row = wr * 128 + mi * 16 + lg * 4 + j;
          cw[row * 256 + col] = f2b(acc[mi][ni][j] + bv);
        }
    }
    __syncthreads();
#pragma unroll
    for (int it = 0; it < 16; ++it) {
      int c = it * 512 + tid;
      int row = c >> 5, ch = c & 31;
      i32x4 v = *(const i32x4*)&cw[row * 256 + ch * 8];
      *(i32x4*)((u16*)Cp + (size_t)(m0 + row) * 1024 + n0 + ch * 8) = v;
    }
  } else {
#pragma unroll
    for (int ni = 0; ni < 4; ++ni) {
      const int col = n0 + wc * 64 + ni * 16 + lr;
      const float bv = (OUTMODE == 2) ? 0.f : biasp[col];
#pragma unroll
      for (int mi = 0; mi < 8; ++mi)
#pragma unroll
        for (int j = 0; j < 4; ++j) {
          const int row = m0 + wr * 128 + mi * 16 + lg * 4 + j;
          const float v = acc[mi][ni][j] + bv;
          if (OUTMODE == 2)
            ((float*)Cp)[(size_t)sp * M * 1024 + (size_t)row * 1024 + col] = v;
          else
            ((float*)Cp)[(size_t)row * 1024 + col] = v;
        }
    }
  }
}

// ---------------------------------------------------------------------------
// Legacy 128x128 GEMM — fallback paths only (small workspace)
//   OUTMODE 3: bf16+bias -> head-major (N,H,Kp,D)
//   OUTMODE 4: bf16+bias -> transposed swizzled (N,H,D,Kp)
// ---------------------------------------------------------------------------
template<int AMODE, int OUTMODE>
__global__ __launch_bounds__(256)
void gemm_bt(const void* A0p, const void* A1p, const void* A2p,
             const u16* B0p, const u16* B1p, const u16* B2p,
             const float* b0p, const float* b1p, const float* b2p,
             void* C0p, void* C1p, void* C2p,
             int M, int K, int kspl) {
  const int zc = blockIdx.z / kspl;
  const int sp = blockIdx.z % kspl;
  const void* Ap = zc == 0 ? A0p : (zc == 1 ? A1p : A2p);
  const u16* Bp = zc == 0 ? B0p : (zc == 1 ? B1p : B2p);
  const float* biasp = zc == 0 ? b0p : (zc == 1 ? b1p : b2p);
  void* Cp = zc == 0 ? C0p : (zc == 1 ? C1p : C2p);

  __shared__ u16 Alds[128 * 64];
  __shared__ u16 Blds[128 * 64];

  const int tid = threadIdx.x;
  const int w = tid >> 6, lane = tid & 63;
  const int lr = lane & 15, lg = lane >> 4;
  const int m0 = blockIdx.x * 128, n0 = blockIdx.y * 128;
  const int wr = (w >> 1) * 64, wc = (w & 1) * 64;
  const int brow = lane >> 3;
  const int bcol = (lane & 7) * 8;

  f32x4 acc[4][4];
#pragma unroll
  for (int mi = 0; mi < 4; ++mi)
#pragma unroll
    for (int ni = 0; ni < 4; ++ni) {
      f32x4 zv = {0.f, 0.f, 0.f, 0.f};
      acc[mi][ni] = zv;
    }

  const int kper = K / kspl;
  const int ktn = kper >> 6;
  const int kb = sp * kper;
  for (int kt = 0; kt < ktn; ++kt) {
    const int k0 = kb + (kt << 6);
    __syncthreads();
#pragma unroll
    for (int i = 0; i < 4; ++i) {
      const int c = w * 4 + i;
      const int row = c * 8 + brow;
      gl_lds16(Bp + (size_t)(n0 + row) * K + k0 + bcol, &Blds[c * 512]);
    }
    if (AMODE == 2) {
      const float* Af = (const float*)Ap;
#pragma unroll
      for (int i = 0; i < 4; ++i) {
        const int c = i * 256 + tid;
        const int row = c >> 3, k8 = (c & 7) * 8;
        const float* s = Af + (size_t)(m0 + row) * K + k0 + k8;
        f32x4 v0 = *(const f32x4*)s;
        f32x4 v1 = *(const f32x4*)(s + 4);
        u16x8 pk;
        pk[0] = f2b(v0[0]); pk[1] = f2b(v0[1]); pk[2] = f2b(v0[2]); pk[3] = f2b(v0[3]);
        pk[4] = f2b(v1[0]); pk[5] = f2b(v1[1]); pk[6] = f2b(v1[2]); pk[7] = f2b(v1[3]);
        *(u16x8*)&Alds[row * 64 + k8] = pk;
      }
    } else if (AMODE == 0) {
      const u16* Ab = (const u16*)Ap;
#pragma unroll
      for (int i = 0; i < 4; ++i) {
        const int c = w * 4 + i;
        const int row = c * 8 + brow;
        gl_lds16(Ab + (size_t)(m0 + row) * K + k0 + bcol, &Alds[c * 512]);
      }
    } else {
      const u16* Ab = (const u16*)Ap;
#pragma unroll
      for (int i = 0; i < 4; ++i) {
        const int c = w * 4 + i;
        const int m = m0 + c * 8 + brow;
        const int nn = m >> 8, p = m & 255;
        const int k = k0 + bcol;
        gl_lds16(Ab + (size_t)(p * 8 + (k >> 10)) * NE + nn * EDIM + (k & 1023),
                 &Alds[c * 512]);
      }
    }
    __syncthreads();
#pragma unroll
    for (int ks = 0; ks < 2; ++ks) {
      bf16x8 af[4], bf[4];
#pragma unroll
      for (int mi = 0; mi < 4; ++mi)
        af[mi] = *(const bf16x8*)&Alds[(wr + mi * 16 + lr) * 64 + ks * 32 + lg * 8];
#pragma unroll
      for (int ni = 0; ni < 4; ++ni)
        bf[ni] = *(const bf16x8*)&Blds[(wc + ni * 16 + lr) * 64 + ks * 32 + lg * 8];
#pragma unroll
      for (int mi = 0; mi < 4; ++mi)
#pragma unroll
        for (int ni = 0; ni < 4; ++ni)
          acc[mi][ni] = mfma16(af[mi], bf[ni], acc[mi][ni]);
    }
  }
#pragma unroll
  for (int ni = 0; ni < 4; ++ni) {
    const int col = n0 + wc + ni * 16 + lr;
    const float bv = (OUTMODE == 2) ? 0.f : biasp[col];
#pragma unroll
    for (int mi = 0; mi < 4; ++mi)
#pragma unroll
      for (int j = 0; j < 4; ++j) {
        const int row = m0 + wr + mi * 16 + lg * 4 + j;
        const float v = acc[mi][ni][j] + bv;
        if (OUTMODE == 4) {
          const int nn = row >> 8, pp = row & 255, h = col >> 6, d = col & 63;
          ((u16*)Cp)[(size_t)(nn * HNUM + h) * (DDIM * KPDIM) + d * 256 +
                     (((pp >> 3) ^ (d & 7)) * 8) + (pp & 7)] = f2b(v);
        } else if (OUTMODE == 3) {
          const int nn = row >> 8, pp = row & 255, h = col >> 6, d = col & 63;
          ((u16*)Cp)[((size_t)(nn * HNUM + h) * KPDIM + pp) * DDIM + d] = f2b(v);
        } else if (OUTMODE == 2)
          ((float*)Cp)[(size_t)sp * M * 1024 + (size_t)row * 1024 + col] = v;
        else if (OUTMODE == 1)
          ((float*)Cp)[(size_t)row * 1024 + col] = v;
        else
          ((u16*)Cp)[(size_t)row * 1024 + col] = f2b(v);
      }
  }
}

// ---------------------------------------------------------------------------
// Fused attention v3: block = (64 q-rows, n, head-group), hpg heads each.
// Kc (N,H,Kp,D); VcT (N,H,D,Kp) pre-transposed + chunk-swizzled in global.
// ---------------------------------------------------------------------------
__global__ __launch_bounds__(256)
void attn_fused(const u16* __restrict__ Q, const u16* __restrict__ Kc,
                const u16* __restrict__ VcT, u16* __restrict__ Aout,
                float* __restrict__ AWp, int hpg) {
  __shared__ u16 Ares[256 * 64];   // K [p][d] chunk-swizzled -> P quarters
  __shared__ u16 Bres[64 * 256];   // V^T [d][p] chunk-swizzled
  const int tid = threadIdx.x;
  const int w = tid >> 6, lane = tid & 63;
  const int lr = lane & 15, lg = lane >> 4;
  const int n = blockIdx.y;
  const int l0 = blockIdx.x * 64;
  const int lrow = l0 + w * 16 + lr;
  char* kbase = (char*)Ares;
  char* vbase = (char*)Bres;
  char* pbase = (char*)Ares + w * 8192;

  f32x4 macc[16];
#pragma unroll
  for (int ni = 0; ni < 16; ++ni) { f32x4 zv = {0.f,0.f,0.f,0.f}; macc[ni] = zv; }

  for (int hh = 0; hh < hpg; ++hh) {
    const int h = blockIdx.z * hpg + hh;
    const u16* kh = Kc + (size_t)(n * HNUM + h) * (KPDIM * DDIM);
    const u16* vh = VcT + (size_t)(n * HNUM + h) * (DDIM * KPDIM);
    __syncthreads();
#pragma unroll
    for (int it = 0; it < 8; ++it) {
      int c = it * 256 + tid;
      int p = c >> 3, j = c & 7;
      gl_lds16(kh + p * 64 + ((j ^ (p & 7)) << 3), kbase + c * 16);
    }
#pragma unroll
    for (int it = 0; it < 8; ++it) {
      int c = it * 256 + tid;
      gl_lds16(vh + c * 8, vbase + c * 16);
    }
    const u16* qp = Q + (size_t)lrow * NE + n * EDIM + h * DDIM + lg * 8;
    bf16x8 aq0 = *(const bf16x8*)qp;
    bf16x8 aq1 = *(const bf16x8*)(qp + 32);
    __syncthreads();
    f32x4 s[16];
#pragma unroll
    for (int ni = 0; ni < 16; ++ni) { f32x4 zv = {0.f,0.f,0.f,0.f}; s[ni] = zv; }
#pragma unroll
    for (int ni = 0; ni < 16; ++ni) {
      int row = ni * 16 + lr;
      const char* kr = kbase + row * 128;
      bf16x8 b0 = *(const bf16x8*)(kr + ((lg ^ (row & 7)) << 4));
      bf16x8 b1 = *(const bf16x8*)(kr + (((4 + lg) ^ (row & 7)) << 4));
      s[ni] = mfma16(aq0, b0, s[ni]);
      s[ni] = mfma16(aq1, b1, s[ni]);
    }
    float mx[4], sm[4], inv[4];
#pragma unroll
    for (int j = 0; j < 4; ++j) mx[j] = -1e30f;
#pragma unroll
    for (int ni = 0; ni < 16; ++ni)
#pragma unroll
      for (int j = 0; j < 4; ++j) mx[j] = fmaxf(mx[j], s[ni][j]);
#pragma unroll
    for (int msk = 1; msk <= 8; msk <<= 1)
#pragma unroll
      for (int j = 0; j < 4; ++j) mx[j] = fmaxf(mx[j], __shfl_xor(mx[j], msk, 64));
#pragma unroll
    for (int j = 0; j < 4; ++j) sm[j] = 0.f;
#pragma unroll
    for (int ni = 0; ni < 16; ++ni)
#pragma unroll
      for (int j = 0; j < 4; ++j) {
        float e = __expf(s[ni][j] - mx[j]);
        s[ni][j] = e; sm[j] += e;
      }
#pragma unroll
    for (int msk = 1; msk <= 8; msk <<= 1)
#pragma unroll
      for (int j = 0; j < 4; ++j) sm[j] += __shfl_xor(sm[j], msk, 64);
#pragma unroll
    for (int j = 0; j < 4; ++j) inv[j] = 1.0f / sm[j];
    __syncthreads();
#pragma unroll
    for (int ni = 0; ni < 16; ++ni)
#pragma unroll
      for (int j = 0; j < 4; ++j) {
        float pv = s[ni][j] * inv[j];
        macc[ni][j] += pv * 0.0625f;
        int r = lg * 4 + j;
        *(u16*)(pbase + r * 512 + ((ni * 32 + lr * 2) ^ ((r & 7) << 4))) = f2b(pv);
      }
    f32x4 o[4];
#pragma unroll
    for (int ni2 = 0; ni2 < 4; ++ni2) { f32x4 zv = {0.f,0.f,0.f,0.f}; o[ni2] = zv; }
#pragma unroll
    for (int ks = 0; ks < 8; ++ks) {
      bf16x8 a = *(const bf16x8*)(pbase + lr * 512 + ((ks * 64 + 16 * lg) ^ ((lr & 7) << 4)));
#pragma unroll
      for (int ni2 = 0; ni2 < 4; ++ni2) {
        int d = ni2 * 16 + lr;
        bf16x8 b = *(const bf16x8*)(vbase + d * 512 + (((ks * 4 + lg) ^ (d & 7)) << 4));
        o[ni2] = mfma16(a, b, o[ni2]);
      }
    }
#pragma unroll
    for (int ni2 = 0; ni2 < 4; ++ni2)
#pragma unroll
      for (int j = 0; j < 4; ++j) {
        int gl = l0 + w * 16 + lg * 4 + j;
        Aout[(size_t)gl * NE + n * EDIM + h * DDIM + ni2 * 16 + lr] = f2b(o[ni2][j]);
      }
  }
  float* awo = AWp + (size_t)blockIdx.z * AWSZ + (size_t)n * (LSEQ * KPDIM);
#pragma unroll
  for (int ni = 0; ni < 16; ++ni)
#pragma unroll
    for (int j = 0; j < 4; ++j) {
      int r = lg * 4 + j;
      awo[(size_t)(l0 + w * 16 + r) * KPDIM + ni * 16 + lr] = macc[ni][j];
    }
}

// ---------------------------------------------------------------------------
extern "C" void kernel_launch(void* const* d_in, const int* in_sizes, int n_in,
                              void* d_out, int out_size, void* d_ws, size_t ws_size,
                              hipStream_t stream) {
  const float* query = (const float*)d_in[0];
  const float* key   = (const float*)d_in[1];
  const float* value = (const float*)d_in[2];
  const float* ipw   = (const float*)d_in[3];
  const float* ipb   = (const float*)d_in[4];
  const float* ew    = (const float*)d_in[5];
  const float* eb    = (const float*)d_in[6];
  const float* fw    = (const float*)d_in[7];
  const float* fb    = (const float*)d_in[8];
  const float* ow    = (const float*)d_in[9];
  const float* ob    = (const float*)d_in[10];

  char* ws = (char*)d_ws;
  size_t off = 0;
  auto alloc = [&](size_t bytes) {
    void* p = ws + off;
    off += (bytes + 255) & ~(size_t)255;
    return p;
  };
  u16* qp    = (u16*)alloc((size_t)MROWS * EDIM * 2);
  u16* kp    = (u16*)alloc((size_t)MROWS * EDIM * 2);
  u16* vp    = (u16*)alloc((size_t)MROWS * EDIM * 2);
  u16* ao    = (u16*)alloc((size_t)MROWS * EDIM * 2);
  u16* kc    = (u16*)alloc((size_t)NB * KPDIM * EDIM * 2);   // (N,H,Kp,D)
  u16* vcT   = (u16*)alloc((size_t)NB * KPDIM * EDIM * 2);   // (N,H,D,Kp) swz
  u16* w_in  = (u16*)alloc((size_t)3 * EDIM * EDIM * 2);
  u16* w_eT  = (u16*)alloc((size_t)EDIM * 8 * EDIM * 2);
  u16* w_fT  = (u16*)alloc((size_t)EDIM * 8 * EDIM * 2);
  u16* w_out = (u16*)alloc((size_t)EDIM * EDIM * 2);
  float* bq  = (float*)alloc(EDIM * 4);
  size_t base_needed = off;

  size_t qkv16_b = (size_t)3 * MROWS * EDIM * 2;
  size_t part_b  = (size_t)2 * 4 * 2048 * 1024 * 4;
  bool bigX  = ws_size >= base_needed + qkv16_b;
  bool midX  = ws_size >= base_needed + part_b;
  char* X = (char*)alloc(bigX ? qkv16_b : (midX ? part_b : 0));
  u16* qkv16 = (u16*)X;
  float* part = (float*)X;
  float* awp  = (float*)X;

  float* out_f = (float*)d_out;                        // (L, N, E)
  float* aw_f  = (float*)d_out + (size_t)MROWS * EDIM; // (N, L, Kp)

  // weight prep
  wconv<<<dim3(3072), 256, 0, stream>>>(ipw, w_in, 786432, 262144, 0.125f);
  wconv<<<dim3(1024), 256, 0, stream>>>(ow, w_out, 262144, 0, 1.0f);
  wtrans<<<dim3(16384, 2), 64, 0, stream>>>(ew, fw, w_eT, w_fT);
  bscale<<<dim3(4), 256, 0, stream>>>(ipb, bq);

  // q/k/v projections
  if (bigX) {
    castqkv<<<dim3(8192, 3), 256, 0, stream>>>(query, key, value, qkv16);
    gemm256<0, 0><<<dim3(64, 4, 3), 512, 0, stream>>>(
        qkv16, qkv16 + (size_t)MROWS * EDIM, qkv16 + (size_t)2 * MROWS * EDIM,
        w_in, w_in + 1048576, w_in + 2097152,
        bq, ipb + 1024, ipb + 2048,
        qp, kp, vp, MROWS, 1024, 1);
  } else {
    gemm_bt<2, 0><<<dim3(128, 8, 3), 256, 0, stream>>>(
        query, key, value,
        w_in, w_in + 1048576, w_in + 2097152,
        bq, ipb + 1024, ipb + 2048,
        qp, kp, vp, MROWS, 1024, 1);
  }

  // conv compression of k and v -> kc (head-major) / vcT (transposed swz)
  if (bigX || midX) {
    gemm256<1, 2><<<dim3(8, 4, 8), 512, 0, stream>>>(
        kp, vp, vp,
        w_eT, w_fT, w_fT,
        eb, fb, fb,
        part, part + (size_t)4 * 2048 * 1024, part,
        NB * KPDIM, 8192, 4);
    redc<<<dim3(2048, 2), 256, 0, stream>>>(part, eb, fb, kc, vcT);
  } else {
    gemm_bt<1, 3><<<dim3(16, 8, 1), 256, 0, stream>>>(
        kp, kp, kp, w_eT, w_eT, w_eT, eb, eb, eb,
        kc, kc, kc, NB * KPDIM, 8192, 1);
    gemm_bt<1, 4><<<dim3(16, 8, 1), 256, 0, stream>>>(
        vp, vp, vp, w_fT, w_fT, w_fT, fb, fb, fb,
        vcT, vcT, vcT, NB * KPDIM, 8192, 1);
  }

  // fused attention + head-mean weights
  if (bigX) {
    attn_fused<<<dim3(32, 8, 4), 256, 0, stream>>>(qp, kc, vcT, ao, awp, 4);
    awred<<<dim3(4096), 256, 0, stream>>>(awp, aw_f);
  } else {
    attn_fused<<<dim3(32, 8, 1), 256, 0, stream>>>(qp, kc, vcT, ao, aw_f, 16);
  }

  // output projection -> f32 d_out
  gemm256<0, 1><<<dim3(64, 4, 1), 512, 0, stream>>>(
      ao, ao, ao,
      w_out, w_out, w_out,
      ob, ob, ob,
      out_f, out_f, out_f, MROWS, 1024, 1);
}